// Round 2
// baseline (720.364 us; speedup 1.0000x reference)
//
#include <hip/hip_runtime.h>

// DKVMN + code2vec attention. Sizes (fixed):
// B=16 L=128 P=128 NUM_C=100 D=128 M=64 EMB=128 TE=384 CODE_W=584 NROW=10002
//
// All harness inputs/outputs are float32 (per reference dtypes). Internal
// projected tables PS/PE/PP are stored bf16 to halve gather bandwidth.
//
// Pipeline:
//  k_pre : PS/PE/PP[n][j] = emb @ W_pt slices (factorized full@W_pt, 26x FLOP cut)
//  k_cw  : cw[b,p,l] = tanh(PS[s]+PE[e]+PP[pa]+b_pt) . W_att + b_att
//  k_sm  : softmax over l (axis=1!) per (b,p); store attn transposed to [b,l,p]
//  k_cv  : code_vec[b,l,:] = sum_p attn * [EN[s];EN[e];EP[pa]]
//  k_eaw : e = sigmoid(v@W_e), a = tanh(v@W_a), w = softmax(k@Mk^T)
//  k_scan: sequential memory scan, separable in d -> 32 blocks x 64 threads
//  k_out : f = tanh([read,k]@W_f), out = sigmoid(f@W_p)

typedef unsigned short u16;
typedef unsigned int u32;

#define DEV __device__ __forceinline__

DEV float b2f(u16 u) { union { u32 i; float f; } v; v.i = ((u32)u) << 16; return v.f; }
DEV u16 f2b(float f) {
    union { float f; u32 i; } v; v.f = f;
    u32 x = v.i;
    u32 r = (x + 0x7FFFu + ((x >> 16) & 1u)) >> 16;   // RNE
    return (u16)r;
}
DEV float sigmoidf_(float x) { return 1.f / (1.f + __expf(-x)); }

// ---------------------------------------------------------------- k_pre
// grid (626, 3), block 384. which=0: PS=EN@Wpt[:,0:... rows 0:128]; 1: PE (rows 128:256);
// 2: PP (rows 256:384) + b_pt (bias added once, on PP, across all 384 cols).
__global__ void k_pre(const float* __restrict__ EN, const float* __restrict__ EP,
                      const float* __restrict__ Wpt, const float* __restrict__ bpt,
                      u16* __restrict__ PS, u16* __restrict__ PE, u16* __restrict__ PP) {
    int which = blockIdx.y;
    int r0 = blockIdx.x * 16;
    int j = threadIdx.x;                       // 0..383 output col
    const float* src = (which == 2) ? EP : EN;
    int koff = which * 128;
    u16* dst = (which == 0) ? PS : (which == 1) ? PE : PP;

    __shared__ float emb[16][128];
    for (int idx = threadIdx.x; idx < 16 * 128; idx += 384) {
        int rr = idx >> 7, kk = idx & 127;
        int row = r0 + rr;
        emb[rr][kk] = (row < 10002) ? src[row * 128 + kk] : 0.f;
    }
    __syncthreads();

    float acc[16];
#pragma unroll
    for (int r = 0; r < 16; r++) acc[r] = 0.f;
    for (int k = 0; k < 128; k++) {
        float w = Wpt[(koff + k) * 384 + j];
#pragma unroll
        for (int r = 0; r < 16; r++) acc[r] = fmaf(emb[r][k], w, acc[r]);
    }
    float bias = (which == 2) ? bpt[j] : 0.f;
    for (int r = 0; r < 16; r++) {
        int row = r0 + r;
        if (row < 10002) dst[row * 384 + j] = f2b(acc[r] + bias);
    }
}

// ---------------------------------------------------------------- k_cw
// grid 65536, block 256 (4 waves, one triple per wave). cw layout [b][p][l].
__global__ void k_cw(const int* __restrict__ code,
                     const u16* __restrict__ PS, const u16* __restrict__ PE,
                     const u16* __restrict__ PP, const float* __restrict__ Watt,
                     const float* __restrict__ batt, float* __restrict__ cw) {
    int wid = threadIdx.x >> 6, lane = threadIdx.x & 63;
    int t = blockIdx.x * 4 + wid;              // triple index in [0, B*L*P)
    int b = t >> 14;
    int rem = t & 16383;
    int l = rem >> 7, p = rem & 127;

    const int* c = code + ((b * 128 + l) * 584 + 200 + 3 * p);
    int s = c[0], pa = c[1], e = c[2];         // (start, path, end)
    const u16* ps = PS + s * 384;
    const u16* pe = PE + e * 384;
    const u16* pp = PP + pa * 384;

    float acc = 0.f;
    int j0 = lane * 6;
#pragma unroll
    for (int u = 0; u < 6; u++) {
        int j = j0 + u;
        float z = b2f(ps[j]) + b2f(pe[j]) + b2f(pp[j]);
        acc = fmaf(tanhf(z), Watt[j], acc);
    }
#pragma unroll
    for (int off = 32; off; off >>= 1) acc += __shfl_down(acc, off, 64);
    if (lane == 0) cw[(b * 128 + p) * 128 + l] = acc + batt[0];
}

// ---------------------------------------------------------------- k_sm
// grid 2048 = (b,p), block 128 = l. Softmax over l, store attn as [b][l][p].
__global__ void k_sm(const float* __restrict__ cw, float* __restrict__ attn) {
    int g = blockIdx.x;                        // b*128 + p
    int l = threadIdx.x;
    float x = cw[g * 128 + l];
    __shared__ float red[128];
    red[l] = x; __syncthreads();
    for (int s = 64; s; s >>= 1) { if (l < s) red[l] = fmaxf(red[l], red[l + s]); __syncthreads(); }
    float mx = red[0]; __syncthreads();
    float ex = __expf(x - mx);
    red[l] = ex; __syncthreads();
    for (int s = 64; s; s >>= 1) { if (l < s) red[l] += red[l + s]; __syncthreads(); }
    float inv = 1.f / red[0];
    int b = g >> 7, p = g & 127;
    attn[(b * 128 + l) * 128 + p] = ex * inv;
}

// ---------------------------------------------------------------- k_cv
// grid 2048 = (b,l), block 128 = d. code_vec[row][0:384] f32.
__global__ void k_cv(const int* __restrict__ code, const float* __restrict__ attn,
                     const float* __restrict__ EN, const float* __restrict__ EP,
                     float* __restrict__ code_vec) {
    int row = blockIdx.x;                      // b*L + l
    int t = threadIdx.x;
    __shared__ int si[128], ei[128], pi[128];
    __shared__ float at[128];
    const int* c = code + (row * 584 + 200);
    si[t] = c[3 * t]; pi[t] = c[3 * t + 1]; ei[t] = c[3 * t + 2];
    at[t] = attn[row * 128 + t];
    __syncthreads();
    float a0 = 0.f, a1 = 0.f, a2 = 0.f;
    for (int p = 0; p < 128; p++) {
        float w = at[p];
        a0 = fmaf(w, EN[si[p] * 128 + t], a0);
        a1 = fmaf(w, EN[ei[p] * 128 + t], a1);
        a2 = fmaf(w, EP[pi[p] * 128 + t], a2);
    }
    float* out = code_vec + row * 384;
    out[t] = a0; out[128 + t] = a1; out[256 + t] = a2;
}

// ---------------------------------------------------------------- k_eaw
// grid 256 (8 rows each), block 256. threads 0-127: e, 128-255: a. Then w-softmax.
__global__ void k_eaw(const int* __restrict__ rr, const int* __restrict__ qq,
                      const float* __restrict__ Vemb, const float* __restrict__ code_vec,
                      const float* __restrict__ Kemb,
                      const float* __restrict__ We, const float* __restrict__ be,
                      const float* __restrict__ Wa, const float* __restrict__ ba,
                      const float* __restrict__ Mk,
                      float* __restrict__ eb, float* __restrict__ ab, float* __restrict__ wb) {
    int r0 = blockIdx.x * 8;
    int tid = threadIdx.x;
    __shared__ float v[8][512];
    __shared__ float kv[8][128];

    for (int idx = tid; idx < 8 * 512; idx += 256) {
        int r = idx >> 9, kk = idx & 511;
        int row = r0 + r;
        v[r][kk] = (kk < 128) ? Vemb[rr[row] * 128 + kk]
                              : code_vec[row * 384 + (kk - 128)];
    }
    for (int idx = tid; idx < 8 * 128; idx += 256) {
        int r = idx >> 7, kk = idx & 127;
        kv[r][kk] = Kemb[qq[r0 + r] * 128 + kk];
    }
    __syncthreads();

    int d = tid & 127;
    bool doA = tid >= 128;
    const float* W = doA ? Wa : We;
    float bias = (doA ? ba : be)[d];
    float acc[8];
#pragma unroll
    for (int r = 0; r < 8; r++) acc[r] = 0.f;
    for (int kk = 0; kk < 512; kk++) {
        float wv = W[kk * 128 + d];
#pragma unroll
        for (int r = 0; r < 8; r++) acc[r] = fmaf(v[r][kk], wv, acc[r]);
    }
    for (int r = 0; r < 8; r++) {
        float val = acc[r] + bias;
        float res = doA ? tanhf(val) : sigmoidf_(val);
        (doA ? ab : eb)[(r0 + r) * 128 + d] = res;
    }

    // w = softmax(k @ Mk^T): lane = m, wave handles rows half, half+4
    int m = tid & 63, half = tid >> 6;
    for (int r2 = half; r2 < 8; r2 += 4) {
        float lg = 0.f;
        for (int kk = 0; kk < 128; kk++) lg = fmaf(kv[r2][kk], Mk[m * 128 + kk], lg);
        float mx = lg;
#pragma unroll
        for (int off = 32; off; off >>= 1) mx = fmaxf(mx, __shfl_xor(mx, off, 64));
        float ex = __expf(lg - mx);
        float sum = ex;
#pragma unroll
        for (int off = 32; off; off >>= 1) sum += __shfl_xor(sum, off, 64);
        wb[(r0 + r2) * 64 + m] = ex / sum;
    }
}

// ---------------------------------------------------------------- k_scan
// grid 32 = (b, d-half), block 64. State Mv[m][d] separable in d; 64 regs/thread.
__global__ void k_scan(const float* __restrict__ Mv0, const float* __restrict__ eb,
                       const float* __restrict__ ab, const float* __restrict__ wb,
                       float* __restrict__ readb) {
    int b = blockIdx.x >> 1, half = blockIdx.x & 1;
    int d = half * 64 + threadIdx.x;
    float mv[64];
#pragma unroll
    for (int m = 0; m < 64; m++) mv[m] = Mv0[m * 128 + d];
    for (int t = 0; t < 128; t++) {
        int row = b * 128 + t;
        const float4* wp = (const float4*)(wb + row * 64);   // lane-uniform, L1 broadcast
        float ed = eb[row * 128 + d];
        float ad = ab[row * 128 + d];
        float rd = 0.f;
#pragma unroll
        for (int q4 = 0; q4 < 16; q4++) {
            float4 w4 = wp[q4];
            int mb = q4 * 4;
            rd = fmaf(w4.x, mv[mb + 0], rd); mv[mb + 0] = fmaf(w4.x, fmaf(-mv[mb + 0], ed, ad), mv[mb + 0]);
            rd = fmaf(w4.y, mv[mb + 1], rd); mv[mb + 1] = fmaf(w4.y, fmaf(-mv[mb + 1], ed, ad), mv[mb + 1]);
            rd = fmaf(w4.z, mv[mb + 2], rd); mv[mb + 2] = fmaf(w4.z, fmaf(-mv[mb + 2], ed, ad), mv[mb + 2]);
            rd = fmaf(w4.w, mv[mb + 3], rd); mv[mb + 3] = fmaf(w4.w, fmaf(-mv[mb + 3], ed, ad), mv[mb + 3]);
        }
        readb[row * 128 + d] = rd;
    }
}

// ---------------------------------------------------------------- k_out
// grid 256 (8 rows), block 128. f = tanh([read,k]@W_f+b_f); out = sigmoid(f@W_p+b_p)
__global__ void k_out(const int* __restrict__ qq, const float* __restrict__ Kemb,
                      const float* __restrict__ readb,
                      const float* __restrict__ Wf, const float* __restrict__ bfp,
                      const float* __restrict__ Wp, const float* __restrict__ bp,
                      float* __restrict__ out) {
    int r0 = blockIdx.x * 8;
    int tid = threadIdx.x;
    __shared__ float c[8][256];
    __shared__ float fs[8][128];
    for (int idx = tid; idx < 8 * 256; idx += 128) {
        int r = idx >> 8, kk = idx & 255;
        int row = r0 + r;
        c[r][kk] = (kk < 128) ? readb[row * 128 + kk]
                              : Kemb[qq[row] * 128 + (kk - 128)];
    }
    __syncthreads();
    int d = tid;
    float acc[8];
#pragma unroll
    for (int r = 0; r < 8; r++) acc[r] = 0.f;
    for (int kk = 0; kk < 256; kk++) {
        float wv = Wf[kk * 128 + d];
#pragma unroll
        for (int r = 0; r < 8; r++) acc[r] = fmaf(c[r][kk], wv, acc[r]);
    }
    float bias = bfp[d];
#pragma unroll
    for (int r = 0; r < 8; r++) fs[r][d] = tanhf(acc[r] + bias);
    __syncthreads();
    if (tid < 80) {
        int r = tid / 10, j = tid % 10;
        float a2 = 0.f;
        for (int dd = 0; dd < 128; dd++) a2 = fmaf(fs[r][dd], Wp[dd * 10 + j], a2);
        out[(r0 + r) * 10 + j] = sigmoidf_(a2 + bp[j]);
    }
}

extern "C" void kernel_launch(void* const* d_in, const int* in_sizes, int n_in,
                              void* d_out, int out_size, void* d_ws, size_t ws_size,
                              hipStream_t stream) {
    const int*   code = (const int*)d_in[0];
    const int*   q    = (const int*)d_in[1];
    const int*   r    = (const int*)d_in[2];
    const float* EN   = (const float*)d_in[3];
    const float* EP   = (const float*)d_in[4];
    const float* Wpt  = (const float*)d_in[5];
    const float* bpt  = (const float*)d_in[6];
    const float* Watt = (const float*)d_in[7];
    const float* batt = (const float*)d_in[8];
    const float* Kemb = (const float*)d_in[9];
    const float* Mk   = (const float*)d_in[10];
    const float* Mv0  = (const float*)d_in[11];
    const float* Vemb = (const float*)d_in[12];
    const float* We   = (const float*)d_in[13];
    const float* be   = (const float*)d_in[14];
    const float* Wa   = (const float*)d_in[15];
    const float* ba   = (const float*)d_in[16];
    const float* Wf   = (const float*)d_in[17];
    const float* bf_  = (const float*)d_in[18];
    const float* Wp   = (const float*)d_in[19];
    const float* bp   = (const float*)d_in[20];

    char* ws = (char*)d_ws;
    size_t off = 0;
    auto alloc = [&](size_t bytes) { void* p = ws + off; off = (off + bytes + 255) & ~255UL; return p; };
    u16*   PS    = (u16*)alloc(10002UL * 384 * 2);
    u16*   PE    = (u16*)alloc(10002UL * 384 * 2);
    u16*   PP    = (u16*)alloc(10002UL * 384 * 2);
    float* cw    = (float*)alloc(16UL * 128 * 128 * 4);   // [b][p][l]
    float* attn  = (float*)alloc(16UL * 128 * 128 * 4);   // [b][l][p]
    float* cvec  = (float*)alloc(16UL * 128 * 384 * 4);
    float* eb    = (float*)alloc(16UL * 128 * 128 * 4);
    float* ab    = (float*)alloc(16UL * 128 * 128 * 4);
    float* wb    = (float*)alloc(16UL * 128 * 64 * 4);
    float* readb = (float*)alloc(16UL * 128 * 128 * 4);

    k_pre<<<dim3(626, 3), 384, 0, stream>>>(EN, EP, Wpt, bpt, PS, PE, PP);
    k_cw<<<65536, 256, 0, stream>>>(code, PS, PE, PP, Watt, batt, cw);
    k_sm<<<2048, 128, 0, stream>>>(cw, attn);
    k_cv<<<2048, 128, 0, stream>>>(code, attn, EN, EP, cvec);
    k_eaw<<<256, 256, 0, stream>>>(r, q, Vemb, cvec, Kemb, We, be, Wa, ba, Mk, eb, ab, wb);
    k_scan<<<32, 64, 0, stream>>>(Mv0, eb, ab, wb, readb);
    k_out<<<256, 128, 0, stream>>>(q, Kemb, readb, Wf, bf_, Wp, bp, (float*)d_out);
}

// Round 3
// 540.644 us; speedup vs baseline: 1.3324x; 1.3324x over previous
//
#include <hip/hip_runtime.h>

// DKVMN + code2vec attention. Sizes (fixed):
// B=16 L=128 P=128 NUM_C=100 D=128 M=64 EMB=128 TE=384 CODE_W=584 NROW=10002
//
// Inputs/outputs f32. Internal tables PS/PE/PP (projected) and ENb/EPb (raw)
// stored bf16 to halve gather bandwidth.
//
//  k_pre : PS/PE/PP[n][j] = emb @ W_pt slices (factorized full@W_pt, 26x FLOP cut)
//          emb read via wave-uniform s_load (no LDS broadcast reads); also emits
//          bf16 copies ENb/EPb for k_cv.
//  k_cw  : cw[b,p,l] = tanh(PS[s]+PE[e]+PP[pa]) . W_att + b_att   (12B vector gathers)
//  k_sm  : softmax over l (axis=1!) per (b,p); attn stored [b,l,p]
//  k_cv  : code_vec[b,l,:] = sum_p attn * [EN[s];EN[e];EP[pa]]  (bf16 gathers, 4-way p split)
//  k_eaw : e = sigmoid(v@W_e), a = tanh(v@W_a), w = softmax(k@Mk^T)
//  k_scan: sequential memory scan, 8-way m-split, 256 blocks, prefetched
//  k_out : f = tanh([read,k]@W_f), out = sigmoid(f@W_p)

typedef unsigned short u16;
typedef unsigned int u32;

#define DEV __device__ __forceinline__

DEV float b2f(u16 u) { union { u32 i; float f; } v; v.i = ((u32)u) << 16; return v.f; }
DEV float lo16(u32 u) { union { u32 i; float f; } v; v.i = u << 16; return v.f; }
DEV float hi16(u32 u) { union { u32 i; float f; } v; v.i = u & 0xFFFF0000u; return v.f; }
DEV u16 f2b(float f) {
    union { float f; u32 i; } v; v.f = f;
    u32 x = v.i;
    u32 r = (x + 0x7FFFu + ((x >> 16) & 1u)) >> 16;   // RNE
    return (u16)r;
}
DEV float sigmoidf_(float x) { return 1.f / (1.f + __expf(-x)); }
// tanh(x) = 1 - 2/(1+e^{2x}); exact at +/-inf (e=inf -> 0; e=0 -> -1). ~1e-6 rel err.
DEV float fast_tanh(float x) {
    float e = __expf(2.f * x);
    return 1.f - __fdividef(2.f, 1.f + e);
}

// ---------------------------------------------------------------- k_pre
// grid (626, 3), block 384. which=0: PS (Wpt rows 0:128, from EN);
// 1: PE (rows 128:256, EN); 2: PP (rows 256:384, EP) + b_pt.
// emb values are wave-uniform -> compiler emits s_load (SMEM pipe), VALU does fma.
__global__ void k_pre(const float* __restrict__ EN, const float* __restrict__ EP,
                      const float* __restrict__ Wpt, const float* __restrict__ bpt,
                      u16* __restrict__ PS, u16* __restrict__ PE, u16* __restrict__ PP,
                      u16* __restrict__ ENb, u16* __restrict__ EPb) {
    int which = blockIdx.y;
    int r0 = blockIdx.x * 16;
    int j = threadIdx.x;                       // 0..383 output col
    const float* src = (which == 2) ? EP : EN;
    int koff = which * 128;
    u16* dst = (which == 0) ? PS : (which == 1) ? PE : PP;

    float acc[16];
#pragma unroll
    for (int r = 0; r < 16; r++) acc[r] = 0.f;
    for (int k = 0; k < 128; k++) {
        float w = Wpt[(koff + k) * 384 + j];   // coalesced vector load
#pragma unroll
        for (int r = 0; r < 16; r++) {
            int row = min(r0 + r, 10001);      // clamp (uniform); garbage rows masked at store
            acc[r] = fmaf(src[row * 128 + k], w, acc[r]);  // uniform index -> s_load
        }
    }
    float bias = (which == 2) ? bpt[j] : 0.f;
#pragma unroll
    for (int r = 0; r < 16; r++) {
        int row = r0 + r;
        if (row < 10002) dst[row * 384 + j] = f2b(acc[r] + bias);
    }
    // bf16 raw copies for k_cv (coalesced re-read, L2-hot)
    if (which != 1) {
        u16* cdst = (which == 0) ? ENb : EPb;
        for (int idx = threadIdx.x; idx < 16 * 128; idx += 384) {
            int rr = idx >> 7, kk = idx & 127;
            int row = r0 + rr;
            if (row < 10002) cdst[row * 128 + kk] = f2b(src[row * 128 + kk]);
        }
    }
}

// ---------------------------------------------------------------- k_cw
// grid 65536, block 256 (4 waves, one triple per wave). cw layout [b][p][l].
// Per lane: 12 contiguous bytes from each of 3 tables (3x dwordx3-class loads).
__global__ void k_cw(const int* __restrict__ code,
                     const u16* __restrict__ PS, const u16* __restrict__ PE,
                     const u16* __restrict__ PP, const float* __restrict__ Watt,
                     const float* __restrict__ batt, float* __restrict__ cw) {
    int wid = threadIdx.x >> 6, lane = threadIdx.x & 63;
    int t = blockIdx.x * 4 + wid;              // triple index in [0, B*L*P)
    int b = t >> 14;
    int rem = t & 16383;
    int l = rem >> 7, p = rem & 127;

    const int* c = code + ((b * 128 + l) * 584 + 200 + 3 * p);
    int s = c[0], pa = c[1], e = c[2];         // (start, path, end); wave-uniform

    const u32* ps = (const u32*)(PS + s * 384) + lane * 3;
    const u32* pe = (const u32*)(PE + e * 384) + lane * 3;
    const u32* pp = (const u32*)(PP + pa * 384) + lane * 3;
    u32 s0 = ps[0], s1 = ps[1], s2 = ps[2];
    u32 e0 = pe[0], e1 = pe[1], e2 = pe[2];
    u32 p0 = pp[0], p1 = pp[1], p2 = pp[2];

    int j0 = lane * 6;
    float z0 = lo16(s0) + lo16(e0) + lo16(p0);
    float z1 = hi16(s0) + hi16(e0) + hi16(p0);
    float z2 = lo16(s1) + lo16(e1) + lo16(p1);
    float z3 = hi16(s1) + hi16(e1) + hi16(p1);
    float z4 = lo16(s2) + lo16(e2) + lo16(p2);
    float z5 = hi16(s2) + hi16(e2) + hi16(p2);

    float acc = 0.f;
    acc = fmaf(fast_tanh(z0), Watt[j0 + 0], acc);
    acc = fmaf(fast_tanh(z1), Watt[j0 + 1], acc);
    acc = fmaf(fast_tanh(z2), Watt[j0 + 2], acc);
    acc = fmaf(fast_tanh(z3), Watt[j0 + 3], acc);
    acc = fmaf(fast_tanh(z4), Watt[j0 + 4], acc);
    acc = fmaf(fast_tanh(z5), Watt[j0 + 5], acc);

#pragma unroll
    for (int off = 32; off; off >>= 1) acc += __shfl_down(acc, off, 64);
    if (lane == 0) cw[(b * 128 + p) * 128 + l] = acc + batt[0];
}

// ---------------------------------------------------------------- k_sm
// grid 2048 = (b,p), block 128 = l. Softmax over l, store attn as [b][l][p].
__global__ void k_sm(const float* __restrict__ cw, float* __restrict__ attn) {
    int g = blockIdx.x;                        // b*128 + p
    int l = threadIdx.x;
    float x = cw[g * 128 + l];
    __shared__ float red[128];
    red[l] = x; __syncthreads();
    for (int s = 64; s; s >>= 1) { if (l < s) red[l] = fmaxf(red[l], red[l + s]); __syncthreads(); }
    float mx = red[0]; __syncthreads();
    float ex = __expf(x - mx);
    red[l] = ex; __syncthreads();
    for (int s = 64; s; s >>= 1) { if (l < s) red[l] += red[l + s]; __syncthreads(); }
    float inv = 1.f / red[0];
    int b = g >> 7, p = g & 127;
    attn[(b * 128 + l) * 128 + p] = ex * inv;
}

// ---------------------------------------------------------------- k_cv
// grid 2048 = (b,l), block 256 = 4 waves. Wave w handles p = w, w+4, ...;
// lane covers 2 cols via u32 bf16-pair loads. LDS combine of 4 partials.
__global__ void k_cv(const int* __restrict__ code, const float* __restrict__ attn,
                     const u16* __restrict__ ENb, const u16* __restrict__ EPb,
                     float* __restrict__ code_vec) {
    int row = blockIdx.x;                      // b*L + l
    int tid = threadIdx.x;
    int wv = tid >> 6, lane = tid & 63;
    __shared__ int si[128], ei[128], pi[128];
    __shared__ float at[128];
    __shared__ float part[4][3][128];
    if (tid < 128) {
        const int* c = code + (row * 584 + 200);
        si[tid] = c[3 * tid]; pi[tid] = c[3 * tid + 1]; ei[tid] = c[3 * tid + 2];
        at[tid] = attn[row * 128 + tid];
    }
    __syncthreads();
    float a0 = 0.f, a1 = 0.f, b0 = 0.f, b1 = 0.f, c0 = 0.f, c1 = 0.f;
    for (int p = wv; p < 128; p += 4) {
        float w = at[p];
        u32 us = ((const u32*)(ENb + si[p] * 128))[lane];
        u32 ue = ((const u32*)(ENb + ei[p] * 128))[lane];
        u32 up = ((const u32*)(EPb + pi[p] * 128))[lane];
        a0 = fmaf(w, lo16(us), a0); a1 = fmaf(w, hi16(us), a1);
        b0 = fmaf(w, lo16(ue), b0); b1 = fmaf(w, hi16(ue), b1);
        c0 = fmaf(w, lo16(up), c0); c1 = fmaf(w, hi16(up), c1);
    }
    part[wv][0][2 * lane] = a0; part[wv][0][2 * lane + 1] = a1;
    part[wv][1][2 * lane] = b0; part[wv][1][2 * lane + 1] = b1;
    part[wv][2][2 * lane] = c0; part[wv][2][2 * lane + 1] = c1;
    __syncthreads();
    float* out = code_vec + row * 384;
    for (int idx = tid; idx < 384; idx += 256) {
        int tbl = idx >> 7, col = idx & 127;
        out[idx] = part[0][tbl][col] + part[1][tbl][col] + part[2][tbl][col] + part[3][tbl][col];
    }
}

// ---------------------------------------------------------------- k_eaw
// grid 256 (8 rows each), block 256. threads 0-127: e, 128-255: a. Then w-softmax.
__global__ void k_eaw(const int* __restrict__ rr, const int* __restrict__ qq,
                      const float* __restrict__ Vemb, const float* __restrict__ code_vec,
                      const float* __restrict__ Kemb,
                      const float* __restrict__ We, const float* __restrict__ be,
                      const float* __restrict__ Wa, const float* __restrict__ ba,
                      const float* __restrict__ Mk,
                      float* __restrict__ eb, float* __restrict__ ab, float* __restrict__ wb) {
    int r0 = blockIdx.x * 8;
    int tid = threadIdx.x;
    __shared__ float v[8][512];
    __shared__ float kv[8][128];

    for (int idx = tid; idx < 8 * 512; idx += 256) {
        int r = idx >> 9, kk = idx & 511;
        int row = r0 + r;
        v[r][kk] = (kk < 128) ? Vemb[rr[row] * 128 + kk]
                              : code_vec[row * 384 + (kk - 128)];
    }
    for (int idx = tid; idx < 8 * 128; idx += 256) {
        int r = idx >> 7, kk = idx & 127;
        kv[r][kk] = Kemb[qq[r0 + r] * 128 + kk];
    }
    __syncthreads();

    int d = tid & 127;
    bool doA = tid >= 128;
    const float* W = doA ? Wa : We;
    float bias = (doA ? ba : be)[d];
    float acc[8];
#pragma unroll
    for (int r = 0; r < 8; r++) acc[r] = 0.f;
    for (int kk = 0; kk < 512; kk++) {
        float wv = W[kk * 128 + d];
#pragma unroll
        for (int r = 0; r < 8; r++) acc[r] = fmaf(v[r][kk], wv, acc[r]);
    }
    for (int r = 0; r < 8; r++) {
        float val = acc[r] + bias;
        float res = doA ? fast_tanh(val) : sigmoidf_(val);
        (doA ? ab : eb)[(r0 + r) * 128 + d] = res;
    }

    // w = softmax(k @ Mk^T): lane = m, wave handles rows half, half+4
    int m = tid & 63, half = tid >> 6;
    for (int r2 = half; r2 < 8; r2 += 4) {
        float lg = 0.f;
        for (int kk = 0; kk < 128; kk++) lg = fmaf(kv[r2][kk], Mk[m * 128 + kk], lg);
        float mx = lg;
#pragma unroll
        for (int off = 32; off; off >>= 1) mx = fmaxf(mx, __shfl_xor(mx, off, 64));
        float ex = __expf(lg - mx);
        float sum = ex;
#pragma unroll
        for (int off = 32; off; off >>= 1) sum += __shfl_xor(sum, off, 64);
        wb[(r0 + r2) * 64 + m] = ex / sum;
    }
}

// ---------------------------------------------------------------- k_scan
// grid 256 = b(16) x dblk(16), block 64 (1 wave/CU). 8-way m-split:
// lane = s*8 + dlo; d = dblk*8+dlo; lane owns m = s*8 + q (q<8) -> mv[8] regs.
// read[d] reduced over s via shfl_xor(8,16,32). Next-step e/a/w prefetched.
__global__ void k_scan(const float* __restrict__ Mv0, const float* __restrict__ eb,
                       const float* __restrict__ ab, const float* __restrict__ wb,
                       float* __restrict__ readb) {
    int b = blockIdx.x >> 4, dblk = blockIdx.x & 15;
    int lane = threadIdx.x;
    int s = lane >> 3, dlo = lane & 7;
    int d = dblk * 8 + dlo;

    float mv[8];
#pragma unroll
    for (int q = 0; q < 8; q++) mv[q] = Mv0[(s * 8 + q) * 128 + d];

    const float* ebp = eb + b * 128 * 128 + d;
    const float* abp = ab + b * 128 * 128 + d;
    const float4* wbp = (const float4*)wb + (b * 128) * 16 + s * 2;
    float* rout = readb + b * 128 * 128 + d;

    float ecur = ebp[0], acur = abp[0];
    float4 w0 = wbp[0], w1 = wbp[1];

    for (int t = 0; t < 128; t++) {
        int tn = (t < 127) ? t + 1 : 127;
        float en = ebp[tn * 128], an = abp[tn * 128];
        float4 nw0 = wbp[tn * 16], nw1 = wbp[tn * 16 + 1];

        float w[8] = { w0.x, w0.y, w0.z, w0.w, w1.x, w1.y, w1.z, w1.w };
        float rd = 0.f;
#pragma unroll
        for (int q = 0; q < 8; q++) {
            rd = fmaf(w[q], mv[q], rd);
            mv[q] = fmaf(w[q], fmaf(-mv[q], ecur, acur), mv[q]);
        }
        rd += __shfl_xor(rd, 8, 64);
        rd += __shfl_xor(rd, 16, 64);
        rd += __shfl_xor(rd, 32, 64);
        if (s == 0) rout[t * 128] = rd;

        ecur = en; acur = an; w0 = nw0; w1 = nw1;
    }
}

// ---------------------------------------------------------------- k_out
// grid 256 (8 rows), block 128. f = tanh([read,k]@W_f+b_f); out = sigmoid(f@W_p+b_p)
__global__ void k_out(const int* __restrict__ qq, const float* __restrict__ Kemb,
                      const float* __restrict__ readb,
                      const float* __restrict__ Wf, const float* __restrict__ bfp,
                      const float* __restrict__ Wp, const float* __restrict__ bp,
                      float* __restrict__ out) {
    int r0 = blockIdx.x * 8;
    int tid = threadIdx.x;
    __shared__ float c[8][256];
    __shared__ float fs[8][128];
    for (int idx = tid; idx < 8 * 256; idx += 128) {
        int r = idx >> 8, kk = idx & 255;
        int row = r0 + r;
        c[r][kk] = (kk < 128) ? readb[row * 128 + kk]
                              : Kemb[qq[row] * 128 + (kk - 128)];
    }
    __syncthreads();
    int d = tid;
    float acc[8];
#pragma unroll
    for (int r = 0; r < 8; r++) acc[r] = 0.f;
    for (int kk = 0; kk < 256; kk++) {
        float wv = Wf[kk * 128 + d];
#pragma unroll
        for (int r = 0; r < 8; r++) acc[r] = fmaf(c[r][kk], wv, acc[r]);
    }
    float bias = bfp[d];
#pragma unroll
    for (int r = 0; r < 8; r++) fs[r][d] = fast_tanh(acc[r] + bias);
    __syncthreads();
    if (tid < 80) {
        int r = tid / 10, j = tid % 10;
        float a2 = 0.f;
        for (int dd = 0; dd < 128; dd++) a2 = fmaf(fs[r][dd], Wp[dd * 10 + j], a2);
        out[(r0 + r) * 10 + j] = sigmoidf_(a2 + bp[j]);
    }
}

extern "C" void kernel_launch(void* const* d_in, const int* in_sizes, int n_in,
                              void* d_out, int out_size, void* d_ws, size_t ws_size,
                              hipStream_t stream) {
    const int*   code = (const int*)d_in[0];
    const int*   q    = (const int*)d_in[1];
    const int*   r    = (const int*)d_in[2];
    const float* EN   = (const float*)d_in[3];
    const float* EP   = (const float*)d_in[4];
    const float* Wpt  = (const float*)d_in[5];
    const float* bpt  = (const float*)d_in[6];
    const float* Watt = (const float*)d_in[7];
    const float* batt = (const float*)d_in[8];
    const float* Kemb = (const float*)d_in[9];
    const float* Mk   = (const float*)d_in[10];
    const float* Mv0  = (const float*)d_in[11];
    const float* Vemb = (const float*)d_in[12];
    const float* We   = (const float*)d_in[13];
    const float* be   = (const float*)d_in[14];
    const float* Wa   = (const float*)d_in[15];
    const float* ba   = (const float*)d_in[16];
    const float* Wf   = (const float*)d_in[17];
    const float* bf_  = (const float*)d_in[18];
    const float* Wp   = (const float*)d_in[19];
    const float* bp   = (const float*)d_in[20];

    char* ws = (char*)d_ws;
    size_t off = 0;
    auto alloc = [&](size_t bytes) { void* p = ws + off; off = (off + bytes + 255) & ~255UL; return p; };
    u16*   PS    = (u16*)alloc(10002UL * 384 * 2);
    u16*   PE    = (u16*)alloc(10002UL * 384 * 2);
    u16*   PP    = (u16*)alloc(10002UL * 384 * 2);
    u16*   ENb   = (u16*)alloc(10002UL * 128 * 2);
    u16*   EPb   = (u16*)alloc(10002UL * 128 * 2);
    float* cw    = (float*)alloc(16UL * 128 * 128 * 4);   // [b][p][l]
    float* attn  = (float*)alloc(16UL * 128 * 128 * 4);   // [b][l][p]
    float* cvec  = (float*)alloc(16UL * 128 * 384 * 4);
    float* eb    = (float*)alloc(16UL * 128 * 128 * 4);
    float* ab    = (float*)alloc(16UL * 128 * 128 * 4);
    float* wb    = (float*)alloc(16UL * 128 * 64 * 4);
    float* readb = (float*)alloc(16UL * 128 * 128 * 4);

    k_pre<<<dim3(626, 3), 384, 0, stream>>>(EN, EP, Wpt, bpt, PS, PE, PP, ENb, EPb);
    k_cw<<<65536, 256, 0, stream>>>(code, PS, PE, PP, Watt, batt, cw);
    k_sm<<<2048, 128, 0, stream>>>(cw, attn);
    k_cv<<<2048, 256, 0, stream>>>(code, attn, ENb, EPb, cvec);
    k_eaw<<<256, 256, 0, stream>>>(r, q, Vemb, cvec, Kemb, We, be, Wa, ba, Mk, eb, ab, wb);
    k_scan<<<256, 64, 0, stream>>>(Mv0, eb, ab, wb, readb);
    k_out<<<256, 128, 0, stream>>>(q, Kemb, readb, Wf, bf_, Wp, bp, (float*)d_out);
}

// Round 4
// 347.930 us; speedup vs baseline: 2.0704x; 1.5539x over previous
//
#include <hip/hip_runtime.h>

// DKVMN + code2vec attention. Sizes (fixed):
// B=16 L=128 P=128 NUM_C=100 D=128 M=64 EMB=128 TE=384 CODE_W=584 NROW=10002
//
// Inputs/outputs f32. Internal tables bf16.
//
//  k_conv : bf16 copies ENb/EPb of embed tables + transposed bf16 Wt[n][k]=Wpt[k][n]
//  k_preM : PS/PE/PP = emb @ Wpt slices via MFMA 16x16x32 bf16 (factorized full@W_pt)
//  k_cw   : cw[b,p,l] = tanh(PS[s]+PE[e]+PP[pa]) . W_att + b_att  (4 triples/wave, planar gathers)
//  k_sm   : softmax over l (axis=1!) per (b,p); attn stored [b,l,p]
//  k_cv   : code_vec[b,l,:] = sum_p attn * [EN[s];EN[e];EP[pa]]  (bf16 gathers)
//  k_eaw  : e = sigmoid(v@W_e), a = tanh(v@W_a), w = softmax(k@Mk^T)
//  k_scan : sequential memory scan, 8-way m-split, 256 blocks
//  k_out  : f = tanh([read,k]@W_f), out = sigmoid(f@W_p)

typedef unsigned short u16;
typedef unsigned int u32;
typedef __attribute__((ext_vector_type(8))) short short8;   // 8 bf16 (4 VGPRs)
typedef __attribute__((ext_vector_type(4))) float f32x4;    // MFMA C/D

#define DEV __device__ __forceinline__

DEV float b2f(u16 u) { union { u32 i; float f; } v; v.i = ((u32)u) << 16; return v.f; }
DEV float lo16(u32 u) { union { u32 i; float f; } v; v.i = u << 16; return v.f; }
DEV float hi16(u32 u) { union { u32 i; float f; } v; v.i = u & 0xFFFF0000u; return v.f; }
DEV u16 f2b(float f) {
    union { float f; u32 i; } v; v.f = f;
    u32 x = v.i;
    u32 r = (x + 0x7FFFu + ((x >> 16) & 1u)) >> 16;   // RNE
    return (u16)r;
}
DEV float sigmoidf_(float x) { return 1.f / (1.f + __expf(-x)); }
// tanh(x) = 1 - 2/(1+e^{2x}); exact at +/-inf. ~1e-6 rel err.
DEV float fast_tanh(float x) {
    float e = __expf(2.f * x);
    return 1.f - __fdividef(2.f, 1.f + e);
}

// ---------------------------------------------------------------- k_conv
// Flat grid-stride: ENb (1280256), EPb (1280256), Wt (147456: Wt[n*384+k]=Wpt[k*384+n]).
__global__ void k_conv(const float* __restrict__ EN, const float* __restrict__ EP,
                       const float* __restrict__ Wpt,
                       u16* __restrict__ ENb, u16* __restrict__ EPb, u16* __restrict__ Wt) {
    const int NE = 10002 * 128;
    int total = NE * 2 + 147456;
    for (int i = blockIdx.x * blockDim.x + threadIdx.x; i < total; i += gridDim.x * blockDim.x) {
        if (i < NE) {
            ENb[i] = f2b(EN[i]);
        } else if (i < 2 * NE) {
            EPb[i - NE] = f2b(EP[i - NE]);
        } else {
            int w = i - 2 * NE;              // n*384 + k
            u32 n = (u32)w / 384u, k = (u32)w % 384u;
            Wt[w] = f2b(Wpt[k * 384 + n]);
        }
    }
}

// ---------------------------------------------------------------- k_preM
// grid (626, 3), block 256 = 4 waves. Wave wv computes rows r0..r0+15 x cols wv*96..wv*96+95
// of dst = A @ Wpt[koff:koff+128, :], A = ENb (which<2) or EPb (which==2).
// MFMA 16x16x32 bf16; frag layouts per guide (m89/m118-verified):
//   A: m=lane&15, k=quad*8+j ; B: n=lane&15, k=quad*8+j ; C/D: col=lane&15, row=quad*4+reg.
__global__ void k_preM(const u16* __restrict__ ENb, const u16* __restrict__ EPb,
                       const u16* __restrict__ Wt, const float* __restrict__ bpt,
                       u16* __restrict__ PS, u16* __restrict__ PE, u16* __restrict__ PP) {
    int which = blockIdx.y;
    int r0 = blockIdx.x * 16;
    int wv = threadIdx.x >> 6, lane = threadIdx.x & 63;
    int m = lane & 15, quad = lane >> 4;
    const u16* A = (which == 2) ? EPb : ENb;
    int koff = which * 128;
    u16* dst = (which == 0) ? PS : (which == 1) ? PE : PP;

    // A fragments for K=128 (4 chunks of 32). 16B contiguous loads.
    const short8* ap = (const short8*)(A + (r0 + m) * 128 + quad * 8);
    short8 a0 = ap[0], a1 = ap[4], a2 = ap[8], a3 = ap[12];   // kc*32 elems = kc*4 frags

    for (int nt = 0; nt < 6; nt++) {
        int n0 = wv * 96 + nt * 16;
        const short8* bp = (const short8*)(Wt + (n0 + m) * 384 + koff + quad * 8);
        f32x4 acc = {0.f, 0.f, 0.f, 0.f};
        acc = __builtin_amdgcn_mfma_f32_16x16x32_bf16(a0, bp[0],  acc, 0, 0, 0);
        acc = __builtin_amdgcn_mfma_f32_16x16x32_bf16(a1, bp[4],  acc, 0, 0, 0);
        acc = __builtin_amdgcn_mfma_f32_16x16x32_bf16(a2, bp[8],  acc, 0, 0, 0);
        acc = __builtin_amdgcn_mfma_f32_16x16x32_bf16(a3, bp[12], acc, 0, 0, 0);
        int col = n0 + m;
        float bias = (which == 2) ? bpt[col] : 0.f;
#pragma unroll
        for (int reg = 0; reg < 4; reg++) {
            int row = r0 + quad * 4 + reg;
            if (row < 10002) dst[row * 384 + col] = f2b(acc[reg] + bias);
        }
    }
}

// ---------------------------------------------------------------- k_cw
// grid 16384, block 256 (4 waves). Each wave: 4 consecutive-p triples of one (b,l).
// Planar u32 gathers (3 planes x 3 tables x 4 triples = 36 loads issued up-front).
__global__ void k_cw(const int* __restrict__ code,
                     const u16* __restrict__ PS, const u16* __restrict__ PE,
                     const u16* __restrict__ PP, const float* __restrict__ Watt,
                     const float* __restrict__ batt, float* __restrict__ cw) {
    int wv = threadIdx.x >> 6, lane = threadIdx.x & 63;
    int t0 = (blockIdx.x * 4 + wv) * 4;        // first triple; [0, B*L*P)
    int b = t0 >> 14;
    int rem = t0 & 16383;
    int l = rem >> 7, p0 = rem & 127;

    const int* c = code + ((b * 128 + l) * 584 + 200 + 3 * p0);
    int si[4], pi[4], ei[4];
#pragma unroll
    for (int i = 0; i < 4; i++) {
        si[i] = __builtin_amdgcn_readfirstlane(c[3 * i]);
        pi[i] = __builtin_amdgcn_readfirstlane(c[3 * i + 1]);
        ei[i] = __builtin_amdgcn_readfirstlane(c[3 * i + 2]);
    }

    // Watt cols 2*(pl*64+lane), +1
    float2 wat0 = ((const float2*)Watt)[lane];
    float2 wat1 = ((const float2*)Watt)[64 + lane];
    float2 wat2 = ((const float2*)Watt)[128 + lane];

    u32 US[4][3], UE[4][3], UP[4][3];
#pragma unroll
    for (int i = 0; i < 4; i++) {
        const u32* ps = (const u32*)(PS + si[i] * 384);
        const u32* pe = (const u32*)(PE + ei[i] * 384);
        const u32* pp = (const u32*)(PP + pi[i] * 384);
#pragma unroll
        for (int pl = 0; pl < 3; pl++) {
            US[i][pl] = ps[pl * 64 + lane];
            UE[i][pl] = pe[pl * 64 + lane];
            UP[i][pl] = pp[pl * 64 + lane];
        }
    }

    float batt0 = batt[0];
#pragma unroll
    for (int i = 0; i < 4; i++) {
        float acc = 0.f;
#pragma unroll
        for (int pl = 0; pl < 3; pl++) {
            float zl = lo16(US[i][pl]) + lo16(UE[i][pl]) + lo16(UP[i][pl]);
            float zh = hi16(US[i][pl]) + hi16(UE[i][pl]) + hi16(UP[i][pl]);
            float2 w2 = (pl == 0) ? wat0 : (pl == 1) ? wat1 : wat2;
            acc = fmaf(fast_tanh(zl), w2.x, acc);
            acc = fmaf(fast_tanh(zh), w2.y, acc);
        }
#pragma unroll
        for (int off = 32; off; off >>= 1) acc += __shfl_down(acc, off, 64);
        if (lane == 0) cw[(b * 128 + p0 + i) * 128 + l] = acc + batt0;
    }
}

// ---------------------------------------------------------------- k_sm
// grid 2048 = (b,p), block 128 = l. Softmax over l, store attn as [b][l][p].
__global__ void k_sm(const float* __restrict__ cw, float* __restrict__ attn) {
    int g = blockIdx.x;                        // b*128 + p
    int l = threadIdx.x;
    float x = cw[g * 128 + l];
    __shared__ float red[128];
    red[l] = x; __syncthreads();
    for (int s = 64; s; s >>= 1) { if (l < s) red[l] = fmaxf(red[l], red[l + s]); __syncthreads(); }
    float mx = red[0]; __syncthreads();
    float ex = __expf(x - mx);
    red[l] = ex; __syncthreads();
    for (int s = 64; s; s >>= 1) { if (l < s) red[l] += red[l + s]; __syncthreads(); }
    float inv = 1.f / red[0];
    int b = g >> 7, p = g & 127;
    attn[(b * 128 + l) * 128 + p] = ex * inv;
}

// ---------------------------------------------------------------- k_cv
// grid 2048 = (b,l), block 256 = 4 waves. Wave wv handles p = wv, wv+4, ... (2x unrolled);
// lane covers 2 cols via u32 bf16-pair loads. LDS combine of 4 partials.
__global__ void k_cv(const int* __restrict__ code, const float* __restrict__ attn,
                     const u16* __restrict__ ENb, const u16* __restrict__ EPb,
                     float* __restrict__ code_vec) {
    int row = blockIdx.x;                      // b*L + l
    int tid = threadIdx.x;
    int wv = tid >> 6, lane = tid & 63;
    __shared__ int si[128], ei[128], pi[128];
    __shared__ float at[128];
    __shared__ float part[4][3][128];
    if (tid < 128) {
        const int* c = code + (row * 584 + 200);
        si[tid] = c[3 * tid]; pi[tid] = c[3 * tid + 1]; ei[tid] = c[3 * tid + 2];
        at[tid] = attn[row * 128 + tid];
    }
    __syncthreads();
    float a0 = 0.f, a1 = 0.f, b0 = 0.f, b1 = 0.f, c0 = 0.f, c1 = 0.f;
    for (int p = wv; p < 128; p += 8) {
        int p2 = p + 4;
        float w = at[p], w2 = at[p2];
        u32 us = ((const u32*)(ENb + si[p] * 128))[lane];
        u32 ue = ((const u32*)(ENb + ei[p] * 128))[lane];
        u32 up = ((const u32*)(EPb + pi[p] * 128))[lane];
        u32 vs = ((const u32*)(ENb + si[p2] * 128))[lane];
        u32 ve = ((const u32*)(ENb + ei[p2] * 128))[lane];
        u32 vp = ((const u32*)(EPb + pi[p2] * 128))[lane];
        a0 = fmaf(w, lo16(us), a0); a1 = fmaf(w, hi16(us), a1);
        b0 = fmaf(w, lo16(ue), b0); b1 = fmaf(w, hi16(ue), b1);
        c0 = fmaf(w, lo16(up), c0); c1 = fmaf(w, hi16(up), c1);
        a0 = fmaf(w2, lo16(vs), a0); a1 = fmaf(w2, hi16(vs), a1);
        b0 = fmaf(w2, lo16(ve), b0); b1 = fmaf(w2, hi16(ve), b1);
        c0 = fmaf(w2, lo16(vp), c0); c1 = fmaf(w2, hi16(vp), c1);
    }
    part[wv][0][2 * lane] = a0; part[wv][0][2 * lane + 1] = a1;
    part[wv][1][2 * lane] = b0; part[wv][1][2 * lane + 1] = b1;
    part[wv][2][2 * lane] = c0; part[wv][2][2 * lane + 1] = c1;
    __syncthreads();
    float* out = code_vec + row * 384;
    for (int idx = tid; idx < 384; idx += 256) {
        int tbl = idx >> 7, col = idx & 127;
        out[idx] = part[0][tbl][col] + part[1][tbl][col] + part[2][tbl][col] + part[3][tbl][col];
    }
}

// ---------------------------------------------------------------- k_eaw
// grid 256 (8 rows each), block 256. threads 0-127: e, 128-255: a. Then w-softmax.
__global__ void k_eaw(const int* __restrict__ rr, const int* __restrict__ qq,
                      const float* __restrict__ Vemb, const float* __restrict__ code_vec,
                      const float* __restrict__ Kemb,
                      const float* __restrict__ We, const float* __restrict__ be,
                      const float* __restrict__ Wa, const float* __restrict__ ba,
                      const float* __restrict__ Mk,
                      float* __restrict__ eb, float* __restrict__ ab, float* __restrict__ wb) {
    int r0 = blockIdx.x * 8;
    int tid = threadIdx.x;
    __shared__ float v[8][512];
    __shared__ float kv[8][128];

    for (int idx = tid; idx < 8 * 512; idx += 256) {
        int r = idx >> 9, kk = idx & 511;
        int row = r0 + r;
        v[r][kk] = (kk < 128) ? Vemb[rr[row] * 128 + kk]
                              : code_vec[row * 384 + (kk - 128)];
    }
    for (int idx = tid; idx < 8 * 128; idx += 256) {
        int r = idx >> 7, kk = idx & 127;
        kv[r][kk] = Kemb[qq[r0 + r] * 128 + kk];
    }
    __syncthreads();

    int d = tid & 127;
    bool doA = tid >= 128;
    const float* W = doA ? Wa : We;
    float bias = (doA ? ba : be)[d];
    float acc[8];
#pragma unroll
    for (int r = 0; r < 8; r++) acc[r] = 0.f;
    for (int kk = 0; kk < 512; kk++) {
        float wv = W[kk * 128 + d];
#pragma unroll
        for (int r = 0; r < 8; r++) acc[r] = fmaf(v[r][kk], wv, acc[r]);
    }
    for (int r = 0; r < 8; r++) {
        float val = acc[r] + bias;
        float res = doA ? fast_tanh(val) : sigmoidf_(val);
        (doA ? ab : eb)[(r0 + r) * 128 + d] = res;
    }

    // w = softmax(k @ Mk^T): lane = m, wave handles rows half, half+4
    int m = tid & 63, half = tid >> 6;
    for (int r2 = half; r2 < 8; r2 += 4) {
        float lg = 0.f;
        for (int kk = 0; kk < 128; kk++) lg = fmaf(kv[r2][kk], Mk[m * 128 + kk], lg);
        float mx = lg;
#pragma unroll
        for (int off = 32; off; off >>= 1) mx = fmaxf(mx, __shfl_xor(mx, off, 64));
        float ex = __expf(lg - mx);
        float sum = ex;
#pragma unroll
        for (int off = 32; off; off >>= 1) sum += __shfl_xor(sum, off, 64);
        wb[(r0 + r2) * 64 + m] = ex / sum;
    }
}

// ---------------------------------------------------------------- k_scan
// grid 256 = b(16) x dblk(16), block 64. 8-way m-split: lane = s*8 + dlo;
// d = dblk*8+dlo; lane owns m = s*8 + q (q<8). Reduce over s via shfl_xor.
__global__ void k_scan(const float* __restrict__ Mv0, const float* __restrict__ eb,
                       const float* __restrict__ ab, const float* __restrict__ wb,
                       float* __restrict__ readb) {
    int b = blockIdx.x >> 4, dblk = blockIdx.x & 15;
    int lane = threadIdx.x;
    int s = lane >> 3, dlo = lane & 7;
    int d = dblk * 8 + dlo;

    float mv[8];
#pragma unroll
    for (int q = 0; q < 8; q++) mv[q] = Mv0[(s * 8 + q) * 128 + d];

    const float* ebp = eb + b * 128 * 128 + d;
    const float* abp = ab + b * 128 * 128 + d;
    const float4* wbp = (const float4*)wb + (b * 128) * 16 + s * 2;
    float* rout = readb + b * 128 * 128 + d;

    float ecur = ebp[0], acur = abp[0];
    float4 w0 = wbp[0], w1 = wbp[1];

    for (int t = 0; t < 128; t++) {
        int tn = (t < 127) ? t + 1 : 127;
        float en = ebp[tn * 128], an = abp[tn * 128];
        float4 nw0 = wbp[tn * 16], nw1 = wbp[tn * 16 + 1];

        float w[8] = { w0.x, w0.y, w0.z, w0.w, w1.x, w1.y, w1.z, w1.w };
        float rd = 0.f;
#pragma unroll
        for (int q = 0; q < 8; q++) {
            rd = fmaf(w[q], mv[q], rd);
            mv[q] = fmaf(w[q], fmaf(-mv[q], ecur, acur), mv[q]);
        }
        rd += __shfl_xor(rd, 8, 64);
        rd += __shfl_xor(rd, 16, 64);
        rd += __shfl_xor(rd, 32, 64);
        if (s == 0) rout[t * 128] = rd;

        ecur = en; acur = an; w0 = nw0; w1 = nw1;
    }
}

// ---------------------------------------------------------------- k_out
// grid 256 (8 rows), block 128. f = tanh([read,k]@W_f+b_f); out = sigmoid(f@W_p+b_p)
__global__ void k_out(const int* __restrict__ qq, const float* __restrict__ Kemb,
                      const float* __restrict__ readb,
                      const float* __restrict__ Wf, const float* __restrict__ bfp,
                      const float* __restrict__ Wp, const float* __restrict__ bp,
                      float* __restrict__ out) {
    int r0 = blockIdx.x * 8;
    int tid = threadIdx.x;
    __shared__ float c[8][256];
    __shared__ float fs[8][128];
    for (int idx = tid; idx < 8 * 256; idx += 128) {
        int r = idx >> 8, kk = idx & 255;
        int row = r0 + r;
        c[r][kk] = (kk < 128) ? readb[row * 128 + kk]
                              : Kemb[qq[row] * 128 + (kk - 128)];
    }
    __syncthreads();
    int d = tid;
    float acc[8];
#pragma unroll
    for (int r = 0; r < 8; r++) acc[r] = 0.f;
    for (int kk = 0; kk < 256; kk++) {
        float wv = Wf[kk * 128 + d];
#pragma unroll
        for (int r = 0; r < 8; r++) acc[r] = fmaf(c[r][kk], wv, acc[r]);
    }
    float bias = bfp[d];
#pragma unroll
    for (int r = 0; r < 8; r++) fs[r][d] = fast_tanh(acc[r] + bias);
    __syncthreads();
    if (tid < 80) {
        int r = tid / 10, j = tid % 10;
        float a2 = 0.f;
        for (int dd = 0; dd < 128; dd++) a2 = fmaf(fs[r][dd], Wp[dd * 10 + j], a2);
        out[(r0 + r) * 10 + j] = sigmoidf_(a2 + bp[j]);
    }
}

extern "C" void kernel_launch(void* const* d_in, const int* in_sizes, int n_in,
                              void* d_out, int out_size, void* d_ws, size_t ws_size,
                              hipStream_t stream) {
    const int*   code = (const int*)d_in[0];
    const int*   q    = (const int*)d_in[1];
    const int*   r    = (const int*)d_in[2];
    const float* EN   = (const float*)d_in[3];
    const float* EP   = (const float*)d_in[4];
    const float* Wpt  = (const float*)d_in[5];
    const float* bpt  = (const float*)d_in[6];
    const float* Watt = (const float*)d_in[7];
    const float* batt = (const float*)d_in[8];
    const float* Kemb = (const float*)d_in[9];
    const float* Mk   = (const float*)d_in[10];
    const float* Mv0  = (const float*)d_in[11];
    const float* Vemb = (const float*)d_in[12];
    const float* We   = (const float*)d_in[13];
    const float* be   = (const float*)d_in[14];
    const float* Wa   = (const float*)d_in[15];
    const float* ba   = (const float*)d_in[16];
    const float* Wf   = (const float*)d_in[17];
    const float* bf_  = (const float*)d_in[18];
    const float* Wp   = (const float*)d_in[19];
    const float* bp   = (const float*)d_in[20];

    char* ws = (char*)d_ws;
    size_t off = 0;
    auto alloc = [&](size_t bytes) { void* p = ws + off; off = (off + bytes + 255) & ~255UL; return p; };
    u16*   PS    = (u16*)alloc(10002UL * 384 * 2);
    u16*   PE    = (u16*)alloc(10002UL * 384 * 2);
    u16*   PP    = (u16*)alloc(10002UL * 384 * 2);
    u16*   ENb   = (u16*)alloc(10002UL * 128 * 2);
    u16*   EPb   = (u16*)alloc(10016UL * 128 * 2);   // +14 rows pad: k_preM tail reads
    u16*   Wt    = (u16*)alloc(384UL * 384 * 2);
    float* cw    = (float*)alloc(16UL * 128 * 128 * 4);   // [b][p][l]
    float* attn  = (float*)alloc(16UL * 128 * 128 * 4);   // [b][l][p]
    float* cvec  = (float*)alloc(16UL * 128 * 384 * 4);
    float* eb    = (float*)alloc(16UL * 128 * 128 * 4);
    float* ab    = (float*)alloc(16UL * 128 * 128 * 4);
    float* wb    = (float*)alloc(16UL * 128 * 64 * 4);
    float* readb = (float*)alloc(16UL * 128 * 128 * 4);

    k_conv<<<2048, 256, 0, stream>>>(EN, EP, Wpt, ENb, EPb, Wt);
    k_preM<<<dim3(626, 3), 256, 0, stream>>>(ENb, EPb, Wt, bpt, PS, PE, PP);
    k_cw<<<16384, 256, 0, stream>>>(code, PS, PE, PP, Watt, batt, cw);
    k_sm<<<2048, 128, 0, stream>>>(cw, attn);
    k_cv<<<2048, 256, 0, stream>>>(code, attn, ENb, EPb, cvec);
    k_eaw<<<256, 256, 0, stream>>>(r, q, Vemb, cvec, Kemb, We, be, Wa, ba, Mk, eb, ab, wb);
    k_scan<<<256, 64, 0, stream>>>(Mv0, eb, ab, wb, readb);
    k_out<<<256, 128, 0, stream>>>(q, Kemb, readb, Wf, bf_, Wp, bp, (float*)d_out);
}

// Round 5
// 328.682 us; speedup vs baseline: 2.1917x; 1.0586x over previous
//
#include <hip/hip_runtime.h>

// DKVMN + code2vec attention. Sizes (fixed):
// B=16 L=128 P=128 NUM_C=100 D=128 M=64 EMB=128 TE=384 CODE_W=584 NROW=10002
//
// Inputs/outputs f32. Internal tables bf16. All transcendentals via native
// v_exp_f32 / v_rcp_f32 builtins (OCML expansions were 3-4x VALU bloat).
//
//  k_conv : bf16 copies ENb/EPb of embed tables + transposed bf16 Wt[n][k]=Wpt[k][n]
//  k_preM : PS/PE/PP = emb @ Wpt slices via MFMA 16x16x32 bf16 (factorized full@W_pt)
//  k_cw   : cw[b,p,l] = tanh(PS[s]+PE[e]+PP[pa]) . W_att + b_att  (4 triples/wave)
//  k_sm   : softmax over l (axis=1!) per (b,p); attn stored [b,l,p]
//  k_cv   : code_vec[b,l,:] = sum_p attn * [EN[s];EN[e];EP[pa]]  (bf16 gathers)
//  k_eaw  : e = sigmoid(v@W_e), a = tanh(v@W_a), w = softmax(k@Mk^T)
//  k_scan : sequential memory scan, 8-way m-split, 256 blocks
//  k_out  : f = tanh([read,k]@W_f), out = sigmoid(f@W_p)

typedef unsigned short u16;
typedef unsigned int u32;
typedef __attribute__((ext_vector_type(8))) short short8;   // 8 bf16 (4 VGPRs)
typedef __attribute__((ext_vector_type(4))) float f32x4;    // MFMA C/D

#define DEV __device__ __forceinline__
#define LOG2E 1.4426950408889634f

DEV float b2f(u16 u) { union { u32 i; float f; } v; v.i = ((u32)u) << 16; return v.f; }
DEV float lo16(u32 u) { union { u32 i; float f; } v; v.i = u << 16; return v.f; }
DEV float hi16(u32 u) { union { u32 i; float f; } v; v.i = u & 0xFFFF0000u; return v.f; }
DEV u16 f2b(float f) {
    union { float f; u32 i; } v; v.f = f;
    u32 x = v.i;
    u32 r = (x + 0x7FFFu + ((x >> 16) & 1u)) >> 16;   // RNE
    return (u16)r;
}
DEV float nexp(float x) { return __builtin_amdgcn_exp2f(x * LOG2E); }   // e^x, 2 inst
DEV float nrcp(float x) { return __builtin_amdgcn_rcpf(x); }            // 1/x, 1 inst
// tanh(x) = 1 - 2/(1+e^{2x}); exact at +/-inf (exp2->inf => rcp->0 => 1; exp2->0 => -1).
DEV float fast_tanh(float x) {
    return 1.f - 2.f * nrcp(1.f + __builtin_amdgcn_exp2f(x * (2.f * LOG2E)));
}
DEV float sigmoidf_(float x) { return nrcp(1.f + __builtin_amdgcn_exp2f(-x * LOG2E)); }

// ---------------------------------------------------------------- k_conv
// Flat grid-stride: ENb (1280256), EPb (1280256), Wt (147456: Wt[n*384+k]=Wpt[k*384+n]).
__global__ void k_conv(const float* __restrict__ EN, const float* __restrict__ EP,
                       const float* __restrict__ Wpt,
                       u16* __restrict__ ENb, u16* __restrict__ EPb, u16* __restrict__ Wt) {
    const int NE = 10002 * 128;
    int total = NE * 2 + 147456;
    for (int i = blockIdx.x * blockDim.x + threadIdx.x; i < total; i += gridDim.x * blockDim.x) {
        if (i < NE) {
            ENb[i] = f2b(EN[i]);
        } else if (i < 2 * NE) {
            EPb[i - NE] = f2b(EP[i - NE]);
        } else {
            int w = i - 2 * NE;              // n*384 + k
            u32 n = (u32)w / 384u, k = (u32)w % 384u;
            Wt[w] = f2b(Wpt[k * 384 + n]);
        }
    }
}

// ---------------------------------------------------------------- k_preM
// grid (626, 3), block 256 = 4 waves. Wave wv: rows r0..r0+15 x cols wv*96..+95 of
// dst = A @ Wpt[koff:koff+128, :]. MFMA 16x16x32 bf16, verified layouts:
//   A: m=lane&15, k=quad*8+j ; B: n=lane&15, k=quad*8+j ; C/D: col=lane&15, row=quad*4+reg.
__global__ void k_preM(const u16* __restrict__ ENb, const u16* __restrict__ EPb,
                       const u16* __restrict__ Wt, const float* __restrict__ bpt,
                       u16* __restrict__ PS, u16* __restrict__ PE, u16* __restrict__ PP) {
    int which = blockIdx.y;
    int r0 = blockIdx.x * 16;
    int wv = threadIdx.x >> 6, lane = threadIdx.x & 63;
    int m = lane & 15, quad = lane >> 4;
    const u16* A = (which == 2) ? EPb : ENb;
    int koff = which * 128;
    u16* dst = (which == 0) ? PS : (which == 1) ? PE : PP;

    const short8* ap = (const short8*)(A + (r0 + m) * 128 + quad * 8);
    short8 a0 = ap[0], a1 = ap[4], a2 = ap[8], a3 = ap[12];

    for (int nt = 0; nt < 6; nt++) {
        int n0 = wv * 96 + nt * 16;
        const short8* bp = (const short8*)(Wt + (n0 + m) * 384 + koff + quad * 8);
        f32x4 acc = {0.f, 0.f, 0.f, 0.f};
        acc = __builtin_amdgcn_mfma_f32_16x16x32_bf16(a0, bp[0],  acc, 0, 0, 0);
        acc = __builtin_amdgcn_mfma_f32_16x16x32_bf16(a1, bp[4],  acc, 0, 0, 0);
        acc = __builtin_amdgcn_mfma_f32_16x16x32_bf16(a2, bp[8],  acc, 0, 0, 0);
        acc = __builtin_amdgcn_mfma_f32_16x16x32_bf16(a3, bp[12], acc, 0, 0, 0);
        int col = n0 + m;
        float bias = (which == 2) ? bpt[col] : 0.f;
#pragma unroll
        for (int reg = 0; reg < 4; reg++) {
            int row = r0 + quad * 4 + reg;
            if (row < 10002) dst[row * 384 + col] = f2b(acc[reg] + bias);
        }
    }
}

// ---------------------------------------------------------------- k_cw
// grid 16384, block 256 (4 waves). Each wave: 4 consecutive-p triples of one (b,l).
__global__ void k_cw(const int* __restrict__ code,
                     const u16* __restrict__ PS, const u16* __restrict__ PE,
                     const u16* __restrict__ PP, const float* __restrict__ Watt,
                     const float* __restrict__ batt, float* __restrict__ cw) {
    int wv = threadIdx.x >> 6, lane = threadIdx.x & 63;
    int t0 = (blockIdx.x * 4 + wv) * 4;        // first triple; [0, B*L*P)
    int b = t0 >> 14;
    int rem = t0 & 16383;
    int l = rem >> 7, p0 = rem & 127;

    const int* c = code + ((b * 128 + l) * 584 + 200 + 3 * p0);
    int si[4], pi[4], ei[4];
#pragma unroll
    for (int i = 0; i < 4; i++) {
        si[i] = __builtin_amdgcn_readfirstlane(c[3 * i]);
        pi[i] = __builtin_amdgcn_readfirstlane(c[3 * i + 1]);
        ei[i] = __builtin_amdgcn_readfirstlane(c[3 * i + 2]);
    }

    float2 wat0 = ((const float2*)Watt)[lane];
    float2 wat1 = ((const float2*)Watt)[64 + lane];
    float2 wat2 = ((const float2*)Watt)[128 + lane];

    float batt0 = batt[0];
#pragma unroll
    for (int i = 0; i < 4; i++) {
        const u32* ps = (const u32*)(PS + si[i] * 384);
        const u32* pe = (const u32*)(PE + ei[i] * 384);
        const u32* pp = (const u32*)(PP + pi[i] * 384);
        u32 s0 = ps[lane], s1 = ps[64 + lane], s2 = ps[128 + lane];
        u32 e0 = pe[lane], e1 = pe[64 + lane], e2 = pe[128 + lane];
        u32 q0 = pp[lane], q1 = pp[64 + lane], q2 = pp[128 + lane];

        float acc = 0.f;
        acc = fmaf(fast_tanh(lo16(s0) + lo16(e0) + lo16(q0)), wat0.x, acc);
        acc = fmaf(fast_tanh(hi16(s0) + hi16(e0) + hi16(q0)), wat0.y, acc);
        acc = fmaf(fast_tanh(lo16(s1) + lo16(e1) + lo16(q1)), wat1.x, acc);
        acc = fmaf(fast_tanh(hi16(s1) + hi16(e1) + hi16(q1)), wat1.y, acc);
        acc = fmaf(fast_tanh(lo16(s2) + lo16(e2) + lo16(q2)), wat2.x, acc);
        acc = fmaf(fast_tanh(hi16(s2) + hi16(e2) + hi16(q2)), wat2.y, acc);

#pragma unroll
        for (int off = 32; off; off >>= 1) acc += __shfl_down(acc, off, 64);
        if (lane == 0) cw[(b * 128 + p0 + i) * 128 + l] = acc + batt0;
    }
}

// ---------------------------------------------------------------- k_sm
// grid 2048 = (b,p), block 128 = 2 waves. Softmax over l, attn stored [b][l][p].
__global__ void k_sm(const float* __restrict__ cw, float* __restrict__ attn) {
    int g = blockIdx.x;                        // b*128 + p
    int l = threadIdx.x;
    int lane = l & 63, wv = l >> 6;
    float x = cw[g * 128 + l];
    __shared__ float sm[2], ss[2];
    float mx = x;
#pragma unroll
    for (int off = 32; off; off >>= 1) mx = fmaxf(mx, __shfl_xor(mx, off, 64));
    if (lane == 0) sm[wv] = mx;
    __syncthreads();
    mx = fmaxf(sm[0], sm[1]);
    float ex = nexp(x - mx);
    float sum = ex;
#pragma unroll
    for (int off = 32; off; off >>= 1) sum += __shfl_xor(sum, off, 64);
    if (lane == 0) ss[wv] = sum;
    __syncthreads();
    float inv = nrcp(ss[0] + ss[1]);
    int b = g >> 7, p = g & 127;
    attn[(b * 128 + l) * 128 + p] = ex * inv;
}

// ---------------------------------------------------------------- k_cv
// grid 2048 = (b,l), block 256 = 4 waves. Wave wv handles p = wv, wv+4, ... (2x unrolled);
// lane covers 2 cols via u32 bf16-pair loads. LDS combine of 4 partials.
__global__ void k_cv(const int* __restrict__ code, const float* __restrict__ attn,
                     const u16* __restrict__ ENb, const u16* __restrict__ EPb,
                     float* __restrict__ code_vec) {
    int row = blockIdx.x;                      // b*L + l
    int tid = threadIdx.x;
    int wv = tid >> 6, lane = tid & 63;
    __shared__ int si[128], ei[128], pi[128];
    __shared__ float at[128];
    __shared__ float part[4][3][128];
    if (tid < 128) {
        const int* c = code + (row * 584 + 200);
        si[tid] = c[3 * tid]; pi[tid] = c[3 * tid + 1]; ei[tid] = c[3 * tid + 2];
        at[tid] = attn[row * 128 + tid];
    }
    __syncthreads();
    float a0 = 0.f, a1 = 0.f, b0 = 0.f, b1 = 0.f, c0 = 0.f, c1 = 0.f;
    for (int p = wv; p < 128; p += 8) {
        int p2 = p + 4;
        float w = at[p], w2 = at[p2];
        u32 us = ((const u32*)(ENb + si[p] * 128))[lane];
        u32 ue = ((const u32*)(ENb + ei[p] * 128))[lane];
        u32 up = ((const u32*)(EPb + pi[p] * 128))[lane];
        u32 vs = ((const u32*)(ENb + si[p2] * 128))[lane];
        u32 ve = ((const u32*)(ENb + ei[p2] * 128))[lane];
        u32 vp = ((const u32*)(EPb + pi[p2] * 128))[lane];
        a0 = fmaf(w, lo16(us), a0); a1 = fmaf(w, hi16(us), a1);
        b0 = fmaf(w, lo16(ue), b0); b1 = fmaf(w, hi16(ue), b1);
        c0 = fmaf(w, lo16(up), c0); c1 = fmaf(w, hi16(up), c1);
        a0 = fmaf(w2, lo16(vs), a0); a1 = fmaf(w2, hi16(vs), a1);
        b0 = fmaf(w2, lo16(ve), b0); b1 = fmaf(w2, hi16(ve), b1);
        c0 = fmaf(w2, lo16(vp), c0); c1 = fmaf(w2, hi16(vp), c1);
    }
    part[wv][0][2 * lane] = a0; part[wv][0][2 * lane + 1] = a1;
    part[wv][1][2 * lane] = b0; part[wv][1][2 * lane + 1] = b1;
    part[wv][2][2 * lane] = c0; part[wv][2][2 * lane + 1] = c1;
    __syncthreads();
    float* out = code_vec + row * 384;
    for (int idx = tid; idx < 384; idx += 256) {
        int tbl = idx >> 7, col = idx & 127;
        out[idx] = part[0][tbl][col] + part[1][tbl][col] + part[2][tbl][col] + part[3][tbl][col];
    }
}

// ---------------------------------------------------------------- k_eaw
// grid 256 (8 rows each), block 256. threads 0-127: e, 128-255: a. Then w-softmax.
// kk-loop unrolled x8 with batched loads (8 in flight before 64 FMAs).
__global__ void k_eaw(const int* __restrict__ rr, const int* __restrict__ qq,
                      const float* __restrict__ Vemb, const float* __restrict__ code_vec,
                      const float* __restrict__ Kemb,
                      const float* __restrict__ We, const float* __restrict__ be,
                      const float* __restrict__ Wa, const float* __restrict__ ba,
                      const float* __restrict__ Mk,
                      float* __restrict__ eb, float* __restrict__ ab, float* __restrict__ wb) {
    int r0 = blockIdx.x * 8;
    int tid = threadIdx.x;
    __shared__ float v[8][512];
    __shared__ float kv[8][128];

    for (int idx = tid; idx < 8 * 512; idx += 256) {
        int r = idx >> 9, kk = idx & 511;
        int row = r0 + r;
        v[r][kk] = (kk < 128) ? Vemb[rr[row] * 128 + kk]
                              : code_vec[row * 384 + (kk - 128)];
    }
    for (int idx = tid; idx < 8 * 128; idx += 256) {
        int r = idx >> 7, kk = idx & 127;
        kv[r][kk] = Kemb[qq[r0 + r] * 128 + kk];
    }
    __syncthreads();

    int d = tid & 127;
    bool doA = tid >= 128;
    const float* W = doA ? Wa : We;
    float bias = (doA ? ba : be)[d];
    float acc[8];
#pragma unroll
    for (int r = 0; r < 8; r++) acc[r] = 0.f;
    for (int kk = 0; kk < 512; kk += 8) {
        float wv8[8];
#pragma unroll
        for (int u = 0; u < 8; u++) wv8[u] = W[(kk + u) * 128 + d];
#pragma unroll
        for (int u = 0; u < 8; u++)
#pragma unroll
            for (int r = 0; r < 8; r++) acc[r] = fmaf(v[r][kk + u], wv8[u], acc[r]);
    }
    for (int r = 0; r < 8; r++) {
        float val = acc[r] + bias;
        float res = doA ? fast_tanh(val) : sigmoidf_(val);
        (doA ? ab : eb)[(r0 + r) * 128 + d] = res;
    }

    // w = softmax(k @ Mk^T): lane = m, wave handles rows half, half+4
    int m = tid & 63, half = tid >> 6;
    for (int r2 = half; r2 < 8; r2 += 4) {
        float lg = 0.f;
        for (int kk = 0; kk < 128; kk += 8) {
            float mk8[8];
#pragma unroll
            for (int u = 0; u < 8; u++) mk8[u] = Mk[m * 128 + kk + u];
#pragma unroll
            for (int u = 0; u < 8; u++) lg = fmaf(kv[r2][kk + u], mk8[u], lg);
        }
        float mx = lg;
#pragma unroll
        for (int off = 32; off; off >>= 1) mx = fmaxf(mx, __shfl_xor(mx, off, 64));
        float ex = nexp(lg - mx);
        float sum = ex;
#pragma unroll
        for (int off = 32; off; off >>= 1) sum += __shfl_xor(sum, off, 64);
        wb[(r0 + r2) * 64 + m] = ex * nrcp(sum);
    }
}

// ---------------------------------------------------------------- k_scan
// grid 256 = b(16) x dblk(16), block 64. 8-way m-split: lane = s*8 + dlo;
// d = dblk*8+dlo; lane owns m = s*8 + q (q<8). Reduce over s via shfl_xor.
__global__ void k_scan(const float* __restrict__ Mv0, const float* __restrict__ eb,
                       const float* __restrict__ ab, const float* __restrict__ wb,
                       float* __restrict__ readb) {
    int b = blockIdx.x >> 4, dblk = blockIdx.x & 15;
    int lane = threadIdx.x;
    int s = lane >> 3, dlo = lane & 7;
    int d = dblk * 8 + dlo;

    float mv[8];
#pragma unroll
    for (int q = 0; q < 8; q++) mv[q] = Mv0[(s * 8 + q) * 128 + d];

    const float* ebp = eb + b * 128 * 128 + d;
    const float* abp = ab + b * 128 * 128 + d;
    const float4* wbp = (const float4*)wb + (b * 128) * 16 + s * 2;
    float* rout = readb + b * 128 * 128 + d;

    float ecur = ebp[0], acur = abp[0];
    float4 w0 = wbp[0], w1 = wbp[1];

    for (int t = 0; t < 128; t++) {
        int tn = (t < 127) ? t + 1 : 127;
        float en = ebp[tn * 128], an = abp[tn * 128];
        float4 nw0 = wbp[tn * 16], nw1 = wbp[tn * 16 + 1];

        float w[8] = { w0.x, w0.y, w0.z, w0.w, w1.x, w1.y, w1.z, w1.w };
        float rd = 0.f;
#pragma unroll
        for (int q = 0; q < 8; q++) {
            rd = fmaf(w[q], mv[q], rd);
            mv[q] = fmaf(w[q], fmaf(-mv[q], ecur, acur), mv[q]);
        }
        rd += __shfl_xor(rd, 8, 64);
        rd += __shfl_xor(rd, 16, 64);
        rd += __shfl_xor(rd, 32, 64);
        if (s == 0) rout[t * 128] = rd;

        ecur = en; acur = an; w0 = nw0; w1 = nw1;
    }
}

// ---------------------------------------------------------------- k_out
// grid 256 (8 rows), block 128. f = tanh([read,k]@W_f+b_f); out = sigmoid(f@W_p+b_p)
__global__ void k_out(const int* __restrict__ qq, const float* __restrict__ Kemb,
                      const float* __restrict__ readb,
                      const float* __restrict__ Wf, const float* __restrict__ bfp,
                      const float* __restrict__ Wp, const float* __restrict__ bp,
                      float* __restrict__ out) {
    int r0 = blockIdx.x * 8;
    int tid = threadIdx.x;
    __shared__ float c[8][256];
    __shared__ float fs[8][128];
    for (int idx = tid; idx < 8 * 256; idx += 128) {
        int r = idx >> 8, kk = idx & 255;
        int row = r0 + r;
        c[r][kk] = (kk < 128) ? readb[row * 128 + kk]
                              : Kemb[qq[row] * 128 + (kk - 128)];
    }
    __syncthreads();
    int d = tid;
    float acc[8];
#pragma unroll
    for (int r = 0; r < 8; r++) acc[r] = 0.f;
    for (int kk = 0; kk < 256; kk += 8) {
        float wv8[8];
#pragma unroll
        for (int u = 0; u < 8; u++) wv8[u] = Wf[(kk + u) * 128 + d];
#pragma unroll
        for (int u = 0; u < 8; u++)
#pragma unroll
            for (int r = 0; r < 8; r++) acc[r] = fmaf(c[r][kk + u], wv8[u], acc[r]);
    }
    float bias = bfp[d];
#pragma unroll
    for (int r = 0; r < 8; r++) fs[r][d] = fast_tanh(acc[r] + bias);
    __syncthreads();
    if (tid < 80) {
        int r = tid / 10, j = tid % 10;
        float a2 = 0.f;
        for (int dd = 0; dd < 128; dd++) a2 = fmaf(fs[r][dd], Wp[dd * 10 + j], a2);
        out[(r0 + r) * 10 + j] = sigmoidf_(a2 + bp[j]);
    }
}

extern "C" void kernel_launch(void* const* d_in, const int* in_sizes, int n_in,
                              void* d_out, int out_size, void* d_ws, size_t ws_size,
                              hipStream_t stream) {
    const int*   code = (const int*)d_in[0];
    const int*   q    = (const int*)d_in[1];
    const int*   r    = (const int*)d_in[2];
    const float* EN   = (const float*)d_in[3];
    const float* EP   = (const float*)d_in[4];
    const float* Wpt  = (const float*)d_in[5];
    const float* bpt  = (const float*)d_in[6];
    const float* Watt = (const float*)d_in[7];
    const float* batt = (const float*)d_in[8];
    const float* Kemb = (const float*)d_in[9];
    const float* Mk   = (const float*)d_in[10];
    const float* Mv0  = (const float*)d_in[11];
    const float* Vemb = (const float*)d_in[12];
    const float* We   = (const float*)d_in[13];
    const float* be   = (const float*)d_in[14];
    const float* Wa   = (const float*)d_in[15];
    const float* ba   = (const float*)d_in[16];
    const float* Wf   = (const float*)d_in[17];
    const float* bf_  = (const float*)d_in[18];
    const float* Wp   = (const float*)d_in[19];
    const float* bp   = (const float*)d_in[20];

    char* ws = (char*)d_ws;
    size_t off = 0;
    auto alloc = [&](size_t bytes) { void* p = ws + off; off = (off + bytes + 255) & ~255UL; return p; };
    u16*   PS    = (u16*)alloc(10002UL * 384 * 2);
    u16*   PE    = (u16*)alloc(10002UL * 384 * 2);
    u16*   PP    = (u16*)alloc(10002UL * 384 * 2);
    u16*   ENb   = (u16*)alloc(10002UL * 128 * 2);
    u16*   EPb   = (u16*)alloc(10016UL * 128 * 2);   // +14 rows pad: k_preM tail reads
    u16*   Wt    = (u16*)alloc(384UL * 384 * 2);
    float* cw    = (float*)alloc(16UL * 128 * 128 * 4);   // [b][p][l]
    float* attn  = (float*)alloc(16UL * 128 * 128 * 4);   // [b][l][p]
    float* cvec  = (float*)alloc(16UL * 128 * 384 * 4);
    float* eb    = (float*)alloc(16UL * 128 * 128 * 4);
    float* ab    = (float*)alloc(16UL * 128 * 128 * 4);
    float* wb    = (float*)alloc(16UL * 128 * 64 * 4);
    float* readb = (float*)alloc(16UL * 128 * 128 * 4);

    k_conv<<<2048, 256, 0, stream>>>(EN, EP, Wpt, ENb, EPb, Wt);
    k_preM<<<dim3(626, 3), 256, 0, stream>>>(ENb, EPb, Wt, bpt, PS, PE, PP);
    k_cw<<<16384, 256, 0, stream>>>(code, PS, PE, PP, Watt, batt, cw);
    k_sm<<<2048, 128, 0, stream>>>(cw, attn);
    k_cv<<<2048, 256, 0, stream>>>(code, attn, ENb, EPb, cvec);
    k_eaw<<<256, 256, 0, stream>>>(r, q, Vemb, cvec, Kemb, We, be, Wa, ba, Mk, eb, ab, wb);
    k_scan<<<256, 64, 0, stream>>>(Mv0, eb, ab, wb, readb);
    k_out<<<256, 128, 0, stream>>>(q, Kemb, readb, Wf, bf_, Wp, bp, (float*)d_out);
}

// Round 6
// 282.899 us; speedup vs baseline: 2.5464x; 1.1618x over previous
//
#include <hip/hip_runtime.h>

// DKVMN + code2vec attention. Sizes (fixed):
// B=16 L=128 P=128 NUM_C=100 D=128 M=64 EMB=128 TE=384 CODE_W=584 NROW=10002
//
// Inputs/outputs f32. Internal tables/operands bf16. Native v_exp/v_rcp.
//
//  k_conv : bf16 ENb/EPb + transposed bf16 Wt (W_pt), WeaT (We|Wa), WfT, WpT
//  k_wsm  : wsmall[q][m] = softmax(k_emb[q] @ Mk^T) for 101 distinct q rows
//  k_preM : PS/PE/PP = emb @ Wpt slices via MFMA (factorized full@W_pt)
//  k_cw   : cw[b,p,l] = tanh(PS[s]+PE[e]+PP[pa]) . W_att + b_att
//  k_sm   : softmax over l per (b,p); LDS-transposed tile -> coalesced attn[b,l,p]
//  k_cv   : vA[row] = [Vemb[r] bf16 ; code_vec bf16]; fA[row][128:256] = Kemb[q] bf16
//  k_eawM : e|a = act(vA @ WeaT + b) via MFMA  [2048x512]@[512x256]
//  k_scan : sequential memory scan (w rows gathered from wsmall by q); read -> fA bf16
//  k_outM : f = tanh(fA @ WfT + b_f) -> gA bf16   [2048x256]@[256x128]
//  k_fin  : out = sigmoid(gA @ WpT + b_p)         [2048x128]@[128x16(10)]

typedef unsigned short u16;
typedef unsigned int u32;
typedef __attribute__((ext_vector_type(8))) short short8;   // 8 bf16 (4 VGPRs)
typedef __attribute__((ext_vector_type(4))) float f32x4;    // MFMA C/D

#define DEV __device__ __forceinline__
#define LOG2E 1.4426950408889634f

DEV float lo16(u32 u) { union { u32 i; float f; } v; v.i = u << 16; return v.f; }
DEV float hi16(u32 u) { union { u32 i; float f; } v; v.i = u & 0xFFFF0000u; return v.f; }
DEV u16 f2b(float f) {
    union { float f; u32 i; } v; v.f = f;
    u32 x = v.i;
    u32 r = (x + 0x7FFFu + ((x >> 16) & 1u)) >> 16;   // RNE
    return (u16)r;
}
DEV float nexp(float x) { return __builtin_amdgcn_exp2f(x * LOG2E); }
DEV float nrcp(float x) { return __builtin_amdgcn_rcpf(x); }
DEV float fast_tanh(float x) {
    return 1.f - 2.f * nrcp(1.f + __builtin_amdgcn_exp2f(x * (2.f * LOG2E)));
}
DEV float sigmoidf_(float x) { return nrcp(1.f + __builtin_amdgcn_exp2f(-x * LOG2E)); }

// ---------------------------------------------------------------- k_conv
// Grid-stride over: ENb | EPb | Wt[n*384+k]=Wpt[k*384+n] | WeaT[n*512+k]=(We|Wa)[k][n]
//                   | WfT[n*256+k]=Wf[k][n] | WpT[n*128+k]=(n<10?Wp[k][n]:0)
__global__ void k_conv(const float* __restrict__ EN, const float* __restrict__ EP,
                       const float* __restrict__ Wpt, const float* __restrict__ We,
                       const float* __restrict__ Wa, const float* __restrict__ Wf,
                       const float* __restrict__ Wp,
                       u16* __restrict__ ENb, u16* __restrict__ EPb, u16* __restrict__ Wt,
                       u16* __restrict__ WeaT, u16* __restrict__ WfT, u16* __restrict__ WpT) {
    const int NE = 10002 * 128;
    const int T0 = 2 * NE;             // end EPb
    const int T1 = T0 + 147456;        // end Wt
    const int T2 = T1 + 131072;        // end WeaT
    const int T3 = T2 + 32768;         // end WfT
    const int T4 = T3 + 2048;          // end WpT
    for (int i = blockIdx.x * blockDim.x + threadIdx.x; i < T4; i += gridDim.x * blockDim.x) {
        if (i < NE) {
            ENb[i] = f2b(EN[i]);
        } else if (i < T0) {
            EPb[i - NE] = f2b(EP[i - NE]);
        } else if (i < T1) {
            int w = i - T0;  u32 n = (u32)w / 384u, k = (u32)w % 384u;
            Wt[w] = f2b(Wpt[k * 384 + n]);
        } else if (i < T2) {
            int w = i - T1;  int n = w >> 9, k = w & 511;
            WeaT[w] = f2b((n < 128) ? We[k * 128 + n] : Wa[k * 128 + (n - 128)]);
        } else if (i < T3) {
            int w = i - T2;  int n = w >> 8, k = w & 255;
            WfT[w] = f2b(Wf[k * 128 + n]);
        } else {
            int w = i - T3;  int n = w >> 7, k = w & 127;
            WpT[w] = (n < 10) ? f2b(Wp[k * 10 + n]) : (u16)0;
        }
    }
}

// ---------------------------------------------------------------- k_wsm
// grid 101, block 64. wsmall[row][m] = softmax_m(Kemb[row] . Mk[m]).
__global__ void k_wsm(const float* __restrict__ Kemb, const float* __restrict__ Mk,
                      float* __restrict__ wsmall) {
    int row = blockIdx.x;
    int m = threadIdx.x;
    __shared__ float kr[128];
    kr[m] = Kemb[row * 128 + m];
    kr[64 + m] = Kemb[row * 128 + 64 + m];
    __syncthreads();
    float lg = 0.f;
    for (int k = 0; k < 128; k += 8) {
        float mk8[8];
#pragma unroll
        for (int u = 0; u < 8; u++) mk8[u] = Mk[m * 128 + k + u];
#pragma unroll
        for (int u = 0; u < 8; u++) lg = fmaf(kr[k + u], mk8[u], lg);
    }
    float mx = lg;
#pragma unroll
    for (int off = 32; off; off >>= 1) mx = fmaxf(mx, __shfl_xor(mx, off, 64));
    float ex = nexp(lg - mx);
    float sum = ex;
#pragma unroll
    for (int off = 32; off; off >>= 1) sum += __shfl_xor(sum, off, 64);
    wsmall[row * 64 + m] = ex * nrcp(sum);
}

// ---------------------------------------------------------------- k_preM
// grid (626, 3), block 256 = 4 waves. MFMA 16x16x32 bf16 (layouts verified rounds 4-5).
__global__ void k_preM(const u16* __restrict__ ENb, const u16* __restrict__ EPb,
                       const u16* __restrict__ Wt, const float* __restrict__ bpt,
                       u16* __restrict__ PS, u16* __restrict__ PE, u16* __restrict__ PP) {
    int which = blockIdx.y;
    int r0 = blockIdx.x * 16;
    int wv = threadIdx.x >> 6, lane = threadIdx.x & 63;
    int m = lane & 15, quad = lane >> 4;
    const u16* A = (which == 2) ? EPb : ENb;
    int koff = which * 128;
    u16* dst = (which == 0) ? PS : (which == 1) ? PE : PP;

    const short8* ap = (const short8*)(A + (r0 + m) * 128 + quad * 8);
    short8 a0 = ap[0], a1 = ap[4], a2 = ap[8], a3 = ap[12];

    for (int nt = 0; nt < 6; nt++) {
        int n0 = wv * 96 + nt * 16;
        const short8* bp = (const short8*)(Wt + (n0 + m) * 384 + koff + quad * 8);
        f32x4 acc = {0.f, 0.f, 0.f, 0.f};
        acc = __builtin_amdgcn_mfma_f32_16x16x32_bf16(a0, bp[0],  acc, 0, 0, 0);
        acc = __builtin_amdgcn_mfma_f32_16x16x32_bf16(a1, bp[4],  acc, 0, 0, 0);
        acc = __builtin_amdgcn_mfma_f32_16x16x32_bf16(a2, bp[8],  acc, 0, 0, 0);
        acc = __builtin_amdgcn_mfma_f32_16x16x32_bf16(a3, bp[12], acc, 0, 0, 0);
        int col = n0 + m;
        float bias = (which == 2) ? bpt[col] : 0.f;
#pragma unroll
        for (int reg = 0; reg < 4; reg++) {
            int row = r0 + quad * 4 + reg;
            if (row < 10002) dst[row * 384 + col] = f2b(acc[reg] + bias);
        }
    }
}

// ---------------------------------------------------------------- k_cw
// grid 16384, block 256 (4 waves). Each wave: 4 consecutive-p triples of one (b,l).
__global__ void k_cw(const int* __restrict__ code,
                     const u16* __restrict__ PS, const u16* __restrict__ PE,
                     const u16* __restrict__ PP, const float* __restrict__ Watt,
                     const float* __restrict__ batt, float* __restrict__ cw) {
    int wv = threadIdx.x >> 6, lane = threadIdx.x & 63;
    int t0 = (blockIdx.x * 4 + wv) * 4;
    int b = t0 >> 14;
    int rem = t0 & 16383;
    int l = rem >> 7, p0 = rem & 127;

    const int* c = code + ((b * 128 + l) * 584 + 200 + 3 * p0);
    int si[4], pi[4], ei[4];
#pragma unroll
    for (int i = 0; i < 4; i++) {
        si[i] = __builtin_amdgcn_readfirstlane(c[3 * i]);
        pi[i] = __builtin_amdgcn_readfirstlane(c[3 * i + 1]);
        ei[i] = __builtin_amdgcn_readfirstlane(c[3 * i + 2]);
    }

    float2 wat0 = ((const float2*)Watt)[lane];
    float2 wat1 = ((const float2*)Watt)[64 + lane];
    float2 wat2 = ((const float2*)Watt)[128 + lane];
    float batt0 = batt[0];

#pragma unroll
    for (int i = 0; i < 4; i++) {
        const u32* ps = (const u32*)(PS + si[i] * 384);
        const u32* pe = (const u32*)(PE + ei[i] * 384);
        const u32* pp = (const u32*)(PP + pi[i] * 384);
        u32 s0 = ps[lane], s1 = ps[64 + lane], s2 = ps[128 + lane];
        u32 e0 = pe[lane], e1 = pe[64 + lane], e2 = pe[128 + lane];
        u32 q0 = pp[lane], q1 = pp[64 + lane], q2 = pp[128 + lane];

        float acc = 0.f;
        acc = fmaf(fast_tanh(lo16(s0) + lo16(e0) + lo16(q0)), wat0.x, acc);
        acc = fmaf(fast_tanh(hi16(s0) + hi16(e0) + hi16(q0)), wat0.y, acc);
        acc = fmaf(fast_tanh(lo16(s1) + lo16(e1) + lo16(q1)), wat1.x, acc);
        acc = fmaf(fast_tanh(hi16(s1) + hi16(e1) + hi16(q1)), wat1.y, acc);
        acc = fmaf(fast_tanh(lo16(s2) + lo16(e2) + lo16(q2)), wat2.x, acc);
        acc = fmaf(fast_tanh(hi16(s2) + hi16(e2) + hi16(q2)), wat2.y, acc);

#pragma unroll
        for (int off = 32; off; off >>= 1) acc += __shfl_down(acc, off, 64);
        if (lane == 0) cw[(b * 128 + p0 + i) * 128 + l] = acc + batt0;
    }
}

// ---------------------------------------------------------------- k_sm
// grid 128 = (b, ptile16), block 256. Softmax over l per p; LDS transpose
// so attn[b][l][p0:p0+16] stores are 64B-contiguous.
__global__ void k_sm(const float* __restrict__ cw, float* __restrict__ attn) {
    int b = blockIdx.x >> 3, p0 = (blockIdx.x & 7) * 16;
    int tid = threadIdx.x;
    int wv = tid >> 6, lane = tid & 63;
    __shared__ float tile[16][128];
    __shared__ float atile[128][17];
    for (int idx = tid; idx < 2048; idx += 256) {
        int pp = idx >> 7, l = idx & 127;
        tile[pp][l] = cw[(b * 128 + p0 + pp) * 128 + l];
    }
    __syncthreads();
#pragma unroll
    for (int pl = 0; pl < 4; pl++) {
        int pp = wv * 4 + pl;
        float x0 = tile[pp][lane], x1 = tile[pp][64 + lane];
        float mx = fmaxf(x0, x1);
#pragma unroll
        for (int off = 32; off; off >>= 1) mx = fmaxf(mx, __shfl_xor(mx, off, 64));
        float e0 = nexp(x0 - mx), e1 = nexp(x1 - mx);
        float sum = e0 + e1;
#pragma unroll
        for (int off = 32; off; off >>= 1) sum += __shfl_xor(sum, off, 64);
        float inv = nrcp(sum);
        atile[lane][pp] = e0 * inv;
        atile[64 + lane][pp] = e1 * inv;
    }
    __syncthreads();
    for (int idx = tid; idx < 2048; idx += 256) {
        int l = idx >> 4, pp = idx & 15;
        attn[(b * 128 + l) * 128 + p0 + pp] = atile[l][pp];
    }
}

// ---------------------------------------------------------------- k_cv
// grid 2048 = (b,l), block 256 = 4 waves. code_vec -> vA[row][128:512] bf16;
// also vA[row][0:128] = Vemb[r] bf16 and fA[row][128:256] = Kemb[q] bf16.
__global__ void k_cv(const int* __restrict__ code, const float* __restrict__ attn,
                     const u16* __restrict__ ENb, const u16* __restrict__ EPb,
                     const int* __restrict__ rr, const int* __restrict__ qq,
                     const float* __restrict__ Vemb, const float* __restrict__ Kemb,
                     u16* __restrict__ vA, u16* __restrict__ fA) {
    int row = blockIdx.x;
    int tid = threadIdx.x;
    int wv = tid >> 6, lane = tid & 63;
    __shared__ int si[128], ei[128], pi[128];
    __shared__ float at[128];
    __shared__ float part[4][3][128];
    if (tid < 128) {
        const int* c = code + (row * 584 + 200);
        si[tid] = c[3 * tid]; pi[tid] = c[3 * tid + 1]; ei[tid] = c[3 * tid + 2];
        at[tid] = attn[row * 128 + tid];
    }
    // row-dependent gathers (independent of the p-loop)
    if (tid < 128) {
        vA[row * 512 + tid] = f2b(Vemb[rr[row] * 128 + tid]);
    } else {
        int t2 = tid - 128;
        fA[row * 256 + 128 + t2] = f2b(Kemb[qq[row] * 128 + t2]);
    }
    __syncthreads();
    float a0 = 0.f, a1 = 0.f, b0 = 0.f, b1 = 0.f, c0 = 0.f, c1 = 0.f;
    for (int p = wv; p < 128; p += 8) {
        int p2 = p + 4;
        float w = at[p], w2 = at[p2];
        u32 us = ((const u32*)(ENb + si[p] * 128))[lane];
        u32 ue = ((const u32*)(ENb + ei[p] * 128))[lane];
        u32 up = ((const u32*)(EPb + pi[p] * 128))[lane];
        u32 vs = ((const u32*)(ENb + si[p2] * 128))[lane];
        u32 ve = ((const u32*)(ENb + ei[p2] * 128))[lane];
        u32 vp = ((const u32*)(EPb + pi[p2] * 128))[lane];
        a0 = fmaf(w, lo16(us), a0); a1 = fmaf(w, hi16(us), a1);
        b0 = fmaf(w, lo16(ue), b0); b1 = fmaf(w, hi16(ue), b1);
        c0 = fmaf(w, lo16(up), c0); c1 = fmaf(w, hi16(up), c1);
        a0 = fmaf(w2, lo16(vs), a0); a1 = fmaf(w2, hi16(vs), a1);
        b0 = fmaf(w2, lo16(ve), b0); b1 = fmaf(w2, hi16(ve), b1);
        c0 = fmaf(w2, lo16(vp), c0); c1 = fmaf(w2, hi16(vp), c1);
    }
    part[wv][0][2 * lane] = a0; part[wv][0][2 * lane + 1] = a1;
    part[wv][1][2 * lane] = b0; part[wv][1][2 * lane + 1] = b1;
    part[wv][2][2 * lane] = c0; part[wv][2][2 * lane + 1] = c1;
    __syncthreads();
    u16* vrow = vA + row * 512 + 128;
    for (int idx = tid; idx < 384; idx += 256) {
        int tbl = idx >> 7, col = idx & 127;
        vrow[idx] = f2b(part[0][tbl][col] + part[1][tbl][col] + part[2][tbl][col] + part[3][tbl][col]);
    }
}

// ---------------------------------------------------------------- k_eawM
// grid 512, block 256 (4 waves). C[2048][256] = vA @ WeaT^T via MFMA; cols<128 -> e
// (sigmoid), cols>=128 -> a (tanh). K=512.
__global__ void k_eawM(const u16* __restrict__ vA, const u16* __restrict__ WeaT,
                       const float* __restrict__ be, const float* __restrict__ ba,
                       float* __restrict__ eb, float* __restrict__ ab) {
    int rt = blockIdx.x >> 2, cg = blockIdx.x & 3;
    int wv = threadIdx.x >> 6, lane = threadIdx.x & 63;
    int ct = cg * 4 + wv;
    int m = lane & 15, quad = lane >> 4;
    const short8* ap = (const short8*)(vA + (rt * 16 + m) * 512 + quad * 8);
    const short8* bp = (const short8*)(WeaT + (ct * 16 + m) * 512 + quad * 8);
    f32x4 acc = {0.f, 0.f, 0.f, 0.f};
#pragma unroll
    for (int kc = 0; kc < 16; kc++)
        acc = __builtin_amdgcn_mfma_f32_16x16x32_bf16(ap[kc * 4], bp[kc * 4], acc, 0, 0, 0);
    int col = ct * 16 + m;
    bool isA = col >= 128;
    int c2 = isA ? col - 128 : col;
    float bias = isA ? ba[c2] : be[c2];
#pragma unroll
    for (int reg = 0; reg < 4; reg++) {
        int row = rt * 16 + quad * 4 + reg;
        float val = acc[reg] + bias;
        if (isA) ab[row * 128 + c2] = fast_tanh(val);
        else     eb[row * 128 + c2] = sigmoidf_(val);
    }
}

// ---------------------------------------------------------------- k_scan
// grid 256 = b(16) x dblk(16), block 64. 8-way m-split; w rows gathered from
// wsmall by q. read -> fA[row][0:128] bf16.
__global__ void k_scan(const float* __restrict__ Mv0, const float* __restrict__ eb,
                       const float* __restrict__ ab, const float* __restrict__ wsmall,
                       const int* __restrict__ qq, u16* __restrict__ fA) {
    int b = blockIdx.x >> 4, dblk = blockIdx.x & 15;
    int lane = threadIdx.x;
    int s = lane >> 3, dlo = lane & 7;
    int d = dblk * 8 + dlo;

    float mv[8];
#pragma unroll
    for (int q = 0; q < 8; q++) mv[q] = Mv0[(s * 8 + q) * 128 + d];

    const float* ebp = eb + b * 128 * 128 + d;
    const float* abp = ab + b * 128 * 128 + d;
    const int* qrow = qq + b * 128;
    const float4* wsm = (const float4*)wsmall;
    u16* fout = fA + (b * 128) * 256 + d;

    int qv = qrow[0];
    float ecur = ebp[0], acur = abp[0];
    float4 w0 = wsm[qv * 16 + s * 2], w1 = wsm[qv * 16 + s * 2 + 1];

    for (int t = 0; t < 128; t++) {
        int tn = (t < 127) ? t + 1 : 127;
        int qn = qrow[tn];
        float en = ebp[tn * 128], an = abp[tn * 128];
        float4 nw0 = wsm[qn * 16 + s * 2], nw1 = wsm[qn * 16 + s * 2 + 1];

        float w[8] = { w0.x, w0.y, w0.z, w0.w, w1.x, w1.y, w1.z, w1.w };
        float rd = 0.f;
#pragma unroll
        for (int q = 0; q < 8; q++) {
            rd = fmaf(w[q], mv[q], rd);
            mv[q] = fmaf(w[q], fmaf(-mv[q], ecur, acur), mv[q]);
        }
        rd += __shfl_xor(rd, 8, 64);
        rd += __shfl_xor(rd, 16, 64);
        rd += __shfl_xor(rd, 32, 64);
        if (s == 0) fout[t * 256] = f2b(rd);

        ecur = en; acur = an; w0 = nw0; w1 = nw1;
    }
}

// ---------------------------------------------------------------- k_outM
// grid 256, block 256. gA[2048][128] = tanh(fA @ WfT^T + b_f) bf16. K=256.
__global__ void k_outM(const u16* __restrict__ fA, const u16* __restrict__ WfT,
                       const float* __restrict__ bfp, u16* __restrict__ gA) {
    int rt = blockIdx.x >> 1, cg = blockIdx.x & 1;
    int wv = threadIdx.x >> 6, lane = threadIdx.x & 63;
    int ct = cg * 4 + wv;
    int m = lane & 15, quad = lane >> 4;
    const short8* ap = (const short8*)(fA + (rt * 16 + m) * 256 + quad * 8);
    const short8* bp = (const short8*)(WfT + (ct * 16 + m) * 256 + quad * 8);
    f32x4 acc = {0.f, 0.f, 0.f, 0.f};
#pragma unroll
    for (int kc = 0; kc < 8; kc++)
        acc = __builtin_amdgcn_mfma_f32_16x16x32_bf16(ap[kc * 4], bp[kc * 4], acc, 0, 0, 0);
    int col = ct * 16 + m;
    float bias = bfp[col];
#pragma unroll
    for (int reg = 0; reg < 4; reg++) {
        int row = rt * 16 + quad * 4 + reg;
        gA[row * 128 + col] = f2b(fast_tanh(acc[reg] + bias));
    }
}

// ---------------------------------------------------------------- k_fin
// grid 32, block 256. out[2048][10] = sigmoid(gA @ WpT^T + b_p). K=128, N=16 (10 used).
__global__ void k_fin(const u16* __restrict__ gA, const u16* __restrict__ WpT,
                      const float* __restrict__ bp, float* __restrict__ out) {
    int wv = threadIdx.x >> 6, lane = threadIdx.x & 63;
    int rt = blockIdx.x * 4 + wv;
    int m = lane & 15, quad = lane >> 4;
    const short8* ap = (const short8*)(gA + (rt * 16 + m) * 128 + quad * 8);
    const short8* bp8 = (const short8*)(WpT + m * 128 + quad * 8);
    f32x4 acc = {0.f, 0.f, 0.f, 0.f};
#pragma unroll
    for (int kc = 0; kc < 4; kc++)
        acc = __builtin_amdgcn_mfma_f32_16x16x32_bf16(ap[kc * 4], bp8[kc * 4], acc, 0, 0, 0);
    if (m < 10) {
        float bias = bp[m];
#pragma unroll
        for (int reg = 0; reg < 4; reg++) {
            int row = rt * 16 + quad * 4 + reg;
            out[row * 10 + m] = sigmoidf_(acc[reg] + bias);
        }
    }
}

extern "C" void kernel_launch(void* const* d_in, const int* in_sizes, int n_in,
                              void* d_out, int out_size, void* d_ws, size_t ws_size,
                              hipStream_t stream) {
    const int*   code = (const int*)d_in[0];
    const int*   q    = (const int*)d_in[1];
    const int*   r    = (const int*)d_in[2];
    const float* EN   = (const float*)d_in[3];
    const float* EP   = (const float*)d_in[4];
    const float* Wpt  = (const float*)d_in[5];
    const float* bpt  = (const float*)d_in[6];
    const float* Watt = (const float*)d_in[7];
    const float* batt = (const float*)d_in[8];
    const float* Kemb = (const float*)d_in[9];
    const float* Mk   = (const float*)d_in[10];
    const float* Mv0  = (const float*)d_in[11];
    const float* Vemb = (const float*)d_in[12];
    const float* We   = (const float*)d_in[13];
    const float* be   = (const float*)d_in[14];
    const float* Wa   = (const float*)d_in[15];
    const float* ba   = (const float*)d_in[16];
    const float* Wf   = (const float*)d_in[17];
    const float* bf_  = (const float*)d_in[18];
    const float* Wp   = (const float*)d_in[19];
    const float* bp   = (const float*)d_in[20];

    char* ws = (char*)d_ws;
    size_t off = 0;
    auto alloc = [&](size_t bytes) { void* p = ws + off; off = (off + bytes + 255) & ~255UL; return p; };
    u16*   PS     = (u16*)alloc(10002UL * 384 * 2);
    u16*   PE     = (u16*)alloc(10002UL * 384 * 2);
    u16*   PP     = (u16*)alloc(10002UL * 384 * 2);
    u16*   ENb    = (u16*)alloc(10002UL * 128 * 2);
    u16*   EPb    = (u16*)alloc(10016UL * 128 * 2);   // +14 rows pad: k_preM tail reads
    u16*   Wt     = (u16*)alloc(384UL * 384 * 2);
    u16*   WeaT   = (u16*)alloc(256UL * 512 * 2);
    u16*   WfT    = (u16*)alloc(128UL * 256 * 2);
    u16*   WpT    = (u16*)alloc(16UL * 128 * 2);
    float* cw     = (float*)alloc(16UL * 128 * 128 * 4);   // [b][p][l]
    float* attn   = (float*)alloc(16UL * 128 * 128 * 4);   // [b][l][p]
    u16*   vA     = (u16*)alloc(2048UL * 512 * 2);         // [Vemb[r] ; code_vec] bf16
    u16*   fA     = (u16*)alloc(2048UL * 256 * 2);         // [read ; Kemb[q]] bf16
    u16*   gA     = (u16*)alloc(2048UL * 128 * 2);         // f bf16
    float* eb     = (float*)alloc(2048UL * 128 * 4);
    float* ab     = (float*)alloc(2048UL * 128 * 4);
    float* wsmall = (float*)alloc(101UL * 64 * 4);

    k_conv<<<2048, 256, 0, stream>>>(EN, EP, Wpt, We, Wa, Wf, Wp, ENb, EPb, Wt, WeaT, WfT, WpT);
    k_wsm<<<101, 64, 0, stream>>>(Kemb, Mk, wsmall);
    k_preM<<<dim3(626, 3), 256, 0, stream>>>(ENb, EPb, Wt, bpt, PS, PE, PP);
    k_cw<<<16384, 256, 0, stream>>>(code, PS, PE, PP, Watt, batt, cw);
    k_sm<<<128, 256, 0, stream>>>(cw, attn);
    k_cv<<<2048, 256, 0, stream>>>(code, attn, ENb, EPb, r, q, Vemb, Kemb, vA, fA);
    k_eawM<<<512, 256, 0, stream>>>(vA, WeaT, be, ba, eb, ab);
    k_scan<<<256, 64, 0, stream>>>(Mv0, eb, ab, wsmall, q, fA);
    k_outM<<<256, 256, 0, stream>>>(fA, WfT, bf_, gA);
    k_fin<<<32, 256, 0, stream>>>(gA, WpT, bp, (float*)d_out);
}

// Round 7
// 260.071 us; speedup vs baseline: 2.7699x; 1.0878x over previous
//
#include <hip/hip_runtime.h>

// DKVMN + code2vec attention. Sizes (fixed):
// B=16 L=128 P=128 NUM_C=100 D=128 M=64 EMB=128 TE=384 CODE_W=584 NROW=10002
//
// Inputs/outputs f32. MFMA operands bf16; gather tables fp8 e4m3 (halves fetch;
// PS/PE/PP 23->11.5 MB, EN/EP 5->2.5 MB = L2-resident). Native v_exp/v_rcp.
//
//  k_conv : bf16 ENb/EPb (MFMA A), fp8 EN8/EP8 (k_cv gathers), transposed bf16
//           Wt (W_pt), WeaT (We|Wa), WfT, WpT
//  k_wsm  : wsmall[q][m] = softmax(k_emb[q] @ Mk^T), 101 distinct q rows
//  k_preM : PS8/PE8/PP8 = fp8(emb @ Wpt slices) via MFMA (factorized full@W_pt)
//  k_cw   : cw[b,p,l] = tanh(PS[s]+PE[e]+PP[pa]) . W_att + b_att  (fp8 gathers)
//  k_sm   : softmax over l per (b,p); LDS-transposed -> coalesced attn[b,l,p]
//  k_cv   : vA[row]=[Vemb[r];code_vec] bf16 (fp8 gathers); fA[row][128:]=Kemb[q]
//  k_eawM : e|a = act(vA @ WeaT + b) via MFMA  [2048x512]@[512x256]
//  k_scan : sequential scan, all state LDS-staged (wsmall+e/a tile+q)
//  k_outM : f = tanh(fA @ WfT + b_f) -> gA bf16
//  k_fin  : out = sigmoid(gA @ WpT + b_p)

typedef unsigned char u8;
typedef unsigned short u16;
typedef unsigned int u32;
typedef __attribute__((ext_vector_type(8))) short short8;   // 8 bf16 (4 VGPRs)
typedef __attribute__((ext_vector_type(4))) float f32x4;    // MFMA C/D
typedef __attribute__((ext_vector_type(2))) float f32x2;

#define DEV __device__ __forceinline__
#define LOG2E 1.4426950408889634f

DEV u16 f2b(float f) {
    union { float f; u32 i; } v; v.f = f;
    u32 x = v.i;
    u32 r = (x + 0x7FFFu + ((x >> 16) & 1u)) >> 16;   // RNE
    return (u16)r;
}
DEV float nexp(float x) { return __builtin_amdgcn_exp2f(x * LOG2E); }
DEV float nrcp(float x) { return __builtin_amdgcn_rcpf(x); }
DEV float fast_tanh(float x) {
    return 1.f - 2.f * nrcp(1.f + __builtin_amdgcn_exp2f(x * (2.f * LOG2E)));
}
DEV float sigmoidf_(float x) { return nrcp(1.f + __builtin_amdgcn_exp2f(-x * LOG2E)); }
DEV f32x2 d8(u32 x, bool hi) {                 // decode 2 fp8 e4m3 -> 2 f32
    return hi ? __builtin_amdgcn_cvt_pk_f32_fp8((int)x, true)
              : __builtin_amdgcn_cvt_pk_f32_fp8((int)x, false);
}
DEV u8 e8(float x) {                           // encode f32 -> fp8 e4m3
    return (u8)(__builtin_amdgcn_cvt_pk_fp8_f32(x, x, 0, false) & 0xFF);
}

// ---------------------------------------------------------------- k_conv
// Grid-stride segments: ENb | EPb | Wt | WeaT | WfT | WpT | EN8 pairs | EP8 pairs
__global__ void k_conv(const float* __restrict__ EN, const float* __restrict__ EP,
                       const float* __restrict__ Wpt, const float* __restrict__ We,
                       const float* __restrict__ Wa, const float* __restrict__ Wf,
                       const float* __restrict__ Wp,
                       u16* __restrict__ ENb, u16* __restrict__ EPb, u16* __restrict__ Wt,
                       u16* __restrict__ WeaT, u16* __restrict__ WfT, u16* __restrict__ WpT,
                       u8* __restrict__ EN8, u8* __restrict__ EP8) {
    const int NE = 10002 * 128;
    const int T0 = 2 * NE;             // end EPb
    const int T1 = T0 + 147456;        // end Wt
    const int T2 = T1 + 131072;        // end WeaT
    const int T3 = T2 + 32768;         // end WfT
    const int T4 = T3 + 2048;          // end WpT
    const int T5 = T4 + NE / 2;        // end EN8 (u16 pair units)
    const int T6 = T5 + NE / 2;        // end EP8
    for (int i = blockIdx.x * blockDim.x + threadIdx.x; i < T6; i += gridDim.x * blockDim.x) {
        if (i < NE) {
            ENb[i] = f2b(EN[i]);
        } else if (i < T0) {
            EPb[i - NE] = f2b(EP[i - NE]);
        } else if (i < T1) {
            int w = i - T0;  u32 n = (u32)w / 384u, k = (u32)w % 384u;
            Wt[w] = f2b(Wpt[k * 384 + n]);
        } else if (i < T2) {
            int w = i - T1;  int n = w >> 9, k = w & 511;
            WeaT[w] = f2b((n < 128) ? We[k * 128 + n] : Wa[k * 128 + (n - 128)]);
        } else if (i < T3) {
            int w = i - T2;  int n = w >> 8, k = w & 255;
            WfT[w] = f2b(Wf[k * 128 + n]);
        } else if (i < T4) {
            int w = i - T3;  int n = w >> 7, k = w & 127;
            WpT[w] = (n < 10) ? f2b(Wp[k * 10 + n]) : (u16)0;
        } else if (i < T5) {
            int j = i - T4;
            int pk = __builtin_amdgcn_cvt_pk_fp8_f32(EN[2 * j], EN[2 * j + 1], 0, false);
            ((u16*)EN8)[j] = (u16)pk;
        } else {
            int j = i - T5;
            int pk = __builtin_amdgcn_cvt_pk_fp8_f32(EP[2 * j], EP[2 * j + 1], 0, false);
            ((u16*)EP8)[j] = (u16)pk;
        }
    }
}

// ---------------------------------------------------------------- k_wsm
// grid 101, block 64. wsmall[row][m] = softmax_m(Kemb[row] . Mk[m]).
__global__ void k_wsm(const float* __restrict__ Kemb, const float* __restrict__ Mk,
                      float* __restrict__ wsmall) {
    int row = blockIdx.x;
    int m = threadIdx.x;
    __shared__ float kr[128];
    kr[m] = Kemb[row * 128 + m];
    kr[64 + m] = Kemb[row * 128 + 64 + m];
    __syncthreads();
    float lg = 0.f;
    for (int k = 0; k < 128; k += 8) {
        float mk8[8];
#pragma unroll
        for (int u = 0; u < 8; u++) mk8[u] = Mk[m * 128 + k + u];
#pragma unroll
        for (int u = 0; u < 8; u++) lg = fmaf(kr[k + u], mk8[u], lg);
    }
    float mx = lg;
#pragma unroll
    for (int off = 32; off; off >>= 1) mx = fmaxf(mx, __shfl_xor(mx, off, 64));
    float ex = nexp(lg - mx);
    float sum = ex;
#pragma unroll
    for (int off = 32; off; off >>= 1) sum += __shfl_xor(sum, off, 64);
    wsmall[row * 64 + m] = ex * nrcp(sum);
}

// ---------------------------------------------------------------- k_preM
// grid (626, 3), block 256 = 4 waves. MFMA 16x16x32 bf16; fp8 epilogue stores.
__global__ void k_preM(const u16* __restrict__ ENb, const u16* __restrict__ EPb,
                       const u16* __restrict__ Wt, const float* __restrict__ bpt,
                       u8* __restrict__ PS8, u8* __restrict__ PE8, u8* __restrict__ PP8) {
    int which = blockIdx.y;
    int r0 = blockIdx.x * 16;
    int wv = threadIdx.x >> 6, lane = threadIdx.x & 63;
    int m = lane & 15, quad = lane >> 4;
    const u16* A = (which == 2) ? EPb : ENb;
    int koff = which * 128;
    u8* dst = (which == 0) ? PS8 : (which == 1) ? PE8 : PP8;

    const short8* ap = (const short8*)(A + (r0 + m) * 128 + quad * 8);
    short8 a0 = ap[0], a1 = ap[4], a2 = ap[8], a3 = ap[12];

    for (int nt = 0; nt < 6; nt++) {
        int n0 = wv * 96 + nt * 16;
        const short8* bp = (const short8*)(Wt + (n0 + m) * 384 + koff + quad * 8);
        f32x4 acc = {0.f, 0.f, 0.f, 0.f};
        acc = __builtin_amdgcn_mfma_f32_16x16x32_bf16(a0, bp[0],  acc, 0, 0, 0);
        acc = __builtin_amdgcn_mfma_f32_16x16x32_bf16(a1, bp[4],  acc, 0, 0, 0);
        acc = __builtin_amdgcn_mfma_f32_16x16x32_bf16(a2, bp[8],  acc, 0, 0, 0);
        acc = __builtin_amdgcn_mfma_f32_16x16x32_bf16(a3, bp[12], acc, 0, 0, 0);
        int col = n0 + m;
        float bias = (which == 2) ? bpt[col] : 0.f;
#pragma unroll
        for (int reg = 0; reg < 4; reg++) {
            int row = r0 + quad * 4 + reg;
            if (row < 10002) dst[row * 384 + col] = e8(acc[reg] + bias);
        }
    }
}

// ---------------------------------------------------------------- k_cw
// grid 16384, block 256 (4 waves). Each wave: 4 consecutive-p triples of one (b,l).
// fp8 rows (384 B). Lane covers j=6*lane..+5 via one aligned u32 + one u16:
// even lane: u32@6l (j..j+3), u16@6l+4 (j+4,j+5); odd: u16@6l (j,j+1), u32@6l+2 (j+2..j+5).
__global__ void k_cw(const int* __restrict__ code,
                     const u8* __restrict__ PS8, const u8* __restrict__ PE8,
                     const u8* __restrict__ PP8, const float* __restrict__ Watt,
                     const float* __restrict__ batt, float* __restrict__ cw) {
    int wv = threadIdx.x >> 6, lane = threadIdx.x & 63;
    int t0 = (blockIdx.x * 4 + wv) * 4;
    int b = t0 >> 14;
    int rem = t0 & 16383;
    int l = rem >> 7, p0 = rem & 127;

    const int* c = code + ((b * 128 + l) * 584 + 200 + 3 * p0);
    int si[4], pi[4], ei[4];
#pragma unroll
    for (int i = 0; i < 4; i++) {
        si[i] = __builtin_amdgcn_readfirstlane(c[3 * i]);
        pi[i] = __builtin_amdgcn_readfirstlane(c[3 * i + 1]);
        ei[i] = __builtin_amdgcn_readfirstlane(c[3 * i + 2]);
    }

    int j0 = 6 * lane;
    int o32 = j0 + ((lane & 1) << 1);          // aligned u32 offset
    int o16 = j0 + ((~lane & 1) << 2);         // u16 offset
    float wa0 = Watt[o32], wa1 = Watt[o32 + 1], wa2 = Watt[o32 + 2], wa3 = Watt[o32 + 3];
    float wb0 = Watt[o16], wb1 = Watt[o16 + 1];
    float batt0 = batt[0];

#pragma unroll
    for (int i = 0; i < 4; i++) {
        const u8* bs = PS8 + si[i] * 384;
        const u8* be = PE8 + ei[i] * 384;
        const u8* bq = PP8 + pi[i] * 384;
        u32 xs = *(const u32*)(bs + o32), ys = *(const u16*)(bs + o16);
        u32 xe = *(const u32*)(be + o32), ye = *(const u16*)(be + o16);
        u32 xq = *(const u32*)(bq + o32), yq = *(const u16*)(bq + o16);

        f32x2 zA = d8(xs, false) + d8(xe, false) + d8(xq, false);
        f32x2 zB = d8(xs, true)  + d8(xe, true)  + d8(xq, true);
        f32x2 zC = d8(ys, false) + d8(ye, false) + d8(yq, false);

        float acc = 0.f;
        acc = fmaf(fast_tanh(zA.x), wa0, acc);
        acc = fmaf(fast_tanh(zA.y), wa1, acc);
        acc = fmaf(fast_tanh(zB.x), wa2, acc);
        acc = fmaf(fast_tanh(zB.y), wa3, acc);
        acc = fmaf(fast_tanh(zC.x), wb0, acc);
        acc = fmaf(fast_tanh(zC.y), wb1, acc);

#pragma unroll
        for (int off = 32; off; off >>= 1) acc += __shfl_down(acc, off, 64);
        if (lane == 0) cw[(b * 128 + p0 + i) * 128 + l] = acc + batt0;
    }
}

// ---------------------------------------------------------------- k_sm
// grid 128 = (b, ptile16), block 256. Softmax over l per p; LDS transpose.
__global__ void k_sm(const float* __restrict__ cw, float* __restrict__ attn) {
    int b = blockIdx.x >> 3, p0 = (blockIdx.x & 7) * 16;
    int tid = threadIdx.x;
    int wv = tid >> 6, lane = tid & 63;
    __shared__ float tile[16][128];
    __shared__ float atile[128][17];
    for (int idx = tid; idx < 2048; idx += 256) {
        int pp = idx >> 7, l = idx & 127;
        tile[pp][l] = cw[(b * 128 + p0 + pp) * 128 + l];
    }
    __syncthreads();
#pragma unroll
    for (int pl = 0; pl < 4; pl++) {
        int pp = wv * 4 + pl;
        float x0 = tile[pp][lane], x1 = tile[pp][64 + lane];
        float mx = fmaxf(x0, x1);
#pragma unroll
        for (int off = 32; off; off >>= 1) mx = fmaxf(mx, __shfl_xor(mx, off, 64));
        float e0 = nexp(x0 - mx), e1 = nexp(x1 - mx);
        float sum = e0 + e1;
#pragma unroll
        for (int off = 32; off; off >>= 1) sum += __shfl_xor(sum, off, 64);
        float inv = nrcp(sum);
        atile[lane][pp] = e0 * inv;
        atile[64 + lane][pp] = e1 * inv;
    }
    __syncthreads();
    for (int idx = tid; idx < 2048; idx += 256) {
        int l = idx >> 4, pp = idx & 15;
        attn[(b * 128 + l) * 128 + p0 + pp] = atile[l][pp];
    }
}

// ---------------------------------------------------------------- k_cv
// grid 2048 = (b,l), block 256 = 4 waves. fp8 gathers (EN8/EP8 L2-resident).
// Lane covers cols 2*lane, 2*lane+1 via u16 loads.
__global__ void k_cv(const int* __restrict__ code, const float* __restrict__ attn,
                     const u8* __restrict__ EN8, const u8* __restrict__ EP8,
                     const int* __restrict__ rr, const int* __restrict__ qq,
                     const float* __restrict__ Vemb, const float* __restrict__ Kemb,
                     u16* __restrict__ vA, u16* __restrict__ fA) {
    int row = blockIdx.x;
    int tid = threadIdx.x;
    int wv = tid >> 6, lane = tid & 63;
    __shared__ int si[128], ei[128], pi[128];
    __shared__ float at[128];
    __shared__ float part[4][3][128];
    if (tid < 128) {
        const int* c = code + (row * 584 + 200);
        si[tid] = c[3 * tid]; pi[tid] = c[3 * tid + 1]; ei[tid] = c[3 * tid + 2];
        at[tid] = attn[row * 128 + tid];
    }
    if (tid < 128) {
        vA[row * 512 + tid] = f2b(Vemb[rr[row] * 128 + tid]);
    } else {
        int t2 = tid - 128;
        fA[row * 256 + 128 + t2] = f2b(Kemb[qq[row] * 128 + t2]);
    }
    __syncthreads();
    float a0 = 0.f, a1 = 0.f, b0 = 0.f, b1 = 0.f, c0 = 0.f, c1 = 0.f;
    int o = 2 * lane;
    for (int p = wv; p < 128; p += 8) {
        int p2 = p + 4;
        float w = at[p], w2 = at[p2];
        u32 us = *(const u16*)(EN8 + si[p] * 128 + o);
        u32 ue = *(const u16*)(EN8 + ei[p] * 128 + o);
        u32 up = *(const u16*)(EP8 + pi[p] * 128 + o);
        u32 vs = *(const u16*)(EN8 + si[p2] * 128 + o);
        u32 ve = *(const u16*)(EN8 + ei[p2] * 128 + o);
        u32 vp = *(const u16*)(EP8 + pi[p2] * 128 + o);
        f32x2 fs = d8(us, false), fe = d8(ue, false), fp = d8(up, false);
        f32x2 gs = d8(vs, false), ge = d8(ve, false), gp = d8(vp, false);
        a0 = fmaf(w, fs.x, a0); a1 = fmaf(w, fs.y, a1);
        b0 = fmaf(w, fe.x, b0); b1 = fmaf(w, fe.y, b1);
        c0 = fmaf(w, fp.x, c0); c1 = fmaf(w, fp.y, c1);
        a0 = fmaf(w2, gs.x, a0); a1 = fmaf(w2, gs.y, a1);
        b0 = fmaf(w2, ge.x, b0); b1 = fmaf(w2, ge.y, b1);
        c0 = fmaf(w2, gp.x, c0); c1 = fmaf(w2, gp.y, c1);
    }
    part[wv][0][2 * lane] = a0; part[wv][0][2 * lane + 1] = a1;
    part[wv][1][2 * lane] = b0; part[wv][1][2 * lane + 1] = b1;
    part[wv][2][2 * lane] = c0; part[wv][2][2 * lane + 1] = c1;
    __syncthreads();
    u16* vrow = vA + row * 512 + 128;
    for (int idx = tid; idx < 384; idx += 256) {
        int tbl = idx >> 7, col = idx & 127;
        vrow[idx] = f2b(part[0][tbl][col] + part[1][tbl][col] + part[2][tbl][col] + part[3][tbl][col]);
    }
}

// ---------------------------------------------------------------- k_eawM
// grid 512, block 256 (4 waves). C[2048][256] = vA @ WeaT^T via MFMA. K=512.
__global__ void k_eawM(const u16* __restrict__ vA, const u16* __restrict__ WeaT,
                       const float* __restrict__ be, const float* __restrict__ ba,
                       float* __restrict__ eb, float* __restrict__ ab) {
    int rt = blockIdx.x >> 2, cg = blockIdx.x & 3;
    int wv = threadIdx.x >> 6, lane = threadIdx.x & 63;
    int ct = cg * 4 + wv;
    int m = lane & 15, quad = lane >> 4;
    const short8* ap = (const short8*)(vA + (rt * 16 + m) * 512 + quad * 8);
    const short8* bp = (const short8*)(WeaT + (ct * 16 + m) * 512 + quad * 8);
    f32x4 acc = {0.f, 0.f, 0.f, 0.f};
#pragma unroll
    for (int kc = 0; kc < 16; kc++)
        acc = __builtin_amdgcn_mfma_f32_16x16x32_bf16(ap[kc * 4], bp[kc * 4], acc, 0, 0, 0);
    int col = ct * 16 + m;
    bool isA = col >= 128;
    int c2 = isA ? col - 128 : col;
    float bias = isA ? ba[c2] : be[c2];
#pragma unroll
    for (int reg = 0; reg < 4; reg++) {
        int row = rt * 16 + quad * 4 + reg;
        float val = acc[reg] + bias;
        if (isA) ab[row * 128 + c2] = fast_tanh(val);
        else     eb[row * 128 + c2] = sigmoidf_(val);
    }
}

// ---------------------------------------------------------------- k_scan
// grid 256 = b(16) x dblk(16), block 64. All loop state LDS-staged:
// wsmall (25 KB) + e/a 128x8 tile (8 KB) + q (0.5 KB). 8-way m-split,
// reduce over s via shfl_xor; read -> fA[row][0:128] bf16.
__global__ void k_scan(const float* __restrict__ Mv0, const float* __restrict__ eb,
                       const float* __restrict__ ab, const float* __restrict__ wsmall,
                       const int* __restrict__ qq, u16* __restrict__ fA) {
    int b = blockIdx.x >> 4, dblk = blockIdx.x & 15;
    int lane = threadIdx.x;
    int s = lane >> 3, dlo = lane & 7;
    int d = dblk * 8 + dlo;

    __shared__ float wsm[101 * 64];
    __shared__ float el[128][8];
    __shared__ float al[128][8];
    __shared__ int ql[128];

    for (int i = lane; i < 101 * 64; i += 64) wsm[i] = wsmall[i];
    for (int i = lane; i < 1024; i += 64) {
        int t = i >> 3, dl = i & 7;
        el[t][dl] = eb[(b * 128 + t) * 128 + dblk * 8 + dl];
        al[t][dl] = ab[(b * 128 + t) * 128 + dblk * 8 + dl];
    }
    for (int i = lane; i < 128; i += 64) ql[i] = qq[b * 128 + i];
    __syncthreads();

    float mv[8];
#pragma unroll
    for (int q = 0; q < 8; q++) mv[q] = Mv0[(s * 8 + q) * 128 + d];

    u16* fout = fA + (b * 128) * 256 + d;

    int qt = ql[0];
    const float4* wr = (const float4*)(wsm + qt * 64 + s * 8);
    float4 w0 = wr[0], w1 = wr[1];
    float ecur = el[0][dlo], acur = al[0][dlo];

    for (int t = 0; t < 128; t++) {
        int tn = (t < 127) ? t + 1 : 127;
        int qn = ql[tn];
        const float4* wrn = (const float4*)(wsm + qn * 64 + s * 8);
        float4 nw0 = wrn[0], nw1 = wrn[1];
        float en = el[tn][dlo], an = al[tn][dlo];

        float w[8] = { w0.x, w0.y, w0.z, w0.w, w1.x, w1.y, w1.z, w1.w };
        float rd = 0.f;
#pragma unroll
        for (int q = 0; q < 8; q++) {
            rd = fmaf(w[q], mv[q], rd);
            mv[q] = fmaf(w[q], fmaf(-mv[q], ecur, acur), mv[q]);
        }
        rd += __shfl_xor(rd, 8, 64);
        rd += __shfl_xor(rd, 16, 64);
        rd += __shfl_xor(rd, 32, 64);
        if (s == 0) fout[t * 256] = f2b(rd);

        ecur = en; acur = an; w0 = nw0; w1 = nw1;
    }
}

// ---------------------------------------------------------------- k_outM
// grid 256, block 256. gA[2048][128] = tanh(fA @ WfT^T + b_f) bf16. K=256.
__global__ void k_outM(const u16* __restrict__ fA, const u16* __restrict__ WfT,
                       const float* __restrict__ bfp, u16* __restrict__ gA) {
    int rt = blockIdx.x >> 1, cg = blockIdx.x & 1;
    int wv = threadIdx.x >> 6, lane = threadIdx.x & 63;
    int ct = cg * 4 + wv;
    int m = lane & 15, quad = lane >> 4;
    const short8* ap = (const short8*)(fA + (rt * 16 + m) * 256 + quad * 8);
    const short8* bp = (const short8*)(WfT + (ct * 16 + m) * 256 + quad * 8);
    f32x4 acc = {0.f, 0.f, 0.f, 0.f};
#pragma unroll
    for (int kc = 0; kc < 8; kc++)
        acc = __builtin_amdgcn_mfma_f32_16x16x32_bf16(ap[kc * 4], bp[kc * 4], acc, 0, 0, 0);
    int col = ct * 16 + m;
    float bias = bfp[col];
#pragma unroll
    for (int reg = 0; reg < 4; reg++) {
        int row = rt * 16 + quad * 4 + reg;
        gA[row * 128 + col] = f2b(fast_tanh(acc[reg] + bias));
    }
}

// ---------------------------------------------------------------- k_fin
// grid 32, block 256. out[2048][10] = sigmoid(gA @ WpT^T + b_p). K=128, N=16(10).
__global__ void k_fin(const u16* __restrict__ gA, const u16* __restrict__ WpT,
                      const float* __restrict__ bp, float* __restrict__ out) {
    int wv = threadIdx.x >> 6, lane = threadIdx.x & 63;
    int rt = blockIdx.x * 4 + wv;
    int m = lane & 15, quad = lane >> 4;
    const short8* ap = (const short8*)(gA + (rt * 16 + m) * 128 + quad * 8);
    const short8* bp8 = (const short8*)(WpT + m * 128 + quad * 8);
    f32x4 acc = {0.f, 0.f, 0.f, 0.f};
#pragma unroll
    for (int kc = 0; kc < 4; kc++)
        acc = __builtin_amdgcn_mfma_f32_16x16x32_bf16(ap[kc * 4], bp8[kc * 4], acc, 0, 0, 0);
    if (m < 10) {
        float bias = bp[m];
#pragma unroll
        for (int reg = 0; reg < 4; reg++) {
            int row = rt * 16 + quad * 4 + reg;
            out[row * 10 + m] = sigmoidf_(acc[reg] + bias);
        }
    }
}

extern "C" void kernel_launch(void* const* d_in, const int* in_sizes, int n_in,
                              void* d_out, int out_size, void* d_ws, size_t ws_size,
                              hipStream_t stream) {
    const int*   code = (const int*)d_in[0];
    const int*   q    = (const int*)d_in[1];
    const int*   r    = (const int*)d_in[2];
    const float* EN   = (const float*)d_in[3];
    const float* EP   = (const float*)d_in[4];
    const float* Wpt  = (const float*)d_in[5];
    const float* bpt  = (const float*)d_in[6];
    const float* Watt = (const float*)d_in[7];
    const float* batt = (const float*)d_in[8];
    const float* Kemb = (const float*)d_in[9];
    const float* Mk   = (const float*)d_in[10];
    const float* Mv0  = (const float*)d_in[11];
    const float* Vemb = (const float*)d_in[12];
    const float* We   = (const float*)d_in[13];
    const float* be   = (const float*)d_in[14];
    const float* Wa   = (const float*)d_in[15];
    const float* ba   = (const float*)d_in[16];
    const float* Wf   = (const float*)d_in[17];
    const float* bf_  = (const float*)d_in[18];
    const float* Wp   = (const float*)d_in[19];
    const float* bp   = (const float*)d_in[20];

    char* ws = (char*)d_ws;
    size_t off = 0;
    auto alloc = [&](size_t bytes) { void* p = ws + off; off = (off + bytes + 255) & ~255UL; return p; };
    u8*    PS8    = (u8*)alloc(10002UL * 384);
    u8*    PE8    = (u8*)alloc(10002UL * 384);
    u8*    PP8    = (u8*)alloc(10002UL * 384);
    u16*   ENb    = (u16*)alloc(10002UL * 128 * 2);
    u16*   EPb    = (u16*)alloc(10016UL * 128 * 2);   // +14 rows pad: k_preM tail reads
    u8*    EN8    = (u8*)alloc(10002UL * 128);
    u8*    EP8    = (u8*)alloc(10002UL * 128);
    u16*   Wt     = (u16*)alloc(384UL * 384 * 2);
    u16*   WeaT   = (u16*)alloc(256UL * 512 * 2);
    u16*   WfT    = (u16*)alloc(128UL * 256 * 2);
    u16*   WpT    = (u16*)alloc(16UL * 128 * 2);
    float* cw     = (float*)alloc(16UL * 128 * 128 * 4);   // [b][p][l]
    float* attn   = (float*)alloc(16UL * 128 * 128 * 4);   // [b][l][p]
    u16*   vA     = (u16*)alloc(2048UL * 512 * 2);         // [Vemb[r] ; code_vec] bf16
    u16*   fA     = (u16*)alloc(2048UL * 256 * 2);         // [read ; Kemb[q]] bf16
    u16*   gA     = (u16*)alloc(2048UL * 128 * 2);         // f bf16
    float* eb     = (float*)alloc(2048UL * 128 * 4);
    float* ab     = (float*)alloc(2048UL * 128 * 4);
    float* wsmall = (float*)alloc(101UL * 64 * 4);

    k_conv<<<2048, 256, 0, stream>>>(EN, EP, Wpt, We, Wa, Wf, Wp, ENb, EPb, Wt, WeaT, WfT, WpT, EN8, EP8);
    k_wsm<<<101, 64, 0, stream>>>(Kemb, Mk, wsmall);
    k_preM<<<dim3(626, 3), 256, 0, stream>>>(ENb, EPb, Wt, bpt, PS8, PE8, PP8);
    k_cw<<<16384, 256, 0, stream>>>(code, PS8, PE8, PP8, Watt, batt, cw);
    k_sm<<<128, 256, 0, stream>>>(cw, attn);
    k_cv<<<2048, 256, 0, stream>>>(code, attn, EN8, EP8, r, q, Vemb, Kemb, vA, fA);
    k_eawM<<<512, 256, 0, stream>>>(vA, WeaT, be, ba, eb, ab);
    k_scan<<<256, 64, 0, stream>>>(Mv0, eb, ab, wsmall, q, fA);
    k_outM<<<256, 256, 0, stream>>>(fA, WfT, bf_, gA);
    k_fin<<<32, 256, 0, stream>>>(gA, WpT, bp, (float*)d_out);
}

// Round 8
// 258.163 us; speedup vs baseline: 2.7904x; 1.0074x over previous
//
#include <hip/hip_runtime.h>

// DKVMN + code2vec attention. Sizes (fixed):
// B=16 L=128 P=128 NUM_C=100 D=128 M=64 EMB=128 TE=384 CODE_W=584 NROW=10002
//
// Inputs/outputs f32. MFMA operands bf16; gather tables fp8 e4m3.
// k_cw algebra: tanh identity + softmax shift-invariance =>
//   logit'[b,p,l] = -2 * sum_j Watt_j * rcp(1 + exp2(z'_j)),  z' = z*2log2e
// (constants sum(Watt)+b_att cancel in the l-softmax; tables pre-scaled).
//
//  k_conv  : ENb/EPb bf16 + EN8/EP8 fp8 (single read), transposed bf16 Wt/WeaT/
//            WfT/WpT; extra blocks compute wsmall[q][m]=softmax(k_emb[q]@Mk^T)
//  k_preM  : PS8/PE8/PP8 = fp8((emb @ Wpt slice)*2log2e) via MFMA
//  k_cw    : logits via fp8 gathers, rcp-only form, 8 triples/wave
//  k_sm    : softmax over l per (b,p); LDS transpose -> coalesced attn[b,l,p]
//  k_cv    : vA[row]=[Vemb[r];code_vec] bf16 (fp8 gathers); fA[row][128:]=Kemb[q]
//  k_eawM  : e|a = act(vA @ WeaT + b) via MFMA
//  k_scan  : sequential scan, LDS-staged state; read -> fA bf16
//  k_outfin: f = tanh(fA @ WfT + b_f) (LDS) then out = sigmoid(f @ WpT + b_p)

typedef unsigned char u8;
typedef unsigned short u16;
typedef unsigned int u32;
typedef __attribute__((ext_vector_type(8))) short short8;   // 8 bf16 (4 VGPRs)
typedef __attribute__((ext_vector_type(4))) float f32x4;    // MFMA C/D
typedef __attribute__((ext_vector_type(2))) float f32x2;

#define DEV __device__ __forceinline__
#define LOG2E 1.4426950408889634f
#define KSCALE 2.8853900817779268f   // 2*log2(e)

DEV u16 f2b(float f) {
    union { float f; u32 i; } v; v.f = f;
    u32 x = v.i;
    u32 r = (x + 0x7FFFu + ((x >> 16) & 1u)) >> 16;   // RNE
    return (u16)r;
}
DEV float nexp(float x) { return __builtin_amdgcn_exp2f(x * LOG2E); }
DEV float nrcp(float x) { return __builtin_amdgcn_rcpf(x); }
DEV float fast_tanh(float x) {
    return 1.f - 2.f * nrcp(1.f + __builtin_amdgcn_exp2f(x * (2.f * LOG2E)));
}
DEV float sigmoidf_(float x) { return nrcp(1.f + __builtin_amdgcn_exp2f(-x * LOG2E)); }
DEV f32x2 d8(u32 x, bool hi) {                 // decode 2 fp8 e4m3 -> 2 f32
    return hi ? __builtin_amdgcn_cvt_pk_f32_fp8((int)x, true)
              : __builtin_amdgcn_cvt_pk_f32_fp8((int)x, false);
}
DEV u8 e8(float x) {                           // encode f32 -> fp8 e4m3
    return (u8)(__builtin_amdgcn_cvt_pk_fp8_f32(x, x, 0, false) & 0xFF);
}

// ---------------------------------------------------------------- k_conv
// blocks <2048: grid-stride pair-indexed segments:
//   EN pairs -> ENb(u32)+EN8(u16) | EP pairs | Wt | WeaT | WfT | WpT
// blocks >=2048: wsmall (4 rows/block, one per wave).
__global__ void k_conv(const float* __restrict__ EN, const float* __restrict__ EP,
                       const float* __restrict__ Wpt, const float* __restrict__ We,
                       const float* __restrict__ Wa, const float* __restrict__ Wf,
                       const float* __restrict__ Wp,
                       const float* __restrict__ Kemb, const float* __restrict__ Mk,
                       u16* __restrict__ ENb, u16* __restrict__ EPb,
                       u8* __restrict__ EN8, u8* __restrict__ EP8,
                       u16* __restrict__ Wt, u16* __restrict__ WeaT,
                       u16* __restrict__ WfT, u16* __restrict__ WpT,
                       float* __restrict__ wsmall) {
    if (blockIdx.x >= 2048) {                      // ---- wsmall part
        int wv = threadIdx.x >> 6, lane = threadIdx.x & 63;
        int row = (blockIdx.x - 2048) * 4 + wv;
        if (row >= 101) return;
        float lg = 0.f;
        for (int k = 0; k < 128; k += 8) {
            float mk8[8];
#pragma unroll
            for (int u = 0; u < 8; u++) mk8[u] = Mk[lane * 128 + k + u];
#pragma unroll
            for (int u = 0; u < 8; u++) lg = fmaf(Kemb[row * 128 + k + u], mk8[u], lg);
        }
        float mx = lg;
#pragma unroll
        for (int off = 32; off; off >>= 1) mx = fmaxf(mx, __shfl_xor(mx, off, 64));
        float ex = nexp(lg - mx);
        float sum = ex;
#pragma unroll
        for (int off = 32; off; off >>= 1) sum += __shfl_xor(sum, off, 64);
        wsmall[row * 64 + lane] = ex * nrcp(sum);
        return;
    }
    const int NEH = 10002 * 64;        // pair count per table
    const int T0 = 2 * NEH;            // end EP pairs
    const int T1 = T0 + 147456;        // end Wt
    const int T2 = T1 + 131072;        // end WeaT
    const int T3 = T2 + 32768;         // end WfT
    const int T4 = T3 + 2048;          // end WpT
    for (int i = blockIdx.x * blockDim.x + threadIdx.x; i < T4; i += 2048 * blockDim.x) {
        if (i < NEH) {
            float a = EN[2 * i], b = EN[2 * i + 1];
            ((u32*)ENb)[i] = ((u32)f2b(b) << 16) | f2b(a);
            ((u16*)EN8)[i] = (u16)__builtin_amdgcn_cvt_pk_fp8_f32(a, b, 0, false);
        } else if (i < T0) {
            int j = i - NEH;
            float a = EP[2 * j], b = EP[2 * j + 1];
            ((u32*)EPb)[j] = ((u32)f2b(b) << 16) | f2b(a);
            ((u16*)EP8)[j] = (u16)__builtin_amdgcn_cvt_pk_fp8_f32(a, b, 0, false);
        } else if (i < T1) {
            int w = i - T0;  u32 n = (u32)w / 384u, k = (u32)w % 384u;
            Wt[w] = f2b(Wpt[k * 384 + n]);
        } else if (i < T2) {
            int w = i - T1;  int n = w >> 9, k = w & 511;
            WeaT[w] = f2b((n < 128) ? We[k * 128 + n] : Wa[k * 128 + (n - 128)]);
        } else if (i < T3) {
            int w = i - T2;  int n = w >> 8, k = w & 255;
            WfT[w] = f2b(Wf[k * 128 + n]);
        } else {
            int w = i - T3;  int n = w >> 7, k = w & 127;
            WpT[w] = (n < 10) ? f2b(Wp[k * 10 + n]) : (u16)0;
        }
    }
}

// ---------------------------------------------------------------- k_preM
// grid (626, 3), block 256 = 4 waves. MFMA 16x16x32 bf16; epilogue scales by
// 2*log2e and stores fp8 (k_cw consumes via exp2 directly).
__global__ void k_preM(const u16* __restrict__ ENb, const u16* __restrict__ EPb,
                       const u16* __restrict__ Wt, const float* __restrict__ bpt,
                       u8* __restrict__ PS8, u8* __restrict__ PE8, u8* __restrict__ PP8) {
    int which = blockIdx.y;
    int r0 = blockIdx.x * 16;
    int wv = threadIdx.x >> 6, lane = threadIdx.x & 63;
    int m = lane & 15, quad = lane >> 4;
    const u16* A = (which == 2) ? EPb : ENb;
    int koff = which * 128;
    u8* dst = (which == 0) ? PS8 : (which == 1) ? PE8 : PP8;

    const short8* ap = (const short8*)(A + (r0 + m) * 128 + quad * 8);
    short8 a0 = ap[0], a1 = ap[4], a2 = ap[8], a3 = ap[12];

    for (int nt = 0; nt < 6; nt++) {
        int n0 = wv * 96 + nt * 16;
        const short8* bp = (const short8*)(Wt + (n0 + m) * 384 + koff + quad * 8);
        f32x4 acc = {0.f, 0.f, 0.f, 0.f};
        acc = __builtin_amdgcn_mfma_f32_16x16x32_bf16(a0, bp[0],  acc, 0, 0, 0);
        acc = __builtin_amdgcn_mfma_f32_16x16x32_bf16(a1, bp[4],  acc, 0, 0, 0);
        acc = __builtin_amdgcn_mfma_f32_16x16x32_bf16(a2, bp[8],  acc, 0, 0, 0);
        acc = __builtin_amdgcn_mfma_f32_16x16x32_bf16(a3, bp[12], acc, 0, 0, 0);
        int col = n0 + m;
        float bias = (which == 2) ? bpt[col] : 0.f;
#pragma unroll
        for (int reg = 0; reg < 4; reg++) {
            int row = r0 + quad * 4 + reg;
            if (row < 10002) dst[row * 384 + col] = e8((acc[reg] + bias) * KSCALE);
        }
    }
}

// ---------------------------------------------------------------- k_cw
// grid 8192, block 256 (4 waves). Each wave: 8 consecutive-p triples of one (b,l).
// logit = sum_j (-2*Watt_j) * rcp(1 + exp2(z'_j)); constants dropped (softmax-inv).
__global__ void k_cw(const int* __restrict__ code,
                     const u8* __restrict__ PS8, const u8* __restrict__ PE8,
                     const u8* __restrict__ PP8, const float* __restrict__ Watt,
                     float* __restrict__ cw) {
    int wv = threadIdx.x >> 6, lane = threadIdx.x & 63;
    int t0 = (blockIdx.x * 4 + wv) * 8;
    int b = t0 >> 14;
    int rem = t0 & 16383;
    int l = rem >> 7, p0 = rem & 127;

    const int* c = code + ((b * 128 + l) * 584 + 200 + 3 * p0);
    int si[8], pi[8], ei[8];
#pragma unroll
    for (int i = 0; i < 8; i++) {
        si[i] = __builtin_amdgcn_readfirstlane(c[3 * i]);
        pi[i] = __builtin_amdgcn_readfirstlane(c[3 * i + 1]);
        ei[i] = __builtin_amdgcn_readfirstlane(c[3 * i + 2]);
    }

    int j0 = 6 * lane;
    int o32 = j0 + ((lane & 1) << 1);          // aligned u32 offset
    int o16 = j0 + ((~lane & 1) << 2);         // u16 offset
    float wa0 = -2.f * Watt[o32],     wa1 = -2.f * Watt[o32 + 1];
    float wa2 = -2.f * Watt[o32 + 2], wa3 = -2.f * Watt[o32 + 3];
    float wb0 = -2.f * Watt[o16],     wb1 = -2.f * Watt[o16 + 1];

    u32 xs[8], ys[8], xe[8], ye[8], xq[8], yq[8];
#pragma unroll
    for (int i = 0; i < 8; i++) {
        const u8* bs = PS8 + si[i] * 384;
        const u8* be = PE8 + ei[i] * 384;
        const u8* bq = PP8 + pi[i] * 384;
        xs[i] = *(const u32*)(bs + o32); ys[i] = *(const u16*)(bs + o16);
        xe[i] = *(const u32*)(be + o32); ye[i] = *(const u16*)(be + o16);
        xq[i] = *(const u32*)(bq + o32); yq[i] = *(const u16*)(bq + o16);
    }

#pragma unroll
    for (int i = 0; i < 8; i++) {
        f32x2 zA = d8(xs[i], false) + d8(xe[i], false) + d8(xq[i], false);
        f32x2 zB = d8(xs[i], true)  + d8(xe[i], true)  + d8(xq[i], true);
        f32x2 zC = d8(ys[i], false) + d8(ye[i], false) + d8(yq[i], false);

        float acc = nrcp(1.f + __builtin_amdgcn_exp2f(zA.x)) * wa0;
        acc = fmaf(nrcp(1.f + __builtin_amdgcn_exp2f(zA.y)), wa1, acc);
        acc = fmaf(nrcp(1.f + __builtin_amdgcn_exp2f(zB.x)), wa2, acc);
        acc = fmaf(nrcp(1.f + __builtin_amdgcn_exp2f(zB.y)), wa3, acc);
        acc = fmaf(nrcp(1.f + __builtin_amdgcn_exp2f(zC.x)), wb0, acc);
        acc = fmaf(nrcp(1.f + __builtin_amdgcn_exp2f(zC.y)), wb1, acc);

#pragma unroll
        for (int off = 32; off; off >>= 1) acc += __shfl_down(acc, off, 64);
        if (lane == 0) cw[(b * 128 + p0 + i) * 128 + l] = acc;
    }
}

// ---------------------------------------------------------------- k_sm
// grid 128 = (b, ptile16), block 256. Softmax over l per p; LDS transpose.
__global__ void k_sm(const float* __restrict__ cw, float* __restrict__ attn) {
    int b = blockIdx.x >> 3, p0 = (blockIdx.x & 7) * 16;
    int tid = threadIdx.x;
    int wv = tid >> 6, lane = tid & 63;
    __shared__ float tile[16][128];
    __shared__ float atile[128][17];
    for (int idx = tid; idx < 2048; idx += 256) {
        int pp = idx >> 7, l = idx & 127;
        tile[pp][l] = cw[(b * 128 + p0 + pp) * 128 + l];
    }
    __syncthreads();
#pragma unroll
    for (int pl = 0; pl < 4; pl++) {
        int pp = wv * 4 + pl;
        float x0 = tile[pp][lane], x1 = tile[pp][64 + lane];
        float mx = fmaxf(x0, x1);
#pragma unroll
        for (int off = 32; off; off >>= 1) mx = fmaxf(mx, __shfl_xor(mx, off, 64));
        float e0 = nexp(x0 - mx), e1 = nexp(x1 - mx);
        float sum = e0 + e1;
#pragma unroll
        for (int off = 32; off; off >>= 1) sum += __shfl_xor(sum, off, 64);
        float inv = nrcp(sum);
        atile[lane][pp] = e0 * inv;
        atile[64 + lane][pp] = e1 * inv;
    }
    __syncthreads();
    for (int idx = tid; idx < 2048; idx += 256) {
        int l = idx >> 4, pp = idx & 15;
        attn[(b * 128 + l) * 128 + p0 + pp] = atile[l][pp];
    }
}

// ---------------------------------------------------------------- k_cv
// grid 2048 = (b,l), block 256 = 4 waves. fp8 gathers (EN8/EP8 L2-resident).
__global__ void k_cv(const int* __restrict__ code, const float* __restrict__ attn,
                     const u8* __restrict__ EN8, const u8* __restrict__ EP8,
                     const int* __restrict__ rr, const int* __restrict__ qq,
                     const float* __restrict__ Vemb, const float* __restrict__ Kemb,
                     u16* __restrict__ vA, u16* __restrict__ fA) {
    int row = blockIdx.x;
    int tid = threadIdx.x;
    int wv = tid >> 6, lane = tid & 63;
    __shared__ int si[128], ei[128], pi[128];
    __shared__ float at[128];
    __shared__ float part[4][3][128];
    if (tid < 128) {
        const int* c = code + (row * 584 + 200);
        si[tid] = c[3 * tid]; pi[tid] = c[3 * tid + 1]; ei[tid] = c[3 * tid + 2];
        at[tid] = attn[row * 128 + tid];
    }
    if (tid < 128) {
        vA[row * 512 + tid] = f2b(Vemb[rr[row] * 128 + tid]);
    } else {
        int t2 = tid - 128;
        fA[row * 256 + 128 + t2] = f2b(Kemb[qq[row] * 128 + t2]);
    }
    __syncthreads();
    float a0 = 0.f, a1 = 0.f, b0 = 0.f, b1 = 0.f, c0 = 0.f, c1 = 0.f;
    int o = 2 * lane;
    for (int p = wv; p < 128; p += 8) {
        int p2 = p + 4;
        float w = at[p], w2 = at[p2];
        u32 us = *(const u16*)(EN8 + si[p] * 128 + o);
        u32 ue = *(const u16*)(EN8 + ei[p] * 128 + o);
        u32 up = *(const u16*)(EP8 + pi[p] * 128 + o);
        u32 vs = *(const u16*)(EN8 + si[p2] * 128 + o);
        u32 ve = *(const u16*)(EN8 + ei[p2] * 128 + o);
        u32 vp = *(const u16*)(EP8 + pi[p2] * 128 + o);
        f32x2 fs = d8(us, false), fe = d8(ue, false), fp = d8(up, false);
        f32x2 gs = d8(vs, false), ge = d8(ve, false), gp = d8(vp, false);
        a0 = fmaf(w, fs.x, a0); a1 = fmaf(w, fs.y, a1);
        b0 = fmaf(w, fe.x, b0); b1 = fmaf(w, fe.y, b1);
        c0 = fmaf(w, fp.x, c0); c1 = fmaf(w, fp.y, c1);
        a0 = fmaf(w2, gs.x, a0); a1 = fmaf(w2, gs.y, a1);
        b0 = fmaf(w2, ge.x, b0); b1 = fmaf(w2, ge.y, b1);
        c0 = fmaf(w2, gp.x, c0); c1 = fmaf(w2, gp.y, c1);
    }
    part[wv][0][2 * lane] = a0; part[wv][0][2 * lane + 1] = a1;
    part[wv][1][2 * lane] = b0; part[wv][1][2 * lane + 1] = b1;
    part[wv][2][2 * lane] = c0; part[wv][2][2 * lane + 1] = c1;
    __syncthreads();
    u16* vrow = vA + row * 512 + 128;
    for (int idx = tid; idx < 384; idx += 256) {
        int tbl = idx >> 7, col = idx & 127;
        vrow[idx] = f2b(part[0][tbl][col] + part[1][tbl][col] + part[2][tbl][col] + part[3][tbl][col]);
    }
}

// ---------------------------------------------------------------- k_eawM
// grid 512, block 256 (4 waves). C[2048][256] = vA @ WeaT^T via MFMA. K=512.
__global__ void k_eawM(const u16* __restrict__ vA, const u16* __restrict__ WeaT,
                       const float* __restrict__ be, const float* __restrict__ ba,
                       float* __restrict__ eb, float* __restrict__ ab) {
    int rt = blockIdx.x >> 2, cg = blockIdx.x & 3;
    int wv = threadIdx.x >> 6, lane = threadIdx.x & 63;
    int ct = cg * 4 + wv;
    int m = lane & 15, quad = lane >> 4;
    const short8* ap = (const short8*)(vA + (rt * 16 + m) * 512 + quad * 8);
    const short8* bp = (const short8*)(WeaT + (ct * 16 + m) * 512 + quad * 8);
    f32x4 acc = {0.f, 0.f, 0.f, 0.f};
#pragma unroll
    for (int kc = 0; kc < 16; kc++)
        acc = __builtin_amdgcn_mfma_f32_16x16x32_bf16(ap[kc * 4], bp[kc * 4], acc, 0, 0, 0);
    int col = ct * 16 + m;
    bool isA = col >= 128;
    int c2 = isA ? col - 128 : col;
    float bias = isA ? ba[c2] : be[c2];
#pragma unroll
    for (int reg = 0; reg < 4; reg++) {
        int row = rt * 16 + quad * 4 + reg;
        float val = acc[reg] + bias;
        if (isA) ab[row * 128 + c2] = fast_tanh(val);
        else     eb[row * 128 + c2] = sigmoidf_(val);
    }
}

// ---------------------------------------------------------------- k_scan
// grid 256 = b(16) x dblk(16), block 64. LDS-staged wsmall + e/a tile + q.
__global__ void k_scan(const float* __restrict__ Mv0, const float* __restrict__ eb,
                       const float* __restrict__ ab, const float* __restrict__ wsmall,
                       const int* __restrict__ qq, u16* __restrict__ fA) {
    int b = blockIdx.x >> 4, dblk = blockIdx.x & 15;
    int lane = threadIdx.x;
    int s = lane >> 3, dlo = lane & 7;
    int d = dblk * 8 + dlo;

    __shared__ float wsm[101 * 64];
    __shared__ float el[128][8];
    __shared__ float al[128][8];
    __shared__ int ql[128];

    for (int i = lane; i < 101 * 64; i += 64) wsm[i] = wsmall[i];
    for (int i = lane; i < 1024; i += 64) {
        int t = i >> 3, dl = i & 7;
        el[t][dl] = eb[(b * 128 + t) * 128 + dblk * 8 + dl];
        al[t][dl] = ab[(b * 128 + t) * 128 + dblk * 8 + dl];
    }
    for (int i = lane; i < 128; i += 64) ql[i] = qq[b * 128 + i];
    __syncthreads();

    float mv[8];
#pragma unroll
    for (int q = 0; q < 8; q++) mv[q] = Mv0[(s * 8 + q) * 128 + d];

    u16* fout = fA + (b * 128) * 256 + d;

    int qt = ql[0];
    const float4* wr = (const float4*)(wsm + qt * 64 + s * 8);
    float4 w0 = wr[0], w1 = wr[1];
    float ecur = el[0][dlo], acur = al[0][dlo];

    for (int t = 0; t < 128; t++) {
        int tn = (t < 127) ? t + 1 : 127;
        int qn = ql[tn];
        const float4* wrn = (const float4*)(wsm + qn * 64 + s * 8);
        float4 nw0 = wrn[0], nw1 = wrn[1];
        float en = el[tn][dlo], an = al[tn][dlo];

        float w[8] = { w0.x, w0.y, w0.z, w0.w, w1.x, w1.y, w1.z, w1.w };
        float rd = 0.f;
#pragma unroll
        for (int q = 0; q < 8; q++) {
            rd = fmaf(w[q], mv[q], rd);
            mv[q] = fmaf(w[q], fmaf(-mv[q], ecur, acur), mv[q]);
        }
        rd += __shfl_xor(rd, 8, 64);
        rd += __shfl_xor(rd, 16, 64);
        rd += __shfl_xor(rd, 32, 64);
        if (s == 0) fout[t * 256] = f2b(rd);

        ecur = en; acur = an; w0 = nw0; w1 = nw1;
    }
}

// ---------------------------------------------------------------- k_outfin
// grid 128, block 512 (8 waves). Wave wv computes f tile rows rt*16..+15 x cols
// wv*16..+15 (K=256 MFMA), tanh -> LDS bf16. Then wave 0: out = sigmoid(f @ WpT^T + b_p).
__global__ void k_outfin(const u16* __restrict__ fA, const u16* __restrict__ WfT,
                         const float* __restrict__ bfp, const u16* __restrict__ WpT,
                         const float* __restrict__ bp, float* __restrict__ out) {
    int rt = blockIdx.x;
    int wv = threadIdx.x >> 6, lane = threadIdx.x & 63;
    int m = lane & 15, quad = lane >> 4;
    __shared__ u16 ftile[16][128];

    const short8* ap = (const short8*)(fA + (rt * 16 + m) * 256 + quad * 8);
    const short8* bpw = (const short8*)(WfT + (wv * 16 + m) * 256 + quad * 8);
    f32x4 acc = {0.f, 0.f, 0.f, 0.f};
#pragma unroll
    for (int kc = 0; kc < 8; kc++)
        acc = __builtin_amdgcn_mfma_f32_16x16x32_bf16(ap[kc * 4], bpw[kc * 4], acc, 0, 0, 0);
    int col = wv * 16 + m;
    float bias = bfp[col];
#pragma unroll
    for (int reg = 0; reg < 4; reg++)
        ftile[quad * 4 + reg][col] = f2b(fast_tanh(acc[reg] + bias));
    __syncthreads();

    if (wv == 0) {
        f32x4 facc = {0.f, 0.f, 0.f, 0.f};
#pragma unroll
        for (int kc = 0; kc < 4; kc++) {
            short8 af = *(const short8*)(&ftile[m][kc * 32 + quad * 8]);
            short8 bf = *(const short8*)(WpT + m * 128 + kc * 32 + quad * 8);
            facc = __builtin_amdgcn_mfma_f32_16x16x32_bf16(af, bf, facc, 0, 0, 0);
        }
        if (m < 10) {
            float bias2 = bp[m];
#pragma unroll
            for (int reg = 0; reg < 4; reg++) {
                int row = rt * 16 + quad * 4 + reg;
                out[row * 10 + m] = sigmoidf_(facc[reg] + bias2);
            }
        }
    }
}

extern "C" void kernel_launch(void* const* d_in, const int* in_sizes, int n_in,
                              void* d_out, int out_size, void* d_ws, size_t ws_size,
                              hipStream_t stream) {
    const int*   code = (const int*)d_in[0];
    const int*   q    = (const int*)d_in[1];
    const int*   r    = (const int*)d_in[2];
    const float* EN   = (const float*)d_in[3];
    const float* EP   = (const float*)d_in[4];
    const float* Wpt  = (const float*)d_in[5];
    const float* bpt  = (const float*)d_in[6];
    const float* Watt = (const float*)d_in[7];
    const float* Kemb = (const float*)d_in[9];
    const float* Mk   = (const float*)d_in[10];
    const float* Mv0  = (const float*)d_in[11];
    const float* Vemb = (const float*)d_in[12];
    const float* We   = (const float*)d_in[13];
    const float* be   = (const float*)d_in[14];
    const float* Wa   = (const float*)d_in[15];
    const float* ba   = (const float*)d_in[16];
    const float* Wf   = (const float*)d_in[17];
    const float* bf_  = (const float*)d_in[18];
    const float* Wp   = (const float*)d_in[19];
    const float* bp   = (const float*)d_in[20];

    char* ws = (char*)d_ws;
    size_t off = 0;
    auto alloc = [&](size_t bytes) { void* p = ws + off; off = (off + bytes + 255) & ~255UL; return p; };
    u8*    PS8    = (u8*)alloc(10002UL * 384);
    u8*    PE8    = (u8*)alloc(10002UL * 384);
    u8*    PP8    = (u8*)alloc(10002UL * 384);
    u16*   ENb    = (u16*)alloc(10002UL * 128 * 2);
    u16*   EPb    = (u16*)alloc(10016UL * 128 * 2);   // +14 rows pad: k_preM tail reads
    u8*    EN8    = (u8*)alloc(10002UL * 128);
    u8*    EP8    = (u8*)alloc(10002UL * 128);
    u16*   Wt     = (u16*)alloc(384UL * 384 * 2);
    u16*   WeaT   = (u16*)alloc(256UL * 512 * 2);
    u16*   WfT    = (u16*)alloc(128UL * 256 * 2);
    u16*   WpT    = (u16*)alloc(16UL * 128 * 2);
    float* cw     = (float*)alloc(16UL * 128 * 128 * 4);   // [b][p][l]
    float* attn   = (float*)alloc(16UL * 128 * 128 * 4);   // [b][l][p]
    u16*   vA     = (u16*)alloc(2048UL * 512 * 2);         // [Vemb[r] ; code_vec] bf16
    u16*   fA     = (u16*)alloc(2048UL * 256 * 2);         // [read ; Kemb[q]] bf16
    float* eb     = (float*)alloc(2048UL * 128 * 4);
    float* ab     = (float*)alloc(2048UL * 128 * 4);
    float* wsmall = (float*)alloc(101UL * 64 * 4);

    k_conv<<<2048 + 26, 256, 0, stream>>>(EN, EP, Wpt, We, Wa, Wf, Wp, Kemb, Mk,
                                          ENb, EPb, EN8, EP8, Wt, WeaT, WfT, WpT, wsmall);
    k_preM<<<dim3(626, 3), 256, 0, stream>>>(ENb, EPb, Wt, bpt, PS8, PE8, PP8);
    k_cw<<<8192, 256, 0, stream>>>(code, PS8, PE8, PP8, Watt, cw);
    k_sm<<<128, 256, 0, stream>>>(cw, attn);
    k_cv<<<2048, 256, 0, stream>>>(code, attn, EN8, EP8, r, q, Vemb, Kemb, vA, fA);
    k_eawM<<<512, 256, 0, stream>>>(vA, WeaT, be, ba, eb, ab);
    k_scan<<<256, 64, 0, stream>>>(Mv0, eb, ab, wsmall, q, fA);
    k_outfin<<<128, 512, 0, stream>>>(fA, WfT, bf_, WpT, bp, (float*)d_out);
}

// Round 9
// 226.162 us; speedup vs baseline: 3.1852x; 1.1415x over previous
//
#include <hip/hip_runtime.h>

// DKVMN + code2vec attention. Sizes (fixed):
// B=16 L=128 P=128 NUM_C=100 D=128 M=64 EMB=128 TE=384 CODE_W=584 NROW=10002
//
// Inputs/outputs f32. MFMA operands bf16; gather tables fp8 e4m3.
// k_cw algebra: tanh identity + softmax shift-invariance =>
//   logit'[b,p,l] = -2 * sum_j Watt_j * rcp(1 + exp2(z'_j)),  z' = z*2log2e
// k_cw topology: 16 lanes per triple (24 B/lane of each 384-B fp8 row), 4
// concurrent triples per wave -> 4 shared shfl_xor levels instead of 6x64->1.
//
//  k_conv  : ENb/EPb bf16 + EN8/EP8 fp8 (single read), transposed bf16 Wt/WeaT/
//            WfT/WpT; extra blocks compute wsmall[q][m]=softmax(k_emb[q]@Mk^T)
//  k_preM  : PS8/PE8/PP8 = fp8((emb @ Wpt slice)*2log2e) via MFMA, 32 rows/block
//  k_cw    : logits via fp8 gathers, rcp-only form, 16-lane groups
//  k_sm    : softmax over l per (b,p); LDS transpose -> coalesced attn[b,l,p]
//  k_cv    : vA[row]=[Vemb[r];code_vec] bf16 (fp8 gathers, prefetched)
//  k_eawM  : e|a = act(vA @ WeaT + b) via MFMA
//  k_scan  : sequential scan, LDS-staged state; read -> fA bf16
//  k_outfin: f = tanh(fA @ WfT + b_f) (LDS) then out = sigmoid(f @ WpT + b_p)

typedef unsigned char u8;
typedef unsigned short u16;
typedef unsigned int u32;
typedef __attribute__((ext_vector_type(8))) short short8;   // 8 bf16 (4 VGPRs)
typedef __attribute__((ext_vector_type(4))) float f32x4;    // MFMA C/D
typedef __attribute__((ext_vector_type(2))) float f32x2;

#define DEV __device__ __forceinline__
#define LOG2E 1.4426950408889634f
#define KSCALE 2.8853900817779268f   // 2*log2(e)

DEV u16 f2b(float f) {
    union { float f; u32 i; } v; v.f = f;
    u32 x = v.i;
    u32 r = (x + 0x7FFFu + ((x >> 16) & 1u)) >> 16;   // RNE
    return (u16)r;
}
DEV float nexp(float x) { return __builtin_amdgcn_exp2f(x * LOG2E); }
DEV float nrcp(float x) { return __builtin_amdgcn_rcpf(x); }
DEV float fast_tanh(float x) {
    return 1.f - 2.f * nrcp(1.f + __builtin_amdgcn_exp2f(x * (2.f * LOG2E)));
}
DEV float sigmoidf_(float x) { return nrcp(1.f + __builtin_amdgcn_exp2f(-x * LOG2E)); }
DEV f32x2 d8(u32 x, bool hi) {                 // decode 2 fp8 e4m3 -> 2 f32
    return hi ? __builtin_amdgcn_cvt_pk_f32_fp8((int)x, true)
              : __builtin_amdgcn_cvt_pk_f32_fp8((int)x, false);
}
DEV u8 e8(float x) {                           // encode f32 -> fp8 e4m3
    return (u8)(__builtin_amdgcn_cvt_pk_fp8_f32(x, x, 0, false) & 0xFF);
}

// ---------------------------------------------------------------- k_conv
// blocks <2048: grid-stride pair-indexed segments:
//   EN pairs -> ENb(u32)+EN8(u16) | EP pairs | Wt | WeaT | WfT | WpT
// blocks >=2048: wsmall (4 rows/block, one per wave).
__global__ void k_conv(const float* __restrict__ EN, const float* __restrict__ EP,
                       const float* __restrict__ Wpt, const float* __restrict__ We,
                       const float* __restrict__ Wa, const float* __restrict__ Wf,
                       const float* __restrict__ Wp,
                       const float* __restrict__ Kemb, const float* __restrict__ Mk,
                       u16* __restrict__ ENb, u16* __restrict__ EPb,
                       u8* __restrict__ EN8, u8* __restrict__ EP8,
                       u16* __restrict__ Wt, u16* __restrict__ WeaT,
                       u16* __restrict__ WfT, u16* __restrict__ WpT,
                       float* __restrict__ wsmall) {
    if (blockIdx.x >= 2048) {                      // ---- wsmall part
        int wv = threadIdx.x >> 6, lane = threadIdx.x & 63;
        int row = (blockIdx.x - 2048) * 4 + wv;
        if (row >= 101) return;
        float lg = 0.f;
        for (int k = 0; k < 128; k += 8) {
            float mk8[8];
#pragma unroll
            for (int u = 0; u < 8; u++) mk8[u] = Mk[lane * 128 + k + u];
#pragma unroll
            for (int u = 0; u < 8; u++) lg = fmaf(Kemb[row * 128 + k + u], mk8[u], lg);
        }
        float mx = lg;
#pragma unroll
        for (int off = 32; off; off >>= 1) mx = fmaxf(mx, __shfl_xor(mx, off, 64));
        float ex = nexp(lg - mx);
        float sum = ex;
#pragma unroll
        for (int off = 32; off; off >>= 1) sum += __shfl_xor(sum, off, 64);
        wsmall[row * 64 + lane] = ex * nrcp(sum);
        return;
    }
    const int NEH = 10002 * 64;        // pair count per table
    const int T0 = 2 * NEH;            // end EP pairs
    const int T1 = T0 + 147456;        // end Wt
    const int T2 = T1 + 131072;        // end WeaT
    const int T3 = T2 + 32768;         // end WfT
    const int T4 = T3 + 2048;          // end WpT
    for (int i = blockIdx.x * blockDim.x + threadIdx.x; i < T4; i += 2048 * blockDim.x) {
        if (i < NEH) {
            float a = EN[2 * i], b = EN[2 * i + 1];
            ((u32*)ENb)[i] = ((u32)f2b(b) << 16) | f2b(a);
            ((u16*)EN8)[i] = (u16)__builtin_amdgcn_cvt_pk_fp8_f32(a, b, 0, false);
        } else if (i < T0) {
            int j = i - NEH;
            float a = EP[2 * j], b = EP[2 * j + 1];
            ((u32*)EPb)[j] = ((u32)f2b(b) << 16) | f2b(a);
            ((u16*)EP8)[j] = (u16)__builtin_amdgcn_cvt_pk_fp8_f32(a, b, 0, false);
        } else if (i < T1) {
            int w = i - T0;  u32 n = (u32)w / 384u, k = (u32)w % 384u;
            Wt[w] = f2b(Wpt[k * 384 + n]);
        } else if (i < T2) {
            int w = i - T1;  int n = w >> 9, k = w & 511;
            WeaT[w] = f2b((n < 128) ? We[k * 128 + n] : Wa[k * 128 + (n - 128)]);
        } else if (i < T3) {
            int w = i - T2;  int n = w >> 8, k = w & 255;
            WfT[w] = f2b(Wf[k * 128 + n]);
        } else {
            int w = i - T3;  int n = w >> 7, k = w & 127;
            WpT[w] = (n < 10) ? f2b(Wp[k * 10 + n]) : (u16)0;
        }
    }
}

// ---------------------------------------------------------------- k_preM
// grid (313, 3), block 256 = 4 waves. 32 rows x 384 cols per block (each block
// reads full Wt once -> halved L2 traffic vs 16-row blocks). MFMA 16x16x32 bf16;
// epilogue scales by 2*log2e, stores fp8.
__global__ void k_preM(const u16* __restrict__ ENb, const u16* __restrict__ EPb,
                       const u16* __restrict__ Wt, const float* __restrict__ bpt,
                       u8* __restrict__ PS8, u8* __restrict__ PE8, u8* __restrict__ PP8) {
    int which = blockIdx.y;
    int r0 = blockIdx.x * 32;
    int wv = threadIdx.x >> 6, lane = threadIdx.x & 63;
    int m = lane & 15, quad = lane >> 4;
    const u16* A = (which == 2) ? EPb : ENb;
    int koff = which * 128;
    u8* dst = (which == 0) ? PS8 : (which == 1) ? PE8 : PP8;

    short8 a[2][4];
#pragma unroll
    for (int rt = 0; rt < 2; rt++) {
        const short8* ap = (const short8*)(A + (r0 + rt * 16 + m) * 128 + quad * 8);
#pragma unroll
        for (int kc = 0; kc < 4; kc++) a[rt][kc] = ap[kc * 4];
    }

    for (int nt = 0; nt < 6; nt++) {
        int n0 = wv * 96 + nt * 16;
        const short8* bp = (const short8*)(Wt + (n0 + m) * 384 + koff + quad * 8);
        short8 b0 = bp[0], b1 = bp[4], b2 = bp[8], b3 = bp[12];
        int col = n0 + m;
        float bias = (which == 2) ? bpt[col] : 0.f;
#pragma unroll
        for (int rt = 0; rt < 2; rt++) {
            f32x4 acc = {0.f, 0.f, 0.f, 0.f};
            acc = __builtin_amdgcn_mfma_f32_16x16x32_bf16(a[rt][0], b0, acc, 0, 0, 0);
            acc = __builtin_amdgcn_mfma_f32_16x16x32_bf16(a[rt][1], b1, acc, 0, 0, 0);
            acc = __builtin_amdgcn_mfma_f32_16x16x32_bf16(a[rt][2], b2, acc, 0, 0, 0);
            acc = __builtin_amdgcn_mfma_f32_16x16x32_bf16(a[rt][3], b3, acc, 0, 0, 0);
#pragma unroll
            for (int reg = 0; reg < 4; reg++) {
                int row = r0 + rt * 16 + quad * 4 + reg;
                if (row < 10002) dst[row * 384 + col] = e8((acc[reg] + bias) * KSCALE);
            }
        }
    }
}

// ---------------------------------------------------------------- k_cw
// grid 8192, block 256 (4 waves). Wave: 8 triples of one (b,l) in 2 batches of 4.
// Group g (16 lanes) owns one triple; lane gl covers j = gl*24 .. +23 via
// 3x dwordx2 per table. Reduce: 4 shfl_xor levels within the group.
__global__ void k_cw(const int* __restrict__ code,
                     const u8* __restrict__ PS8, const u8* __restrict__ PE8,
                     const u8* __restrict__ PP8, const float* __restrict__ Watt,
                     float* __restrict__ cw) {
    int wv = threadIdx.x >> 6, lane = threadIdx.x & 63;
    int g = lane >> 4, gl = lane & 15;
    int t0 = (blockIdx.x * 4 + wv) * 8;
    int b = t0 >> 14;
    int rem = t0 & 16383;
    int l = rem >> 7, p0 = rem & 127;

    const int* c = code + ((b * 128 + l) * 584 + 200 + 3 * p0);
    int si[8], pi[8], ei[8];
#pragma unroll
    for (int i = 0; i < 8; i++) {
        si[i] = __builtin_amdgcn_readfirstlane(c[3 * i]);
        pi[i] = __builtin_amdgcn_readfirstlane(c[3 * i + 1]);
        ei[i] = __builtin_amdgcn_readfirstlane(c[3 * i + 2]);
    }

    // Watt[gl*24 .. +23], pre-scaled by -2 (tanh-identity constant folded;
    // the +sum(Watt)+b_att constant cancels in the l-softmax)
    float w24[24];
    const float4* wp = (const float4*)(Watt + gl * 24);
#pragma unroll
    for (int u = 0; u < 6; u++) {
        float4 f = wp[u];
        w24[4 * u + 0] = -2.f * f.x; w24[4 * u + 1] = -2.f * f.y;
        w24[4 * u + 2] = -2.f * f.z; w24[4 * u + 3] = -2.f * f.w;
    }

    float res[2];
#pragma unroll
    for (int batch = 0; batch < 2; batch++) {
        int i = batch * 4 + g;
        const uint2* bs = (const uint2*)(PS8 + si[i] * 384 + gl * 24);
        const uint2* be = (const uint2*)(PE8 + ei[i] * 384 + gl * 24);
        const uint2* bq = (const uint2*)(PP8 + pi[i] * 384 + gl * 24);
        uint2 s0 = bs[0], s1 = bs[1], s2 = bs[2];
        uint2 e0 = be[0], e1 = be[1], e2 = be[2];
        uint2 q0 = bq[0], q1 = bq[1], q2 = bq[2];

        float acc = 0.f;
        u32 sv[6] = { s0.x, s0.y, s1.x, s1.y, s2.x, s2.y };
        u32 ev[6] = { e0.x, e0.y, e1.x, e1.y, e2.x, e2.y };
        u32 qv[6] = { q0.x, q0.y, q1.x, q1.y, q2.x, q2.y };
#pragma unroll
        for (int u = 0; u < 6; u++) {
            f32x2 zl = d8(sv[u], false) + d8(ev[u], false) + d8(qv[u], false);
            f32x2 zh = d8(sv[u], true)  + d8(ev[u], true)  + d8(qv[u], true);
            acc = fmaf(nrcp(1.f + __builtin_amdgcn_exp2f(zl.x)), w24[4 * u + 0], acc);
            acc = fmaf(nrcp(1.f + __builtin_amdgcn_exp2f(zl.y)), w24[4 * u + 1], acc);
            acc = fmaf(nrcp(1.f + __builtin_amdgcn_exp2f(zh.x)), w24[4 * u + 2], acc);
            acc = fmaf(nrcp(1.f + __builtin_amdgcn_exp2f(zh.y)), w24[4 * u + 3], acc);
        }
        acc += __shfl_xor(acc, 1, 64);
        acc += __shfl_xor(acc, 2, 64);
        acc += __shfl_xor(acc, 4, 64);
        acc += __shfl_xor(acc, 8, 64);
        res[batch] = acc;
    }
    if (gl == 0) {
        cw[(b * 128 + p0 + g) * 128 + l] = res[0];
        cw[(b * 128 + p0 + 4 + g) * 128 + l] = res[1];
    }
}

// ---------------------------------------------------------------- k_sm
// grid 128 = (b, ptile16), block 256. Softmax over l per p; LDS transpose.
__global__ void k_sm(const float* __restrict__ cw, float* __restrict__ attn) {
    int b = blockIdx.x >> 3, p0 = (blockIdx.x & 7) * 16;
    int tid = threadIdx.x;
    int wv = tid >> 6, lane = tid & 63;
    __shared__ float tile[16][128];
    __shared__ float atile[128][17];
    for (int idx = tid; idx < 2048; idx += 256) {
        int pp = idx >> 7, l = idx & 127;
        tile[pp][l] = cw[(b * 128 + p0 + pp) * 128 + l];
    }
    __syncthreads();
#pragma unroll
    for (int pl = 0; pl < 4; pl++) {
        int pp = wv * 4 + pl;
        float x0 = tile[pp][lane], x1 = tile[pp][64 + lane];
        float mx = fmaxf(x0, x1);
#pragma unroll
        for (int off = 32; off; off >>= 1) mx = fmaxf(mx, __shfl_xor(mx, off, 64));
        float e0 = nexp(x0 - mx), e1 = nexp(x1 - mx);
        float sum = e0 + e1;
#pragma unroll
        for (int off = 32; off; off >>= 1) sum += __shfl_xor(sum, off, 64);
        float inv = nrcp(sum);
        atile[lane][pp] = e0 * inv;
        atile[64 + lane][pp] = e1 * inv;
    }
    __syncthreads();
    for (int idx = tid; idx < 2048; idx += 256) {
        int l = idx >> 4, pp = idx & 15;
        attn[(b * 128 + l) * 128 + p0 + pp] = atile[l][pp];
    }
}

// ---------------------------------------------------------------- k_cv
// grid 2048 = (b,l), block 256 = 4 waves. fp8 gathers, software-pipelined
// (next iteration's 6 row-loads issued before current compute).
__global__ void k_cv(const int* __restrict__ code, const float* __restrict__ attn,
                     const u8* __restrict__ EN8, const u8* __restrict__ EP8,
                     const int* __restrict__ rr, const int* __restrict__ qq,
                     const float* __restrict__ Vemb, const float* __restrict__ Kemb,
                     u16* __restrict__ vA, u16* __restrict__ fA) {
    int row = blockIdx.x;
    int tid = threadIdx.x;
    int wv = tid >> 6, lane = tid & 63;
    __shared__ int si[128], ei[128], pi[128];
    __shared__ float at[128];
    __shared__ float part[4][3][128];
    if (tid < 128) {
        const int* c = code + (row * 584 + 200);
        si[tid] = c[3 * tid]; pi[tid] = c[3 * tid + 1]; ei[tid] = c[3 * tid + 2];
        at[tid] = attn[row * 128 + tid];
    }
    if (tid < 128) {
        vA[row * 512 + tid] = f2b(Vemb[rr[row] * 128 + tid]);
    } else {
        int t2 = tid - 128;
        fA[row * 256 + 128 + t2] = f2b(Kemb[qq[row] * 128 + t2]);
    }
    __syncthreads();
    float a0 = 0.f, a1 = 0.f, b0 = 0.f, b1 = 0.f, c0 = 0.f, c1 = 0.f;
    int o = 2 * lane;

    u32 cur[6];
    {
        int p = wv, p2 = wv + 4;
        cur[0] = *(const u16*)(EN8 + si[p] * 128 + o);
        cur[1] = *(const u16*)(EN8 + ei[p] * 128 + o);
        cur[2] = *(const u16*)(EP8 + pi[p] * 128 + o);
        cur[3] = *(const u16*)(EN8 + si[p2] * 128 + o);
        cur[4] = *(const u16*)(EN8 + ei[p2] * 128 + o);
        cur[5] = *(const u16*)(EP8 + pi[p2] * 128 + o);
    }
#pragma unroll
    for (int it = 0; it < 16; it++) {
        int p = wv + it * 8;
        u32 nxt[6];
        if (it < 15) {
            int pn = p + 8, pn2 = p + 12;
            nxt[0] = *(const u16*)(EN8 + si[pn] * 128 + o);
            nxt[1] = *(const u16*)(EN8 + ei[pn] * 128 + o);
            nxt[2] = *(const u16*)(EP8 + pi[pn] * 128 + o);
            nxt[3] = *(const u16*)(EN8 + si[pn2] * 128 + o);
            nxt[4] = *(const u16*)(EN8 + ei[pn2] * 128 + o);
            nxt[5] = *(const u16*)(EP8 + pi[pn2] * 128 + o);
        }
        float w = at[p], w2 = at[p + 4];
        f32x2 fs = d8(cur[0], false), fe = d8(cur[1], false), fp = d8(cur[2], false);
        f32x2 gs = d8(cur[3], false), ge = d8(cur[4], false), gp = d8(cur[5], false);
        a0 = fmaf(w, fs.x, a0); a1 = fmaf(w, fs.y, a1);
        b0 = fmaf(w, fe.x, b0); b1 = fmaf(w, fe.y, b1);
        c0 = fmaf(w, fp.x, c0); c1 = fmaf(w, fp.y, c1);
        a0 = fmaf(w2, gs.x, a0); a1 = fmaf(w2, gs.y, a1);
        b0 = fmaf(w2, ge.x, b0); b1 = fmaf(w2, ge.y, b1);
        c0 = fmaf(w2, gp.x, c0); c1 = fmaf(w2, gp.y, c1);
        if (it < 15) {
#pragma unroll
            for (int z = 0; z < 6; z++) cur[z] = nxt[z];
        }
    }
    part[wv][0][2 * lane] = a0; part[wv][0][2 * lane + 1] = a1;
    part[wv][1][2 * lane] = b0; part[wv][1][2 * lane + 1] = b1;
    part[wv][2][2 * lane] = c0; part[wv][2][2 * lane + 1] = c1;
    __syncthreads();
    u16* vrow = vA + row * 512 + 128;
    for (int idx = tid; idx < 384; idx += 256) {
        int tbl = idx >> 7, col = idx & 127;
        vrow[idx] = f2b(part[0][tbl][col] + part[1][tbl][col] + part[2][tbl][col] + part[3][tbl][col]);
    }
}

// ---------------------------------------------------------------- k_eawM
// grid 512, block 256 (4 waves). C[2048][256] = vA @ WeaT^T via MFMA. K=512.
__global__ void k_eawM(const u16* __restrict__ vA, const u16* __restrict__ WeaT,
                       const float* __restrict__ be, const float* __restrict__ ba,
                       float* __restrict__ eb, float* __restrict__ ab) {
    int rt = blockIdx.x >> 2, cg = blockIdx.x & 3;
    int wv = threadIdx.x >> 6, lane = threadIdx.x & 63;
    int ct = cg * 4 + wv;
    int m = lane & 15, quad = lane >> 4;
    const short8* ap = (const short8*)(vA + (rt * 16 + m) * 512 + quad * 8);
    const short8* bp = (const short8*)(WeaT + (ct * 16 + m) * 512 + quad * 8);
    f32x4 acc = {0.f, 0.f, 0.f, 0.f};
#pragma unroll
    for (int kc = 0; kc < 16; kc++)
        acc = __builtin_amdgcn_mfma_f32_16x16x32_bf16(ap[kc * 4], bp[kc * 4], acc, 0, 0, 0);
    int col = ct * 16 + m;
    bool isA = col >= 128;
    int c2 = isA ? col - 128 : col;
    float bias = isA ? ba[c2] : be[c2];
#pragma unroll
    for (int reg = 0; reg < 4; reg++) {
        int row = rt * 16 + quad * 4 + reg;
        float val = acc[reg] + bias;
        if (isA) ab[row * 128 + c2] = fast_tanh(val);
        else     eb[row * 128 + c2] = sigmoidf_(val);
    }
}

// ---------------------------------------------------------------- k_scan
// grid 256 = b(16) x dblk(16), block 64. LDS-staged wsmall + e/a tile + q.
__global__ void k_scan(const float* __restrict__ Mv0, const float* __restrict__ eb,
                       const float* __restrict__ ab, const float* __restrict__ wsmall,
                       const int* __restrict__ qq, u16* __restrict__ fA) {
    int b = blockIdx.x >> 4, dblk = blockIdx.x & 15;
    int lane = threadIdx.x;
    int s = lane >> 3, dlo = lane & 7;
    int d = dblk * 8 + dlo;

    __shared__ float wsm[101 * 64];
    __shared__ float el[128][8];
    __shared__ float al[128][8];
    __shared__ int ql[128];

    for (int i = lane; i < 101 * 64; i += 64) wsm[i] = wsmall[i];
    for (int i = lane; i < 1024; i += 64) {
        int t = i >> 3, dl = i & 7;
        el[t][dl] = eb[(b * 128 + t) * 128 + dblk * 8 + dl];
        al[t][dl] = ab[(b * 128 + t) * 128 + dblk * 8 + dl];
    }
    for (int i = lane; i < 128; i += 64) ql[i] = qq[b * 128 + i];
    __syncthreads();

    float mv[8];
#pragma unroll
    for (int q = 0; q < 8; q++) mv[q] = Mv0[(s * 8 + q) * 128 + d];

    u16* fout = fA + (b * 128) * 256 + d;

    int qt = ql[0];
    const float4* wr = (const float4*)(wsm + qt * 64 + s * 8);
    float4 w0 = wr[0], w1 = wr[1];
    float ecur = el[0][dlo], acur = al[0][dlo];

    for (int t = 0; t < 128; t++) {
        int tn = (t < 127) ? t + 1 : 127;
        int qn = ql[tn];
        const float4* wrn = (const float4*)(wsm + qn * 64 + s * 8);
        float4 nw0 = wrn[0], nw1 = wrn[1];
        float en = el[tn][dlo], an = al[tn][dlo];

        float w[8] = { w0.x, w0.y, w0.z, w0.w, w1.x, w1.y, w1.z, w1.w };
        float rd = 0.f;
#pragma unroll
        for (int q = 0; q < 8; q++) {
            rd = fmaf(w[q], mv[q], rd);
            mv[q] = fmaf(w[q], fmaf(-mv[q], ecur, acur), mv[q]);
        }
        rd += __shfl_xor(rd, 8, 64);
        rd += __shfl_xor(rd, 16, 64);
        rd += __shfl_xor(rd, 32, 64);
        if (s == 0) fout[t * 256] = f2b(rd);

        ecur = en; acur = an; w0 = nw0; w1 = nw1;
    }
}

// ---------------------------------------------------------------- k_outfin
// grid 128, block 512 (8 waves). Wave wv computes f tile rows rt*16..+15 x cols
// wv*16..+15 (K=256 MFMA), tanh -> LDS bf16. Then wave 0: out = sigmoid(f @ WpT^T + b_p).
__global__ void k_outfin(const u16* __restrict__ fA, const u16* __restrict__ WfT,
                         const float* __restrict__ bfp, const u16* __restrict__ WpT,
                         const float* __restrict__ bp, float* __restrict__ out) {
    int rt = blockIdx.x;
    int wv = threadIdx.x >> 6, lane = threadIdx.x & 63;
    int m = lane & 15, quad = lane >> 4;
    __shared__ u16 ftile[16][128];

    const short8* ap = (const short8*)(fA + (rt * 16 + m) * 256 + quad * 8);
    const short8* bpw = (const short8*)(WfT + (wv * 16 + m) * 256 + quad * 8);
    f32x4 acc = {0.f, 0.f, 0.f, 0.f};
#pragma unroll
    for (int kc = 0; kc < 8; kc++)
        acc = __builtin_amdgcn_mfma_f32_16x16x32_bf16(ap[kc * 4], bpw[kc * 4], acc, 0, 0, 0);
    int col = wv * 16 + m;
    float bias = bfp[col];
#pragma unroll
    for (int reg = 0; reg < 4; reg++)
        ftile[quad * 4 + reg][col] = f2b(fast_tanh(acc[reg] + bias));
    __syncthreads();

    if (wv == 0) {
        f32x4 facc = {0.f, 0.f, 0.f, 0.f};
#pragma unroll
        for (int kc = 0; kc < 4; kc++) {
            short8 af = *(const short8*)(&ftile[m][kc * 32 + quad * 8]);
            short8 bf = *(const short8*)(WpT + m * 128 + kc * 32 + quad * 8);
            facc = __builtin_amdgcn_mfma_f32_16x16x32_bf16(af, bf, facc, 0, 0, 0);
        }
        if (m < 10) {
            float bias2 = bp[m];
#pragma unroll
            for (int reg = 0; reg < 4; reg++) {
                int row = rt * 16 + quad * 4 + reg;
                out[row * 10 + m] = sigmoidf_(facc[reg] + bias2);
            }
        }
    }
}

extern "C" void kernel_launch(void* const* d_in, const int* in_sizes, int n_in,
                              void* d_out, int out_size, void* d_ws, size_t ws_size,
                              hipStream_t stream) {
    const int*   code = (const int*)d_in[0];
    const int*   q    = (const int*)d_in[1];
    const int*   r    = (const int*)d_in[2];
    const float* EN   = (const float*)d_in[3];
    const float* EP   = (const float*)d_in[4];
    const float* Wpt  = (const float*)d_in[5];
    const float* bpt  = (const float*)d_in[6];
    const float* Watt = (const float*)d_in[7];
    const float* Kemb = (const float*)d_in[9];
    const float* Mk   = (const float*)d_in[10];
    const float* Mv0  = (const float*)d_in[11];
    const float* Vemb = (const float*)d_in[12];
    const float* We   = (const float*)d_in[13];
    const float* be   = (const float*)d_in[14];
    const float* Wa   = (const float*)d_in[15];
    const float* ba   = (const float*)d_in[16];
    const float* Wf   = (const float*)d_in[17];
    const float* bf_  = (const float*)d_in[18];
    const float* Wp   = (const float*)d_in[19];
    const float* bp   = (const float*)d_in[20];

    char* ws = (char*)d_ws;
    size_t off = 0;
    auto alloc = [&](size_t bytes) { void* p = ws + off; off = (off + bytes + 255) & ~255UL; return p; };
    u8*    PS8    = (u8*)alloc(10002UL * 384);
    u8*    PE8    = (u8*)alloc(10002UL * 384);
    u8*    PP8    = (u8*)alloc(10002UL * 384);
    u16*   ENb    = (u16*)alloc(10016UL * 128 * 2);   // +14 rows pad: k_preM tail reads
    u16*   EPb    = (u16*)alloc(10016UL * 128 * 2);
    u8*    EN8    = (u8*)alloc(10002UL * 128);
    u8*    EP8    = (u8*)alloc(10002UL * 128);
    u16*   Wt     = (u16*)alloc(384UL * 384 * 2);
    u16*   WeaT   = (u16*)alloc(256UL * 512 * 2);
    u16*   WfT    = (u16*)alloc(128UL * 256 * 2);
    u16*   WpT    = (u16*)alloc(16UL * 128 * 2);
    float* cw     = (float*)alloc(16UL * 128 * 128 * 4);   // [b][p][l]
    float* attn   = (float*)alloc(16UL * 128 * 128 * 4);   // [b][l][p]
    u16*   vA     = (u16*)alloc(2048UL * 512 * 2);         // [Vemb[r] ; code_vec] bf16
    u16*   fA     = (u16*)alloc(2048UL * 256 * 2);         // [read ; Kemb[q]] bf16
    float* eb     = (float*)alloc(2048UL * 128 * 4);
    float* ab     = (float*)alloc(2048UL * 128 * 4);
    float* wsmall = (float*)alloc(101UL * 64 * 4);

    k_conv<<<2048 + 26, 256, 0, stream>>>(EN, EP, Wpt, We, Wa, Wf, Wp, Kemb, Mk,
                                          ENb, EPb, EN8, EP8, Wt, WeaT, WfT, WpT, wsmall);
    k_preM<<<dim3(313, 3), 256, 0, stream>>>(ENb, EPb, Wt, bpt, PS8, PE8, PP8);
    k_cw<<<8192, 256, 0, stream>>>(code, PS8, PE8, PP8, Watt, cw);
    k_sm<<<128, 256, 0, stream>>>(cw, attn);
    k_cv<<<2048, 256, 0, stream>>>(code, attn, EN8, EP8, r, q, Vemb, Kemb, vA, fA);
    k_eawM<<<512, 256, 0, stream>>>(vA, WeaT, be, ba, eb, ab);
    k_scan<<<256, 64, 0, stream>>>(Mv0, eb, ab, wsmall, q, fA);
    k_outfin<<<128, 512, 0, stream>>>(fA, WfT, bf_, WpT, bp, (float*)d_out);
}

// Round 10
// 223.972 us; speedup vs baseline: 3.2163x; 1.0098x over previous
//
#include <hip/hip_runtime.h>

// DKVMN + code2vec attention. Sizes (fixed):
// B=16 L=128 P=128 NUM_C=100 D=128 M=64 EMB=128 TE=384 CODE_W=584 NROW=10002
//
// Inputs/outputs f32. MFMA operands bf16; gather tables fp8 e4m3.
// k_cwsm algebra: tanh identity + softmax shift-invariance =>
//   logit'[b,p,l] = -2 * sum_j Watt_j * rcp(1 + exp2(z'_j)),  z' = z*2log2e
// Topology: block = (b,p); 16-lane group per triple (24 B/lane of the 384-B fp8
// rows), 8 l's per group -> all 128 logits of one softmax row in LDS -> fused
// l-softmax -> attn[b,l,p] written directly (cw buffer + k_sm kernel eliminated).
//
//  k_conv  : ENb/EPb bf16 + EN8/EP8 fp8 (single read), transposed bf16 Wt/WeaT/
//            WfT/WpT; extra blocks compute wsmall[q][m]=softmax(k_emb[q]@Mk^T)
//  k_preM  : PS8/PE8/PP8 = fp8((emb @ Wpt slice)*2log2e) via MFMA, 32 rows/block
//  k_cwsm  : logits (fp8 gathers, rcp-only) + fused softmax over l -> attn
//  k_cv    : vA[row]=[Vemb[r];code_vec] bf16 (fp8 gathers, prefetched)
//  k_eawM  : e|a = act(vA @ WeaT + b) via MFMA
//  k_scan  : sequential scan, LDS-staged state; read -> fA bf16
//  k_outfin: f = tanh(fA @ WfT + b_f) (LDS) then out = sigmoid(f @ WpT + b_p)

typedef unsigned char u8;
typedef unsigned short u16;
typedef unsigned int u32;
typedef __attribute__((ext_vector_type(8))) short short8;   // 8 bf16 (4 VGPRs)
typedef __attribute__((ext_vector_type(4))) float f32x4;    // MFMA C/D
typedef __attribute__((ext_vector_type(2))) float f32x2;

#define DEV __device__ __forceinline__
#define LOG2E 1.4426950408889634f
#define KSCALE 2.8853900817779268f   // 2*log2(e)

DEV u16 f2b(float f) {
    union { float f; u32 i; } v; v.f = f;
    u32 x = v.i;
    u32 r = (x + 0x7FFFu + ((x >> 16) & 1u)) >> 16;   // RNE
    return (u16)r;
}
DEV float nexp(float x) { return __builtin_amdgcn_exp2f(x * LOG2E); }
DEV float nrcp(float x) { return __builtin_amdgcn_rcpf(x); }
DEV float fast_tanh(float x) {
    return 1.f - 2.f * nrcp(1.f + __builtin_amdgcn_exp2f(x * (2.f * LOG2E)));
}
DEV float sigmoidf_(float x) { return nrcp(1.f + __builtin_amdgcn_exp2f(-x * LOG2E)); }
DEV f32x2 d8(u32 x, bool hi) {                 // decode 2 fp8 e4m3 -> 2 f32
    return hi ? __builtin_amdgcn_cvt_pk_f32_fp8((int)x, true)
              : __builtin_amdgcn_cvt_pk_f32_fp8((int)x, false);
}
DEV u8 e8(float x) {                           // encode f32 -> fp8 e4m3
    return (u8)(__builtin_amdgcn_cvt_pk_fp8_f32(x, x, 0, false) & 0xFF);
}

// ---------------------------------------------------------------- k_conv
// blocks <2048: grid-stride pair-indexed segments:
//   EN pairs -> ENb(u32)+EN8(u16) | EP pairs | Wt | WeaT | WfT | WpT
// blocks >=2048: wsmall (4 rows/block, one per wave).
__global__ void k_conv(const float* __restrict__ EN, const float* __restrict__ EP,
                       const float* __restrict__ Wpt, const float* __restrict__ We,
                       const float* __restrict__ Wa, const float* __restrict__ Wf,
                       const float* __restrict__ Wp,
                       const float* __restrict__ Kemb, const float* __restrict__ Mk,
                       u16* __restrict__ ENb, u16* __restrict__ EPb,
                       u8* __restrict__ EN8, u8* __restrict__ EP8,
                       u16* __restrict__ Wt, u16* __restrict__ WeaT,
                       u16* __restrict__ WfT, u16* __restrict__ WpT,
                       float* __restrict__ wsmall) {
    if (blockIdx.x >= 2048) {                      // ---- wsmall part
        int wv = threadIdx.x >> 6, lane = threadIdx.x & 63;
        int row = (blockIdx.x - 2048) * 4 + wv;
        if (row >= 101) return;
        float lg = 0.f;
        for (int k = 0; k < 128; k += 8) {
            float mk8[8];
#pragma unroll
            for (int u = 0; u < 8; u++) mk8[u] = Mk[lane * 128 + k + u];
#pragma unroll
            for (int u = 0; u < 8; u++) lg = fmaf(Kemb[row * 128 + k + u], mk8[u], lg);
        }
        float mx = lg;
#pragma unroll
        for (int off = 32; off; off >>= 1) mx = fmaxf(mx, __shfl_xor(mx, off, 64));
        float ex = nexp(lg - mx);
        float sum = ex;
#pragma unroll
        for (int off = 32; off; off >>= 1) sum += __shfl_xor(sum, off, 64);
        wsmall[row * 64 + lane] = ex * nrcp(sum);
        return;
    }
    const int NEH = 10002 * 64;        // pair count per table
    const int T0 = 2 * NEH;            // end EP pairs
    const int T1 = T0 + 147456;        // end Wt
    const int T2 = T1 + 131072;        // end WeaT
    const int T3 = T2 + 32768;         // end WfT
    const int T4 = T3 + 2048;          // end WpT
    for (int i = blockIdx.x * blockDim.x + threadIdx.x; i < T4; i += 2048 * blockDim.x) {
        if (i < NEH) {
            float a = EN[2 * i], b = EN[2 * i + 1];
            ((u32*)ENb)[i] = ((u32)f2b(b) << 16) | f2b(a);
            ((u16*)EN8)[i] = (u16)__builtin_amdgcn_cvt_pk_fp8_f32(a, b, 0, false);
        } else if (i < T0) {
            int j = i - NEH;
            float a = EP[2 * j], b = EP[2 * j + 1];
            ((u32*)EPb)[j] = ((u32)f2b(b) << 16) | f2b(a);
            ((u16*)EP8)[j] = (u16)__builtin_amdgcn_cvt_pk_fp8_f32(a, b, 0, false);
        } else if (i < T1) {
            int w = i - T0;  u32 n = (u32)w / 384u, k = (u32)w % 384u;
            Wt[w] = f2b(Wpt[k * 384 + n]);
        } else if (i < T2) {
            int w = i - T1;  int n = w >> 9, k = w & 511;
            WeaT[w] = f2b((n < 128) ? We[k * 128 + n] : Wa[k * 128 + (n - 128)]);
        } else if (i < T3) {
            int w = i - T2;  int n = w >> 8, k = w & 255;
            WfT[w] = f2b(Wf[k * 128 + n]);
        } else {
            int w = i - T3;  int n = w >> 7, k = w & 127;
            WpT[w] = (n < 10) ? f2b(Wp[k * 10 + n]) : (u16)0;
        }
    }
}

// ---------------------------------------------------------------- k_preM
// grid (313, 3), block 256 = 4 waves. 32 rows x 384 cols per block. MFMA
// 16x16x32 bf16; epilogue scales by 2*log2e, stores fp8.
__global__ void k_preM(const u16* __restrict__ ENb, const u16* __restrict__ EPb,
                       const u16* __restrict__ Wt, const float* __restrict__ bpt,
                       u8* __restrict__ PS8, u8* __restrict__ PE8, u8* __restrict__ PP8) {
    int which = blockIdx.y;
    int r0 = blockIdx.x * 32;
    int wv = threadIdx.x >> 6, lane = threadIdx.x & 63;
    int m = lane & 15, quad = lane >> 4;
    const u16* A = (which == 2) ? EPb : ENb;
    int koff = which * 128;
    u8* dst = (which == 0) ? PS8 : (which == 1) ? PE8 : PP8;

    short8 a[2][4];
#pragma unroll
    for (int rt = 0; rt < 2; rt++) {
        const short8* ap = (const short8*)(A + (r0 + rt * 16 + m) * 128 + quad * 8);
#pragma unroll
        for (int kc = 0; kc < 4; kc++) a[rt][kc] = ap[kc * 4];
    }

    for (int nt = 0; nt < 6; nt++) {
        int n0 = wv * 96 + nt * 16;
        const short8* bp = (const short8*)(Wt + (n0 + m) * 384 + koff + quad * 8);
        short8 b0 = bp[0], b1 = bp[4], b2 = bp[8], b3 = bp[12];
        int col = n0 + m;
        float bias = (which == 2) ? bpt[col] : 0.f;
#pragma unroll
        for (int rt = 0; rt < 2; rt++) {
            f32x4 acc = {0.f, 0.f, 0.f, 0.f};
            acc = __builtin_amdgcn_mfma_f32_16x16x32_bf16(a[rt][0], b0, acc, 0, 0, 0);
            acc = __builtin_amdgcn_mfma_f32_16x16x32_bf16(a[rt][1], b1, acc, 0, 0, 0);
            acc = __builtin_amdgcn_mfma_f32_16x16x32_bf16(a[rt][2], b2, acc, 0, 0, 0);
            acc = __builtin_amdgcn_mfma_f32_16x16x32_bf16(a[rt][3], b3, acc, 0, 0, 0);
#pragma unroll
            for (int reg = 0; reg < 4; reg++) {
                int row = r0 + rt * 16 + quad * 4 + reg;
                if (row < 10002) dst[row * 384 + col] = e8((acc[reg] + bias) * KSCALE);
            }
        }
    }
}

// ---------------------------------------------------------------- k_cwsm
// grid 2048 = (b,p), block 256 = 16 groups of 16 lanes. Group g: l = g+16*it,
// it<8. Lane gl covers j = gl*24..+23 (3 uint2 per table). Logits -> LDS,
// then fused softmax over l, attn[b][l][p] stored directly.
__global__ void k_cwsm(const int* __restrict__ code,
                       const u8* __restrict__ PS8, const u8* __restrict__ PE8,
                       const u8* __restrict__ PP8, const float* __restrict__ Watt,
                       float* __restrict__ attn) {
    int bp = blockIdx.x;
    int b = bp >> 7, p = bp & 127;
    int tid = threadIdx.x;
    int g = tid >> 4, gl = tid & 15;
    __shared__ float lgs[128];
    __shared__ float redm[4], reds[4];

    // Watt[gl*24..+23] pre-scaled by -2 (tanh identity; constants cancel in softmax)
    float w24[24];
    const float4* wp = (const float4*)(Watt + gl * 24);
#pragma unroll
    for (int u = 0; u < 6; u++) {
        float4 f = wp[u];
        w24[4 * u + 0] = -2.f * f.x; w24[4 * u + 1] = -2.f * f.y;
        w24[4 * u + 2] = -2.f * f.z; w24[4 * u + 3] = -2.f * f.w;
    }

    // indices for all 8 l's of this group (16-lane broadcast loads)
    int si[8], pi[8], ei[8];
#pragma unroll
    for (int it = 0; it < 8; it++) {
        const int* c = code + ((b * 128 + g + it * 16) * 584 + 200 + 3 * p);
        si[it] = c[0]; pi[it] = c[1]; ei[it] = c[2];
    }

    uint2 cs0, cs1, cs2, ce0, ce1, ce2, cq0, cq1, cq2;
    {
        const uint2* bs = (const uint2*)(PS8 + si[0] * 384 + gl * 24);
        const uint2* be = (const uint2*)(PE8 + ei[0] * 384 + gl * 24);
        const uint2* bq = (const uint2*)(PP8 + pi[0] * 384 + gl * 24);
        cs0 = bs[0]; cs1 = bs[1]; cs2 = bs[2];
        ce0 = be[0]; ce1 = be[1]; ce2 = be[2];
        cq0 = bq[0]; cq1 = bq[1]; cq2 = bq[2];
    }
#pragma unroll
    for (int it = 0; it < 8; it++) {
        uint2 ns0, ns1, ns2, ne0, ne1, ne2, nq0, nq1, nq2;
        if (it < 7) {
            const uint2* bs = (const uint2*)(PS8 + si[it + 1] * 384 + gl * 24);
            const uint2* be = (const uint2*)(PE8 + ei[it + 1] * 384 + gl * 24);
            const uint2* bq = (const uint2*)(PP8 + pi[it + 1] * 384 + gl * 24);
            ns0 = bs[0]; ns1 = bs[1]; ns2 = bs[2];
            ne0 = be[0]; ne1 = be[1]; ne2 = be[2];
            nq0 = bq[0]; nq1 = bq[1]; nq2 = bq[2];
        }
        u32 sv[6] = { cs0.x, cs0.y, cs1.x, cs1.y, cs2.x, cs2.y };
        u32 ev[6] = { ce0.x, ce0.y, ce1.x, ce1.y, ce2.x, ce2.y };
        u32 qv[6] = { cq0.x, cq0.y, cq1.x, cq1.y, cq2.x, cq2.y };
        float acc = 0.f;
#pragma unroll
        for (int u = 0; u < 6; u++) {
            f32x2 zl = d8(sv[u], false) + d8(ev[u], false) + d8(qv[u], false);
            f32x2 zh = d8(sv[u], true)  + d8(ev[u], true)  + d8(qv[u], true);
            acc = fmaf(nrcp(1.f + __builtin_amdgcn_exp2f(zl.x)), w24[4 * u + 0], acc);
            acc = fmaf(nrcp(1.f + __builtin_amdgcn_exp2f(zl.y)), w24[4 * u + 1], acc);
            acc = fmaf(nrcp(1.f + __builtin_amdgcn_exp2f(zh.x)), w24[4 * u + 2], acc);
            acc = fmaf(nrcp(1.f + __builtin_amdgcn_exp2f(zh.y)), w24[4 * u + 3], acc);
        }
        acc += __shfl_xor(acc, 1, 64);
        acc += __shfl_xor(acc, 2, 64);
        acc += __shfl_xor(acc, 4, 64);
        acc += __shfl_xor(acc, 8, 64);
        if (gl == 0) lgs[g + it * 16] = acc;
        if (it < 7) {
            cs0 = ns0; cs1 = ns1; cs2 = ns2;
            ce0 = ne0; ce1 = ne1; ce2 = ne2;
            cq0 = nq0; cq1 = nq1; cq2 = nq2;
        }
    }
    __syncthreads();

    // fused softmax over l (threads 0-127 hold data; all 256 hit barriers)
    int lane = tid & 63, wvi = tid >> 6;
    float x = (tid < 128) ? lgs[tid] : -1e30f;
    float mx = x;
#pragma unroll
    for (int off = 32; off; off >>= 1) mx = fmaxf(mx, __shfl_xor(mx, off, 64));
    if (lane == 0) redm[wvi] = mx;
    __syncthreads();
    mx = fmaxf(redm[0], redm[1]);
    float ex = nexp(x - mx);
    float sum = ex;
#pragma unroll
    for (int off = 32; off; off >>= 1) sum += __shfl_xor(sum, off, 64);
    if (lane == 0) reds[wvi] = sum;
    __syncthreads();
    float inv = nrcp(reds[0] + reds[1]);
    if (tid < 128) attn[(b * 128 + tid) * 128 + p] = ex * inv;
}

// ---------------------------------------------------------------- k_cv
// grid 2048 = (b,l), block 256 = 4 waves. fp8 gathers, software-pipelined.
__global__ void k_cv(const int* __restrict__ code, const float* __restrict__ attn,
                     const u8* __restrict__ EN8, const u8* __restrict__ EP8,
                     const int* __restrict__ rr, const int* __restrict__ qq,
                     const float* __restrict__ Vemb, const float* __restrict__ Kemb,
                     u16* __restrict__ vA, u16* __restrict__ fA) {
    int row = blockIdx.x;
    int tid = threadIdx.x;
    int wv = tid >> 6, lane = tid & 63;
    __shared__ int si[128], ei[128], pi[128];
    __shared__ float at[128];
    __shared__ float part[4][3][128];
    if (tid < 128) {
        const int* c = code + (row * 584 + 200);
        si[tid] = c[3 * tid]; pi[tid] = c[3 * tid + 1]; ei[tid] = c[3 * tid + 2];
        at[tid] = attn[row * 128 + tid];
    }
    if (tid < 128) {
        vA[row * 512 + tid] = f2b(Vemb[rr[row] * 128 + tid]);
    } else {
        int t2 = tid - 128;
        fA[row * 256 + 128 + t2] = f2b(Kemb[qq[row] * 128 + t2]);
    }
    __syncthreads();
    float a0 = 0.f, a1 = 0.f, b0 = 0.f, b1 = 0.f, c0 = 0.f, c1 = 0.f;
    int o = 2 * lane;

    u32 cur[6];
    {
        int p = wv, p2 = wv + 4;
        cur[0] = *(const u16*)(EN8 + si[p] * 128 + o);
        cur[1] = *(const u16*)(EN8 + ei[p] * 128 + o);
        cur[2] = *(const u16*)(EP8 + pi[p] * 128 + o);
        cur[3] = *(const u16*)(EN8 + si[p2] * 128 + o);
        cur[4] = *(const u16*)(EN8 + ei[p2] * 128 + o);
        cur[5] = *(const u16*)(EP8 + pi[p2] * 128 + o);
    }
#pragma unroll
    for (int it = 0; it < 16; it++) {
        int p = wv + it * 8;
        u32 nxt[6];
        if (it < 15) {
            int pn = p + 8, pn2 = p + 12;
            nxt[0] = *(const u16*)(EN8 + si[pn] * 128 + o);
            nxt[1] = *(const u16*)(EN8 + ei[pn] * 128 + o);
            nxt[2] = *(const u16*)(EP8 + pi[pn] * 128 + o);
            nxt[3] = *(const u16*)(EN8 + si[pn2] * 128 + o);
            nxt[4] = *(const u16*)(EN8 + ei[pn2] * 128 + o);
            nxt[5] = *(const u16*)(EP8 + pi[pn2] * 128 + o);
        }
        float w = at[p], w2 = at[p + 4];
        f32x2 fs = d8(cur[0], false), fe = d8(cur[1], false), fp = d8(cur[2], false);
        f32x2 gs = d8(cur[3], false), ge = d8(cur[4], false), gp = d8(cur[5], false);
        a0 = fmaf(w, fs.x, a0); a1 = fmaf(w, fs.y, a1);
        b0 = fmaf(w, fe.x, b0); b1 = fmaf(w, fe.y, b1);
        c0 = fmaf(w, fp.x, c0); c1 = fmaf(w, fp.y, c1);
        a0 = fmaf(w2, gs.x, a0); a1 = fmaf(w2, gs.y, a1);
        b0 = fmaf(w2, ge.x, b0); b1 = fmaf(w2, ge.y, b1);
        c0 = fmaf(w2, gp.x, c0); c1 = fmaf(w2, gp.y, c1);
        if (it < 15) {
#pragma unroll
            for (int z = 0; z < 6; z++) cur[z] = nxt[z];
        }
    }
    part[wv][0][2 * lane] = a0; part[wv][0][2 * lane + 1] = a1;
    part[wv][1][2 * lane] = b0; part[wv][1][2 * lane + 1] = b1;
    part[wv][2][2 * lane] = c0; part[wv][2][2 * lane + 1] = c1;
    __syncthreads();
    u16* vrow = vA + row * 512 + 128;
    for (int idx = tid; idx < 384; idx += 256) {
        int tbl = idx >> 7, col = idx & 127;
        vrow[idx] = f2b(part[0][tbl][col] + part[1][tbl][col] + part[2][tbl][col] + part[3][tbl][col]);
    }
}

// ---------------------------------------------------------------- k_eawM
// grid 512, block 256 (4 waves). C[2048][256] = vA @ WeaT^T via MFMA. K=512.
__global__ void k_eawM(const u16* __restrict__ vA, const u16* __restrict__ WeaT,
                       const float* __restrict__ be, const float* __restrict__ ba,
                       float* __restrict__ eb, float* __restrict__ ab) {
    int rt = blockIdx.x >> 2, cg = blockIdx.x & 3;
    int wv = threadIdx.x >> 6, lane = threadIdx.x & 63;
    int ct = cg * 4 + wv;
    int m = lane & 15, quad = lane >> 4;
    const short8* ap = (const short8*)(vA + (rt * 16 + m) * 512 + quad * 8);
    const short8* bp = (const short8*)(WeaT + (ct * 16 + m) * 512 + quad * 8);
    f32x4 acc = {0.f, 0.f, 0.f, 0.f};
#pragma unroll
    for (int kc = 0; kc < 16; kc++)
        acc = __builtin_amdgcn_mfma_f32_16x16x32_bf16(ap[kc * 4], bp[kc * 4], acc, 0, 0, 0);
    int col = ct * 16 + m;
    bool isA = col >= 128;
    int c2 = isA ? col - 128 : col;
    float bias = isA ? ba[c2] : be[c2];
#pragma unroll
    for (int reg = 0; reg < 4; reg++) {
        int row = rt * 16 + quad * 4 + reg;
        float val = acc[reg] + bias;
        if (isA) ab[row * 128 + c2] = fast_tanh(val);
        else     eb[row * 128 + c2] = sigmoidf_(val);
    }
}

// ---------------------------------------------------------------- k_scan
// grid 256 = b(16) x dblk(16), block 64. LDS-staged wsmall + e/a tile + q.
__global__ void k_scan(const float* __restrict__ Mv0, const float* __restrict__ eb,
                       const float* __restrict__ ab, const float* __restrict__ wsmall,
                       const int* __restrict__ qq, u16* __restrict__ fA) {
    int b = blockIdx.x >> 4, dblk = blockIdx.x & 15;
    int lane = threadIdx.x;
    int s = lane >> 3, dlo = lane & 7;
    int d = dblk * 8 + dlo;

    __shared__ float wsm[101 * 64];
    __shared__ float el[128][8];
    __shared__ float al[128][8];
    __shared__ int ql[128];

    for (int i = lane; i < 101 * 64; i += 64) wsm[i] = wsmall[i];
    for (int i = lane; i < 1024; i += 64) {
        int t = i >> 3, dl = i & 7;
        el[t][dl] = eb[(b * 128 + t) * 128 + dblk * 8 + dl];
        al[t][dl] = ab[(b * 128 + t) * 128 + dblk * 8 + dl];
    }
    for (int i = lane; i < 128; i += 64) ql[i] = qq[b * 128 + i];
    __syncthreads();

    float mv[8];
#pragma unroll
    for (int q = 0; q < 8; q++) mv[q] = Mv0[(s * 8 + q) * 128 + d];

    u16* fout = fA + (b * 128) * 256 + d;

    int qt = ql[0];
    const float4* wr = (const float4*)(wsm + qt * 64 + s * 8);
    float4 w0 = wr[0], w1 = wr[1];
    float ecur = el[0][dlo], acur = al[0][dlo];

    for (int t = 0; t < 128; t++) {
        int tn = (t < 127) ? t + 1 : 127;
        int qn = ql[tn];
        const float4* wrn = (const float4*)(wsm + qn * 64 + s * 8);
        float4 nw0 = wrn[0], nw1 = wrn[1];
        float en = el[tn][dlo], an = al[tn][dlo];

        float w[8] = { w0.x, w0.y, w0.z, w0.w, w1.x, w1.y, w1.z, w1.w };
        float rd = 0.f;
#pragma unroll
        for (int q = 0; q < 8; q++) {
            rd = fmaf(w[q], mv[q], rd);
            mv[q] = fmaf(w[q], fmaf(-mv[q], ecur, acur), mv[q]);
        }
        rd += __shfl_xor(rd, 8, 64);
        rd += __shfl_xor(rd, 16, 64);
        rd += __shfl_xor(rd, 32, 64);
        if (s == 0) fout[t * 256] = f2b(rd);

        ecur = en; acur = an; w0 = nw0; w1 = nw1;
    }
}

// ---------------------------------------------------------------- k_outfin
// grid 128, block 512 (8 waves). Wave wv computes f tile rows rt*16..+15 x cols
// wv*16..+15 (K=256 MFMA), tanh -> LDS bf16. Then wave 0: out = sigmoid(f @ WpT^T + b_p).
__global__ void k_outfin(const u16* __restrict__ fA, const u16* __restrict__ WfT,
                         const float* __restrict__ bfp, const u16* __restrict__ WpT,
                         const float* __restrict__ bp, float* __restrict__ out) {
    int rt = blockIdx.x;
    int wv = threadIdx.x >> 6, lane = threadIdx.x & 63;
    int m = lane & 15, quad = lane >> 4;
    __shared__ u16 ftile[16][128];

    const short8* ap = (const short8*)(fA + (rt * 16 + m) * 256 + quad * 8);
    const short8* bpw = (const short8*)(WfT + (wv * 16 + m) * 256 + quad * 8);
    f32x4 acc = {0.f, 0.f, 0.f, 0.f};
#pragma unroll
    for (int kc = 0; kc < 8; kc++)
        acc = __builtin_amdgcn_mfma_f32_16x16x32_bf16(ap[kc * 4], bpw[kc * 4], acc, 0, 0, 0);
    int col = wv * 16 + m;
    float bias = bfp[col];
#pragma unroll
    for (int reg = 0; reg < 4; reg++)
        ftile[quad * 4 + reg][col] = f2b(fast_tanh(acc[reg] + bias));
    __syncthreads();

    if (wv == 0) {
        f32x4 facc = {0.f, 0.f, 0.f, 0.f};
#pragma unroll
        for (int kc = 0; kc < 4; kc++) {
            short8 af = *(const short8*)(&ftile[m][kc * 32 + quad * 8]);
            short8 bf = *(const short8*)(WpT + m * 128 + kc * 32 + quad * 8);
            facc = __builtin_amdgcn_mfma_f32_16x16x32_bf16(af, bf, facc, 0, 0, 0);
        }
        if (m < 10) {
            float bias2 = bp[m];
#pragma unroll
            for (int reg = 0; reg < 4; reg++) {
                int row = rt * 16 + quad * 4 + reg;
                out[row * 10 + m] = sigmoidf_(facc[reg] + bias2);
            }
        }
    }
}

extern "C" void kernel_launch(void* const* d_in, const int* in_sizes, int n_in,
                              void* d_out, int out_size, void* d_ws, size_t ws_size,
                              hipStream_t stream) {
    const int*   code = (const int*)d_in[0];
    const int*   q    = (const int*)d_in[1];
    const int*   r    = (const int*)d_in[2];
    const float* EN   = (const float*)d_in[3];
    const float* EP   = (const float*)d_in[4];
    const float* Wpt  = (const float*)d_in[5];
    const float* bpt  = (const float*)d_in[6];
    const float* Watt = (const float*)d_in[7];
    const float* Kemb = (const float*)d_in[9];
    const float* Mk   = (const float*)d_in[10];
    const float* Mv0  = (const float*)d_in[11];
    const float* Vemb = (const float*)d_in[12];
    const float* We   = (const float*)d_in[13];
    const float* be   = (const float*)d_in[14];
    const float* Wa   = (const float*)d_in[15];
    const float* ba   = (const float*)d_in[16];
    const float* Wf   = (const float*)d_in[17];
    const float* bf_  = (const float*)d_in[18];
    const float* Wp   = (const float*)d_in[19];
    const float* bp   = (const float*)d_in[20];

    char* ws = (char*)d_ws;
    size_t off = 0;
    auto alloc = [&](size_t bytes) { void* p = ws + off; off = (off + bytes + 255) & ~255UL; return p; };
    u8*    PS8    = (u8*)alloc(10002UL * 384);
    u8*    PE8    = (u8*)alloc(10002UL * 384);
    u8*    PP8    = (u8*)alloc(10002UL * 384);
    u16*   ENb    = (u16*)alloc(10016UL * 128 * 2);   // +14 rows pad: k_preM tail reads
    u16*   EPb    = (u16*)alloc(10016UL * 128 * 2);
    u8*    EN8    = (u8*)alloc(10002UL * 128);
    u8*    EP8    = (u8*)alloc(10002UL * 128);
    u16*   Wt     = (u16*)alloc(384UL * 384 * 2);
    u16*   WeaT   = (u16*)alloc(256UL * 512 * 2);
    u16*   WfT    = (u16*)alloc(128UL * 256 * 2);
    u16*   WpT    = (u16*)alloc(16UL * 128 * 2);
    float* attn   = (float*)alloc(16UL * 128 * 128 * 4);   // [b][l][p]
    u16*   vA     = (u16*)alloc(2048UL * 512 * 2);         // [Vemb[r] ; code_vec] bf16
    u16*   fA     = (u16*)alloc(2048UL * 256 * 2);         // [read ; Kemb[q]] bf16
    float* eb     = (float*)alloc(2048UL * 128 * 4);
    float* ab     = (float*)alloc(2048UL * 128 * 4);
    float* wsmall = (float*)alloc(101UL * 64 * 4);

    k_conv<<<2048 + 26, 256, 0, stream>>>(EN, EP, Wpt, We, Wa, Wf, Wp, Kemb, Mk,
                                          ENb, EPb, EN8, EP8, Wt, WeaT, WfT, WpT, wsmall);
    k_preM<<<dim3(313, 3), 256, 0, stream>>>(ENb, EPb, Wt, bpt, PS8, PE8, PP8);
    k_cwsm<<<2048, 256, 0, stream>>>(code, PS8, PE8, PP8, Watt, attn);
    k_cv<<<2048, 256, 0, stream>>>(code, attn, EN8, EP8, r, q, Vemb, Kemb, vA, fA);
    k_eawM<<<512, 256, 0, stream>>>(vA, WeaT, be, ba, eb, ab);
    k_scan<<<256, 64, 0, stream>>>(Mv0, eb, ab, wsmall, q, fA);
    k_outfin<<<128, 512, 0, stream>>>(fA, WfT, bf_, WpT, bp, (float*)d_out);
}

// Round 11
// 222.426 us; speedup vs baseline: 3.2387x; 1.0070x over previous
//
#include <hip/hip_runtime.h>

// DKVMN + code2vec attention. Sizes (fixed):
// B=16 L=128 P=128 NUM_C=100 D=128 M=64 EMB=128 TE=384 CODE_W=584 NROW=10002
//
// Inputs/outputs f32. MFMA operands bf16; gather tables fp8 e4m3.
// k_cwsm algebra: tanh identity + softmax shift-invariance =>
//   logit'[b,p,l] = -2 * sum_j Watt_j * rcp(1 + exp2(z'_j)),  z' = z*2log2e
// plus pairwise common-denominator: w0/d0 + w1/d1 = (w0 d1 + w1 d0) rcp(d0 d1)
// (1 rcp per 2 elements; |z'|<~35 so d0*d1 < 2^71, no overflow).
//
//  k_conv  : ENb/EPb bf16 + EN8/EP8 fp8 (single read), transposed bf16 Wt/WeaT/
//            WfT/WpT (coalesced-read/scattered-write); extra blocks: wsmall
//  k_preM  : PS8/PE8/PP8 = fp8((emb @ Wpt slice)*2log2e) via MFMA
//  k_cwsm  : logits (fp8 gathers dwordx4+x2, pairwise rcp) + fused l-softmax
//  k_cv    : half-wave coalesced u32 fp8 gathers -> vA bf16
//  k_eawM  : e|a = act(vA @ WeaT + b) via MFMA
//  k_scan  : sequential scan, LDS-staged state; read -> fA bf16
//  k_outfin: f = tanh(fA @ WfT + b_f) (LDS) then out = sigmoid(f @ WpT + b_p)

typedef unsigned char u8;
typedef unsigned short u16;
typedef unsigned int u32;
typedef __attribute__((ext_vector_type(8))) short short8;   // 8 bf16 (4 VGPRs)
typedef __attribute__((ext_vector_type(4))) float f32x4;    // MFMA C/D
typedef __attribute__((ext_vector_type(2))) float f32x2;

#define DEV __device__ __forceinline__
#define LOG2E 1.4426950408889634f
#define KSCALE 2.8853900817779268f   // 2*log2(e)

DEV u16 f2b(float f) {
    union { float f; u32 i; } v; v.f = f;
    u32 x = v.i;
    u32 r = (x + 0x7FFFu + ((x >> 16) & 1u)) >> 16;   // RNE
    return (u16)r;
}
DEV float nexp(float x) { return __builtin_amdgcn_exp2f(x * LOG2E); }
DEV float nrcp(float x) { return __builtin_amdgcn_rcpf(x); }
DEV float fast_tanh(float x) {
    return 1.f - 2.f * nrcp(1.f + __builtin_amdgcn_exp2f(x * (2.f * LOG2E)));
}
DEV float sigmoidf_(float x) { return nrcp(1.f + __builtin_amdgcn_exp2f(-x * LOG2E)); }
DEV f32x2 d8(u32 x, bool hi) {                 // decode 2 fp8 e4m3 -> 2 f32
    return hi ? __builtin_amdgcn_cvt_pk_f32_fp8((int)x, true)
              : __builtin_amdgcn_cvt_pk_f32_fp8((int)x, false);
}
DEV u8 e8(float x) {                           // encode f32 -> fp8 e4m3
    return (u8)(__builtin_amdgcn_cvt_pk_fp8_f32(x, x, 0, false) & 0xFF);
}

// ---------------------------------------------------------------- k_conv
// blocks <2048: grid-stride pair/elem-indexed segments, all reads coalesced:
//   EN pairs -> ENb(u32)+EN8(u16) | EP pairs | Wpt->Wt | We->WeaT | Wa->WeaT
//   | Wf->WfT | WpT
// blocks >=2048: wsmall (4 rows/block, one per wave).
__global__ void k_conv(const float* __restrict__ EN, const float* __restrict__ EP,
                       const float* __restrict__ Wpt, const float* __restrict__ We,
                       const float* __restrict__ Wa, const float* __restrict__ Wf,
                       const float* __restrict__ Wp,
                       const float* __restrict__ Kemb, const float* __restrict__ Mk,
                       u16* __restrict__ ENb, u16* __restrict__ EPb,
                       u8* __restrict__ EN8, u8* __restrict__ EP8,
                       u16* __restrict__ Wt, u16* __restrict__ WeaT,
                       u16* __restrict__ WfT, u16* __restrict__ WpT,
                       float* __restrict__ wsmall) {
    if (blockIdx.x >= 2048) {                      // ---- wsmall part
        int wv = threadIdx.x >> 6, lane = threadIdx.x & 63;
        int row = (blockIdx.x - 2048) * 4 + wv;
        if (row >= 101) return;
        float lg = 0.f;
        for (int k = 0; k < 128; k += 8) {
            float mk8[8];
#pragma unroll
            for (int u = 0; u < 8; u++) mk8[u] = Mk[lane * 128 + k + u];
#pragma unroll
            for (int u = 0; u < 8; u++) lg = fmaf(Kemb[row * 128 + k + u], mk8[u], lg);
        }
        float mx = lg;
#pragma unroll
        for (int off = 32; off; off >>= 1) mx = fmaxf(mx, __shfl_xor(mx, off, 64));
        float ex = nexp(lg - mx);
        float sum = ex;
#pragma unroll
        for (int off = 32; off; off >>= 1) sum += __shfl_xor(sum, off, 64);
        wsmall[row * 64 + lane] = ex * nrcp(sum);
        return;
    }
    const int NEH = 10002 * 64;        // pair count per table
    const int T0 = 2 * NEH;            // end EP pairs
    const int T1 = T0 + 147456;        // end Wt   (read Wpt k-major)
    const int T2 = T1 + 65536;         // end We part of WeaT
    const int T2b = T2 + 65536;        // end Wa part
    const int T3 = T2b + 32768;        // end WfT
    const int T4 = T3 + 2048;          // end WpT
    for (int i = blockIdx.x * blockDim.x + threadIdx.x; i < T4; i += 2048 * blockDim.x) {
        if (i < NEH) {
            float a = EN[2 * i], b = EN[2 * i + 1];
            ((u32*)ENb)[i] = ((u32)f2b(b) << 16) | f2b(a);
            ((u16*)EN8)[i] = (u16)__builtin_amdgcn_cvt_pk_fp8_f32(a, b, 0, false);
        } else if (i < T0) {
            int j = i - NEH;
            float a = EP[2 * j], b = EP[2 * j + 1];
            ((u32*)EPb)[j] = ((u32)f2b(b) << 16) | f2b(a);
            ((u16*)EP8)[j] = (u16)__builtin_amdgcn_cvt_pk_fp8_f32(a, b, 0, false);
        } else if (i < T1) {
            int w = i - T0;                       // w = k*384 + n (coalesced read)
            u32 k = (u32)w / 384u, n = (u32)w % 384u;
            Wt[n * 384 + k] = f2b(Wpt[w]);
        } else if (i < T2) {
            int w = i - T1;  int k = w >> 7, n = w & 127;
            WeaT[n * 512 + k] = f2b(We[w]);
        } else if (i < T2b) {
            int w = i - T2;  int k = w >> 7, n = w & 127;
            WeaT[(128 + n) * 512 + k] = f2b(Wa[w]);
        } else if (i < T3) {
            int w = i - T2b; int k = w >> 7, n = w & 127;
            WfT[n * 256 + k] = f2b(Wf[w]);
        } else {
            int w = i - T3;  int n = w >> 7, k = w & 127;
            WpT[w] = (n < 10) ? f2b(Wp[k * 10 + n]) : (u16)0;
        }
    }
}

// ---------------------------------------------------------------- k_preM
// grid (313, 3), block 256 = 4 waves. 32 rows x 384 cols per block. MFMA
// 16x16x32 bf16; epilogue scales by 2*log2e, stores fp8.
__global__ void k_preM(const u16* __restrict__ ENb, const u16* __restrict__ EPb,
                       const u16* __restrict__ Wt, const float* __restrict__ bpt,
                       u8* __restrict__ PS8, u8* __restrict__ PE8, u8* __restrict__ PP8) {
    int which = blockIdx.y;
    int r0 = blockIdx.x * 32;
    int wv = threadIdx.x >> 6, lane = threadIdx.x & 63;
    int m = lane & 15, quad = lane >> 4;
    const u16* A = (which == 2) ? EPb : ENb;
    int koff = which * 128;
    u8* dst = (which == 0) ? PS8 : (which == 1) ? PE8 : PP8;

    short8 a[2][4];
#pragma unroll
    for (int rt = 0; rt < 2; rt++) {
        const short8* ap = (const short8*)(A + (r0 + rt * 16 + m) * 128 + quad * 8);
#pragma unroll
        for (int kc = 0; kc < 4; kc++) a[rt][kc] = ap[kc * 4];
    }

    for (int nt = 0; nt < 6; nt++) {
        int n0 = wv * 96 + nt * 16;
        const short8* bp = (const short8*)(Wt + (n0 + m) * 384 + koff + quad * 8);
        short8 b0 = bp[0], b1 = bp[4], b2 = bp[8], b3 = bp[12];
        int col = n0 + m;
        float bias = (which == 2) ? bpt[col] : 0.f;
#pragma unroll
        for (int rt = 0; rt < 2; rt++) {
            f32x4 acc = {0.f, 0.f, 0.f, 0.f};
            acc = __builtin_amdgcn_mfma_f32_16x16x32_bf16(a[rt][0], b0, acc, 0, 0, 0);
            acc = __builtin_amdgcn_mfma_f32_16x16x32_bf16(a[rt][1], b1, acc, 0, 0, 0);
            acc = __builtin_amdgcn_mfma_f32_16x16x32_bf16(a[rt][2], b2, acc, 0, 0, 0);
            acc = __builtin_amdgcn_mfma_f32_16x16x32_bf16(a[rt][3], b3, acc, 0, 0, 0);
#pragma unroll
            for (int reg = 0; reg < 4; reg++) {
                int row = r0 + rt * 16 + quad * 4 + reg;
                if (row < 10002) dst[row * 384 + col] = e8((acc[reg] + bias) * KSCALE);
            }
        }
    }
}

// ---------------------------------------------------------------- k_cwsm
// grid 2048 = (b,p), block 256 = 16 groups of 16 lanes. Group g: l = g+16*it,
// it<8. Lane gl covers j = gl*24..+23 (dwordx4 + dwordx2 per table). Pairwise
// rcp. Logits -> LDS, fused softmax over l, attn[b][l][p] stored directly.
__global__ void k_cwsm(const int* __restrict__ code,
                       const u8* __restrict__ PS8, const u8* __restrict__ PE8,
                       const u8* __restrict__ PP8, const float* __restrict__ Watt,
                       float* __restrict__ attn) {
    int bp = blockIdx.x;
    int b = bp >> 7, p = bp & 127;
    int tid = threadIdx.x;
    int g = tid >> 4, gl = tid & 15;
    __shared__ float lgs[128];
    __shared__ float redm[4], reds[4];

    // Watt[gl*24..+23] pre-scaled by -2 (tanh identity; constants cancel in softmax)
    float w24[24];
    const float4* wp = (const float4*)(Watt + gl * 24);
#pragma unroll
    for (int u = 0; u < 6; u++) {
        float4 f = wp[u];
        w24[4 * u + 0] = -2.f * f.x; w24[4 * u + 1] = -2.f * f.y;
        w24[4 * u + 2] = -2.f * f.z; w24[4 * u + 3] = -2.f * f.w;
    }

    // indices for all 8 l's of this group (16-lane broadcast loads)
    int si[8], pi[8], ei[8];
#pragma unroll
    for (int it = 0; it < 8; it++) {
        const int* c = code + ((b * 128 + g + it * 16) * 584 + 200 + 3 * p);
        si[it] = c[0]; pi[it] = c[1]; ei[it] = c[2];
    }

    uint4 cs4, ce4, cq4; uint2 cs2, ce2, cq2;
    {
        const u8* bs = PS8 + si[0] * 384 + gl * 24;
        const u8* be = PE8 + ei[0] * 384 + gl * 24;
        const u8* bq = PP8 + pi[0] * 384 + gl * 24;
        cs4 = *(const uint4*)bs; cs2 = *(const uint2*)(bs + 16);
        ce4 = *(const uint4*)be; ce2 = *(const uint2*)(be + 16);
        cq4 = *(const uint4*)bq; cq2 = *(const uint2*)(bq + 16);
    }
#pragma unroll
    for (int it = 0; it < 8; it++) {
        uint4 ns4, ne4, nq4; uint2 ns2, ne2, nq2;
        if (it < 7) {
            const u8* bs = PS8 + si[it + 1] * 384 + gl * 24;
            const u8* be = PE8 + ei[it + 1] * 384 + gl * 24;
            const u8* bq = PP8 + pi[it + 1] * 384 + gl * 24;
            ns4 = *(const uint4*)bs; ns2 = *(const uint2*)(bs + 16);
            ne4 = *(const uint4*)be; ne2 = *(const uint2*)(be + 16);
            nq4 = *(const uint4*)bq; nq2 = *(const uint2*)(bq + 16);
        }
        u32 sv[6] = { cs4.x, cs4.y, cs4.z, cs4.w, cs2.x, cs2.y };
        u32 ev[6] = { ce4.x, ce4.y, ce4.z, ce4.w, ce2.x, ce2.y };
        u32 qv[6] = { cq4.x, cq4.y, cq4.z, cq4.w, cq2.x, cq2.y };
        float acc = 0.f;
#pragma unroll
        for (int u = 0; u < 6; u++) {
            f32x2 zl = d8(sv[u], false) + d8(ev[u], false) + d8(qv[u], false);
            f32x2 zh = d8(sv[u], true)  + d8(ev[u], true)  + d8(qv[u], true);
            float d0 = 1.f + __builtin_amdgcn_exp2f(zl.x);
            float d1 = 1.f + __builtin_amdgcn_exp2f(zl.y);
            float d2 = 1.f + __builtin_amdgcn_exp2f(zh.x);
            float d3 = 1.f + __builtin_amdgcn_exp2f(zh.y);
            float n01 = fmaf(w24[4 * u + 0], d1, w24[4 * u + 1] * d0);
            float n23 = fmaf(w24[4 * u + 2], d3, w24[4 * u + 3] * d2);
            acc = fmaf(n01, nrcp(d0 * d1), acc);
            acc = fmaf(n23, nrcp(d2 * d3), acc);
        }
        acc += __shfl_xor(acc, 1, 64);
        acc += __shfl_xor(acc, 2, 64);
        acc += __shfl_xor(acc, 4, 64);
        acc += __shfl_xor(acc, 8, 64);
        if (gl == 0) lgs[g + it * 16] = acc;
        if (it < 7) {
            cs4 = ns4; cs2 = ns2;
            ce4 = ne4; ce2 = ne2;
            cq4 = nq4; cq2 = nq2;
        }
    }
    __syncthreads();

    // fused softmax over l (threads 0-127 hold data; all 256 hit barriers)
    int lane = tid & 63, wvi = tid >> 6;
    float x = (tid < 128) ? lgs[tid] : -1e30f;
    float mx = x;
#pragma unroll
    for (int off = 32; off; off >>= 1) mx = fmaxf(mx, __shfl_xor(mx, off, 64));
    if (lane == 0) redm[wvi] = mx;
    __syncthreads();
    mx = fmaxf(redm[0], redm[1]);
    float ex = nexp(x - mx);
    float sum = ex;
#pragma unroll
    for (int off = 32; off; off >>= 1) sum += __shfl_xor(sum, off, 64);
    if (lane == 0) reds[wvi] = sum;
    __syncthreads();
    float inv = nrcp(reds[0] + reds[1]);
    if (tid < 128) attn[(b * 128 + tid) * 128 + p] = ex * inv;
}

// ---------------------------------------------------------------- k_cv
// grid 2048 = (b,l), block 256 = 4 waves. Half-wave coalesced u32 fp8 gathers:
// lanes 0-31 cover row(p), lanes 32-63 row(p+4), 4 cols/lane. 3 load insts
// per (p,p+4) pair (vs 6 u16). Partials combined via part[8][3][128].
__global__ void k_cv(const int* __restrict__ code, const float* __restrict__ attn,
                     const u8* __restrict__ EN8, const u8* __restrict__ EP8,
                     const int* __restrict__ rr, const int* __restrict__ qq,
                     const float* __restrict__ Vemb, const float* __restrict__ Kemb,
                     u16* __restrict__ vA, u16* __restrict__ fA) {
    int row = blockIdx.x;
    int tid = threadIdx.x;
    int wv = tid >> 6, lane = tid & 63;
    int h = lane >> 5, cl = lane & 31;
    __shared__ int si[128], ei[128], pi[128];
    __shared__ float at[128];
    __shared__ float part[8][3][128];
    if (tid < 128) {
        const int* c = code + (row * 584 + 200);
        si[tid] = c[3 * tid]; pi[tid] = c[3 * tid + 1]; ei[tid] = c[3 * tid + 2];
        at[tid] = attn[row * 128 + tid];
    }
    if (tid < 128) {
        vA[row * 512 + tid] = f2b(Vemb[rr[row] * 128 + tid]);
    } else {
        int t2 = tid - 128;
        fA[row * 256 + 128 + t2] = f2b(Kemb[qq[row] * 128 + t2]);
    }
    __syncthreads();

    int o = cl * 4;                              // byte offset in 128-B row
    int pb = wv + h * 4;                         // this half's p base (stride 8)
    float a0 = 0.f, a1 = 0.f, a2 = 0.f, a3 = 0.f;
    float b0 = 0.f, b1 = 0.f, b2 = 0.f, b3 = 0.f;
    float c0 = 0.f, c1 = 0.f, c2 = 0.f, c3 = 0.f;

    u32 cur0, cur1, cur2;
    cur0 = *(const u32*)(EN8 + si[pb] * 128 + o);
    cur1 = *(const u32*)(EN8 + ei[pb] * 128 + o);
    cur2 = *(const u32*)(EP8 + pi[pb] * 128 + o);
#pragma unroll
    for (int it = 0; it < 16; it++) {
        int p = pb + it * 8;
        u32 n0, n1, n2;
        if (it < 15) {
            int pn = p + 8;
            n0 = *(const u32*)(EN8 + si[pn] * 128 + o);
            n1 = *(const u32*)(EN8 + ei[pn] * 128 + o);
            n2 = *(const u32*)(EP8 + pi[pn] * 128 + o);
        }
        float w = at[p];
        f32x2 sl = d8(cur0, false), sh = d8(cur0, true);
        f32x2 el = d8(cur1, false), eh = d8(cur1, true);
        f32x2 pl = d8(cur2, false), ph = d8(cur2, true);
        a0 = fmaf(w, sl.x, a0); a1 = fmaf(w, sl.y, a1); a2 = fmaf(w, sh.x, a2); a3 = fmaf(w, sh.y, a3);
        b0 = fmaf(w, el.x, b0); b1 = fmaf(w, el.y, b1); b2 = fmaf(w, eh.x, b2); b3 = fmaf(w, eh.y, b3);
        c0 = fmaf(w, pl.x, c0); c1 = fmaf(w, pl.y, c1); c2 = fmaf(w, ph.x, c2); c3 = fmaf(w, ph.y, c3);
        if (it < 15) { cur0 = n0; cur1 = n1; cur2 = n2; }
    }
    int slot = wv * 2 + h;
    part[slot][0][o + 0] = a0; part[slot][0][o + 1] = a1; part[slot][0][o + 2] = a2; part[slot][0][o + 3] = a3;
    part[slot][1][o + 0] = b0; part[slot][1][o + 1] = b1; part[slot][1][o + 2] = b2; part[slot][1][o + 3] = b3;
    part[slot][2][o + 0] = c0; part[slot][2][o + 1] = c1; part[slot][2][o + 2] = c2; part[slot][2][o + 3] = c3;
    __syncthreads();
    u16* vrow = vA + row * 512 + 128;
    for (int idx = tid; idx < 384; idx += 256) {
        int tbl = idx >> 7, col = idx & 127;
        float s = 0.f;
#pragma unroll
        for (int sl2 = 0; sl2 < 8; sl2++) s += part[sl2][tbl][col];
        vrow[idx] = f2b(s);
    }
}

// ---------------------------------------------------------------- k_eawM
// grid 512, block 256 (4 waves). C[2048][256] = vA @ WeaT^T via MFMA. K=512.
__global__ void k_eawM(const u16* __restrict__ vA, const u16* __restrict__ WeaT,
                       const float* __restrict__ be, const float* __restrict__ ba,
                       float* __restrict__ eb, float* __restrict__ ab) {
    int rt = blockIdx.x >> 2, cg = blockIdx.x & 3;
    int wv = threadIdx.x >> 6, lane = threadIdx.x & 63;
    int ct = cg * 4 + wv;
    int m = lane & 15, quad = lane >> 4;
    const short8* ap = (const short8*)(vA + (rt * 16 + m) * 512 + quad * 8);
    const short8* bp = (const short8*)(WeaT + (ct * 16 + m) * 512 + quad * 8);
    f32x4 acc = {0.f, 0.f, 0.f, 0.f};
#pragma unroll
    for (int kc = 0; kc < 16; kc++)
        acc = __builtin_amdgcn_mfma_f32_16x16x32_bf16(ap[kc * 4], bp[kc * 4], acc, 0, 0, 0);
    int col = ct * 16 + m;
    bool isA = col >= 128;
    int c2 = isA ? col - 128 : col;
    float bias = isA ? ba[c2] : be[c2];
#pragma unroll
    for (int reg = 0; reg < 4; reg++) {
        int row = rt * 16 + quad * 4 + reg;
        float val = acc[reg] + bias;
        if (isA) ab[row * 128 + c2] = fast_tanh(val);
        else     eb[row * 128 + c2] = sigmoidf_(val);
    }
}

// ---------------------------------------------------------------- k_scan
// grid 256 = b(16) x dblk(16), block 64. LDS-staged wsmall + e/a tile + q.
__global__ void k_scan(const float* __restrict__ Mv0, const float* __restrict__ eb,
                       const float* __restrict__ ab, const float* __restrict__ wsmall,
                       const int* __restrict__ qq, u16* __restrict__ fA) {
    int b = blockIdx.x >> 4, dblk = blockIdx.x & 15;
    int lane = threadIdx.x;
    int s = lane >> 3, dlo = lane & 7;
    int d = dblk * 8 + dlo;

    __shared__ float wsm[101 * 64];
    __shared__ float el[128][8];
    __shared__ float al[128][8];
    __shared__ int ql[128];

    for (int i = lane; i < 101 * 64; i += 64) wsm[i] = wsmall[i];
    for (int i = lane; i < 1024; i += 64) {
        int t = i >> 3, dl = i & 7;
        el[t][dl] = eb[(b * 128 + t) * 128 + dblk * 8 + dl];
        al[t][dl] = ab[(b * 128 + t) * 128 + dblk * 8 + dl];
    }
    for (int i = lane; i < 128; i += 64) ql[i] = qq[b * 128 + i];
    __syncthreads();

    float mv[8];
#pragma unroll
    for (int q = 0; q < 8; q++) mv[q] = Mv0[(s * 8 + q) * 128 + d];

    u16* fout = fA + (b * 128) * 256 + d;

    int qt = ql[0];
    const float4* wr = (const float4*)(wsm + qt * 64 + s * 8);
    float4 w0 = wr[0], w1 = wr[1];
    float ecur = el[0][dlo], acur = al[0][dlo];

    for (int t = 0; t < 128; t++) {
        int tn = (t < 127) ? t + 1 : 127;
        int qn = ql[tn];
        const float4* wrn = (const float4*)(wsm + qn * 64 + s * 8);
        float4 nw0 = wrn[0], nw1 = wrn[1];
        float en = el[tn][dlo], an = al[tn][dlo];

        float w[8] = { w0.x, w0.y, w0.z, w0.w, w1.x, w1.y, w1.z, w1.w };
        float rd = 0.f;
#pragma unroll
        for (int q = 0; q < 8; q++) {
            rd = fmaf(w[q], mv[q], rd);
            mv[q] = fmaf(w[q], fmaf(-mv[q], ecur, acur), mv[q]);
        }
        rd += __shfl_xor(rd, 8, 64);
        rd += __shfl_xor(rd, 16, 64);
        rd += __shfl_xor(rd, 32, 64);
        if (s == 0) fout[t * 256] = f2b(rd);

        ecur = en; acur = an; w0 = nw0; w1 = nw1;
    }
}

// ---------------------------------------------------------------- k_outfin
// grid 128, block 512 (8 waves). Wave wv computes f tile rows rt*16..+15 x cols
// wv*16..+15 (K=256 MFMA), tanh -> LDS bf16. Then wave 0: out = sigmoid(f @ WpT^T + b_p).
__global__ void k_outfin(const u16* __restrict__ fA, const u16* __restrict__ WfT,
                         const float* __restrict__ bfp, const u16* __restrict__ WpT,
                         const float* __restrict__ bp, float* __restrict__ out) {
    int rt = blockIdx.x;
    int wv = threadIdx.x >> 6, lane = threadIdx.x & 63;
    int m = lane & 15, quad = lane >> 4;
    __shared__ u16 ftile[16][128];

    const short8* ap = (const short8*)(fA + (rt * 16 + m) * 256 + quad * 8);
    const short8* bpw = (const short8*)(WfT + (wv * 16 + m) * 256 + quad * 8);
    f32x4 acc = {0.f, 0.f, 0.f, 0.f};
#pragma unroll
    for (int kc = 0; kc < 8; kc++)
        acc = __builtin_amdgcn_mfma_f32_16x16x32_bf16(ap[kc * 4], bpw[kc * 4], acc, 0, 0, 0);
    int col = wv * 16 + m;
    float bias = bfp[col];
#pragma unroll
    for (int reg = 0; reg < 4; reg++)
        ftile[quad * 4 + reg][col] = f2b(fast_tanh(acc[reg] + bias));
    __syncthreads();

    if (wv == 0) {
        f32x4 facc = {0.f, 0.f, 0.f, 0.f};
#pragma unroll
        for (int kc = 0; kc < 4; kc++) {
            short8 af = *(const short8*)(&ftile[m][kc * 32 + quad * 8]);
            short8 bf = *(const short8*)(WpT + m * 128 + kc * 32 + quad * 8);
            facc = __builtin_amdgcn_mfma_f32_16x16x32_bf16(af, bf, facc, 0, 0, 0);
        }
        if (m < 10) {
            float bias2 = bp[m];
#pragma unroll
            for (int reg = 0; reg < 4; reg++) {
                int row = rt * 16 + quad * 4 + reg;
                out[row * 10 + m] = sigmoidf_(facc[reg] + bias2);
            }
        }
    }
}

extern "C" void kernel_launch(void* const* d_in, const int* in_sizes, int n_in,
                              void* d_out, int out_size, void* d_ws, size_t ws_size,
                              hipStream_t stream) {
    const int*   code = (const int*)d_in[0];
    const int*   q    = (const int*)d_in[1];
    const int*   r    = (const int*)d_in[2];
    const float* EN   = (const float*)d_in[3];
    const float* EP   = (const float*)d_in[4];
    const float* Wpt  = (const float*)d_in[5];
    const float* bpt  = (const float*)d_in[6];
    const float* Watt = (const float*)d_in[7];
    const float* Kemb = (const float*)d_in[9];
    const float* Mk   = (const float*)d_in[10];
    const float* Mv0  = (const float*)d_in[11];
    const float* Vemb = (const float*)d_in[12];
    const float* We   = (const float*)d_in[13];
    const float* be   = (const float*)d_in[14];
    const float* Wa   = (const float*)d_in[15];
    const float* ba   = (const float*)d_in[16];
    const float* Wf   = (const float*)d_in[17];
    const float* bf_  = (const float*)d_in[18];
    const float* Wp   = (const float*)d_in[19];
    const float* bp   = (const float*)d_in[20];

    char* ws = (char*)d_ws;
    size_t off = 0;
    auto alloc = [&](size_t bytes) { void* p = ws + off; off = (off + bytes + 255) & ~255UL; return p; };
    u8*    PS8    = (u8*)alloc(10002UL * 384);
    u8*    PE8    = (u8*)alloc(10002UL * 384);
    u8*    PP8    = (u8*)alloc(10002UL * 384);
    u16*   ENb    = (u16*)alloc(10016UL * 128 * 2);   // +14 rows pad: k_preM tail reads
    u16*   EPb    = (u16*)alloc(10016UL * 128 * 2);
    u8*    EN8    = (u8*)alloc(10002UL * 128);
    u8*    EP8    = (u8*)alloc(10002UL * 128);
    u16*   Wt     = (u16*)alloc(384UL * 384 * 2);
    u16*   WeaT   = (u16*)alloc(256UL * 512 * 2);
    u16*   WfT    = (u16*)alloc(128UL * 256 * 2);
    u16*   WpT    = (u16*)alloc(16UL * 128 * 2);
    float* attn   = (float*)alloc(16UL * 128 * 128 * 4);   // [b][l][p]
    u16*   vA     = (u16*)alloc(2048UL * 512 * 2);         // [Vemb[r] ; code_vec] bf16
    u16*   fA     = (u16*)alloc(2048UL * 256 * 2);         // [read ; Kemb[q]] bf16
    float* eb     = (float*)alloc(2048UL * 128 * 4);
    float* ab     = (float*)alloc(2048UL * 128 * 4);
    float* wsmall = (float*)alloc(101UL * 64 * 4);

    k_conv<<<2048 + 26, 256, 0, stream>>>(EN, EP, Wpt, We, Wa, Wf, Wp, Kemb, Mk,
                                          ENb, EPb, EN8, EP8, Wt, WeaT, WfT, WpT, wsmall);
    k_preM<<<dim3(313, 3), 256, 0, stream>>>(ENb, EPb, Wt, bpt, PS8, PE8, PP8);
    k_cwsm<<<2048, 256, 0, stream>>>(code, PS8, PE8, PP8, Watt, attn);
    k_cv<<<2048, 256, 0, stream>>>(code, attn, EN8, EP8, r, q, Vemb, Kemb, vA, fA);
    k_eawM<<<512, 256, 0, stream>>>(vA, WeaT, be, ba, eb, ab);
    k_scan<<<256, 64, 0, stream>>>(Mv0, eb, ab, wsmall, q, fA);
    k_outfin<<<128, 512, 0, stream>>>(fA, WfT, bf_, WpT, bp, (float*)d_out);
}